// Round 13
// baseline (2506.420 us; speedup 1.0000x reference)
//
#include <hip/hip_runtime.h>
#include <math.h>

// ---- problem constants ----
#define BB   8
#define TT   5
#define NN   2048
#define FIN  64
#define EE   32768
#define DD   256
#define HH   8
#define FFD  2048
#define NCLS 10
#define GG   (BB*TT)        // 40 graphs
#define BN   (BB*NN)        // 16384
#define NM   (GG*NN)        // 81920 rows (= TT*BN)
#define NE   ((long)GG*EE)  // 1310720 edges

#define MR        16384           // rows per FFN chunk (5 chunks)

typedef __attribute__((ext_vector_type(8))) short short8;
typedef __attribute__((ext_vector_type(4))) float f32x4;

// ---- bf16 helpers (RNE) ----
__device__ __forceinline__ unsigned short f2b(float f) {
    unsigned u = __float_as_uint(f);
    u = (u + 0x7fffu + ((u >> 16) & 1u)) >> 16;
    return (unsigned short)u;
}
__device__ __forceinline__ float b2f(unsigned short b) {
    return __uint_as_float(((unsigned)b) << 16);
}

// async global->LDS, 16B per lane (dest must be wave-uniform base + lane*16)
__device__ __forceinline__ void gload_lds16(const void* g, void* l) {
    __builtin_amdgcn_global_load_lds(
        (__attribute__((address_space(1))) void*)g,
        (__attribute__((address_space(3))) void*)l, 16, 0, 0);
}

// =====================================================================
// Weight transpose+convert: in fp32 [K][N] row-major -> out bf16 [N][K]
// =====================================================================
__global__ void wtrans(const float* __restrict__ in, unsigned short* __restrict__ out,
                       int K, int N) {
    __shared__ float t[32][33];
    const int n0 = blockIdx.x * 32, k0 = blockIdx.y * 32;
    const int tx = threadIdx.x, ty = threadIdx.y;
    for (int i = ty; i < 32; i += 8) t[i][tx] = in[(long)(k0 + i) * N + n0 + tx];
    __syncthreads();
    for (int i = ty; i < 32; i += 8)
        out[(long)(n0 + i) * K + k0 + tx] = f2b(t[tx][i]);
}

// fp32 -> bf16 elementwise (n4 float4 groups)
__global__ void xconvert(const float* __restrict__ in, unsigned short* __restrict__ out, long n4) {
    long gid = (long)blockIdx.x * blockDim.x + threadIdx.x;
    if (gid >= n4) return;
    float4 v = ((const float4*)in)[gid];
    ushort4 o;
    o.x = f2b(v.x); o.y = f2b(v.y); o.z = f2b(v.z); o.w = f2b(v.w);
    ((ushort4*)out)[gid] = o;
}

// pack 3 bias vectors of 256 into one 768 buffer
__global__ void pack3(const float* __restrict__ a, const float* __restrict__ b,
                      const float* __restrict__ c, float* __restrict__ o) {
    int i = threadIdx.x;
    o[i] = a[i]; o[256 + i] = b[i]; o[512 + i] = c[i];
}

// =====================================================================
// bf16 MFMA GEMM, BK=64 + XOR-swizzled LDS (rule-21 compliant).
// C[M x N] = A[M x K] @ W[K x N] + bias. K % 64 == 0.
// 128x128 tile, 256 threads = 4 waves (2x2), 16x16x32 MFMA, XCD swizzle.
// =====================================================================
template <bool RELU, bool OUTBF>
__global__ __launch_bounds__(256) void gemm_mfma(
    const unsigned short* __restrict__ A, int lda,
    const unsigned short* __restrict__ WT,
    const float* __restrict__ bias,
    void* __restrict__ Cv, int ldc, int K)
{
    __shared__ unsigned short As[128 * 64];
    __shared__ unsigned short Bs[128 * 64];
    const int tid = threadIdx.x;
    const int wid = tid >> 6, lane = tid & 63;
    const int wm = wid >> 1, wn = wid & 1;
    const int gx = gridDim.x, gy = gridDim.y;
    int bx = blockIdx.x, by = blockIdx.y;
    if ((gx & 7) == 0) {
        const int lbid = bx + gx * by;
        const int xcd = lbid & 7;
        const int i = lbid >> 3;
        const int CX = gx >> 3;
        bx = xcd * CX + i / gy;
        by = i - (i / gy) * gy;
    }
    const long row0 = (long)bx * 128;
    const long col0 = (long)by * 128;
    const int srow = tid >> 3;            // 0..31 (per pass)
    const int schunk = tid & 7;           // 16B chunk in 128B row
    const int fr = lane & 15;
    const int q = lane >> 4;
    f32x4 acc[4][4] = {};
    for (int k0 = 0; k0 < K; k0 += 64) {
        __syncthreads();
#pragma unroll
        for (int p = 0; p < 4; ++p) {
            const int row = p * 32 + srow;
            const int sc = (schunk ^ (row & 7)) * 8;
            gload_lds16(&A[(row0 + row) * (long)lda + k0 + sc], As + row * 64 + schunk * 8);
            gload_lds16(&WT[(col0 + row) * (long)K + k0 + sc], Bs + row * 64 + schunk * 8);
        }
        __syncthreads();
#pragma unroll
        for (int kk = 0; kk < 2; ++kk) {
            short8 af[4], bfr[4];
#pragma unroll
            for (int mf = 0; mf < 4; ++mf) {
                const int row = wm * 64 + mf * 16 + fr;
                const int byo = (row * 128 + kk * 64 + q * 16) ^ ((row & 7) << 4);
                af[mf] = *(const short8*)((const char*)As + byo);
            }
#pragma unroll
            for (int nf = 0; nf < 4; ++nf) {
                const int row = wn * 64 + nf * 16 + fr;
                const int byo = (row * 128 + kk * 64 + q * 16) ^ ((row & 7) << 4);
                bfr[nf] = *(const short8*)((const char*)Bs + byo);
            }
#pragma unroll
            for (int mf = 0; mf < 4; ++mf)
#pragma unroll
                for (int nf = 0; nf < 4; ++nf)
                    acc[mf][nf] = __builtin_amdgcn_mfma_f32_16x16x32_bf16(
                        af[mf], bfr[nf], acc[mf][nf], 0, 0, 0);
        }
    }
#pragma unroll
    for (int nf = 0; nf < 4; ++nf) {
        const long col = col0 + wn * 64 + nf * 16 + fr;
        const float bv = bias[col];
#pragma unroll
        for (int mf = 0; mf < 4; ++mf) {
#pragma unroll
            for (int i = 0; i < 4; ++i) {
                const long r = row0 + wm * 64 + mf * 16 + q * 4 + i;
                float vv = acc[mf][nf][i] + bv;
                if (RELU) vv = fmaxf(vv, 0.f);
                if (OUTBF) ((unsigned short*)Cv)[r * ldc + col] = f2b(vv);
                else       ((float*)Cv)[r * ldc + col] = vv;
            }
        }
    }
}

// =====================================================================
// Fused GEMM + residual + LayerNorm:
//   seq[M][256] = LN(seq + A @ W + bias) * g + b      (in-place over seq)
// 64x256 tile (full LN row per block), 256 threads = 4 waves (1x4), BK=64.
// WT = W^T [256][K]. Same rule-21 staging/swizzle as gemm_mfma.
// =====================================================================
__global__ __launch_bounds__(256) void gemm_ln(
    const unsigned short* __restrict__ A, int lda,
    const unsigned short* __restrict__ WT,
    const float* __restrict__ bias,
    unsigned short* __restrict__ seq,
    const float* __restrict__ g, const float* __restrict__ b, int K)
{
    __shared__ unsigned short As[64 * 64];
    __shared__ unsigned short Bs[256 * 64];
    __shared__ float Lsum[64][4];
    __shared__ float Lsq[64][4];
    const int tid = threadIdx.x;
    const int wn = tid >> 6, lane = tid & 63;
    const int fr = lane & 15, q = lane >> 4;
    const int gx = gridDim.x;
    int bx = blockIdx.x;
    if ((gx & 7) == 0) bx = (bx & 7) * (gx >> 3) + (bx >> 3);
    const long row0 = (long)bx * 64;
    const int srow = tid >> 3;            // 0..31
    const int schunk = tid & 7;
    f32x4 acc[4][4] = {};
    for (int k0 = 0; k0 < K; k0 += 64) {
        __syncthreads();
#pragma unroll
        for (int p = 0; p < 2; ++p) {
            const int row = p * 32 + srow;
            const int sc = (schunk ^ (row & 7)) * 8;
            gload_lds16(&A[(row0 + row) * (long)lda + k0 + sc], As + row * 64 + schunk * 8);
        }
#pragma unroll
        for (int p = 0; p < 8; ++p) {
            const int row = p * 32 + srow;
            const int sc = (schunk ^ (row & 7)) * 8;
            gload_lds16(&WT[(long)row * K + k0 + sc], Bs + row * 64 + schunk * 8);
        }
        __syncthreads();
#pragma unroll
        for (int kk = 0; kk < 2; ++kk) {
            short8 af[4], bfr[4];
#pragma unroll
            for (int mf = 0; mf < 4; ++mf) {
                const int row = mf * 16 + fr;
                const int byo = (row * 128 + kk * 64 + q * 16) ^ ((row & 7) << 4);
                af[mf] = *(const short8*)((const char*)As + byo);
            }
#pragma unroll
            for (int nf = 0; nf < 4; ++nf) {
                const int row = wn * 64 + nf * 16 + fr;
                const int byo = (row * 128 + kk * 64 + q * 16) ^ ((row & 7) << 4);
                bfr[nf] = *(const short8*)((const char*)Bs + byo);
            }
#pragma unroll
            for (int mf = 0; mf < 4; ++mf)
#pragma unroll
                for (int nf = 0; nf < 4; ++nf)
                    acc[mf][nf] = __builtin_amdgcn_mfma_f32_16x16x32_bf16(
                        af[mf], bfr[nf], acc[mf][nf], 0, 0, 0);
        }
    }
    // epilogue: val = acc + bias + residual(seq)
#pragma unroll
    for (int nf = 0; nf < 4; ++nf) {
        const int col = wn * 64 + nf * 16 + fr;
        const float bv = bias[col];
#pragma unroll
        for (int mf = 0; mf < 4; ++mf)
#pragma unroll
            for (int i = 0; i < 4; ++i) {
                const long r = row0 + mf * 16 + q * 4 + i;
                acc[mf][nf][i] += bv + b2f(seq[r * 256 + col]);
            }
    }
    // per-row stats: sum over nf locally, shfl over fr-group, LDS cross-wave
#pragma unroll
    for (int mf = 0; mf < 4; ++mf)
#pragma unroll
        for (int i = 0; i < 4; ++i) {
            float s = acc[mf][0][i] + acc[mf][1][i] + acc[mf][2][i] + acc[mf][3][i];
            float s2 = acc[mf][0][i] * acc[mf][0][i] + acc[mf][1][i] * acc[mf][1][i]
                     + acc[mf][2][i] * acc[mf][2][i] + acc[mf][3][i] * acc[mf][3][i];
#pragma unroll
            for (int m = 1; m <= 8; m <<= 1) {
                s += __shfl_xor(s, m, 64);
                s2 += __shfl_xor(s2, m, 64);
            }
            if (fr == 0) {
                Lsum[mf * 16 + q * 4 + i][wn] = s;
                Lsq[mf * 16 + q * 4 + i][wn] = s2;
            }
        }
    __syncthreads();
#pragma unroll
    for (int mf = 0; mf < 4; ++mf)
#pragma unroll
        for (int i = 0; i < 4; ++i) {
            const int lr = mf * 16 + q * 4 + i;
            const float sum = Lsum[lr][0] + Lsum[lr][1] + Lsum[lr][2] + Lsum[lr][3];
            const float sq  = Lsq[lr][0] + Lsq[lr][1] + Lsq[lr][2] + Lsq[lr][3];
            const float mean = sum * (1.f / 256.f);
            const float var = sq * (1.f / 256.f) - mean * mean;
            const float inv = rsqrtf(var + 1e-5f);
            const long r = row0 + lr;
#pragma unroll
            for (int nf = 0; nf < 4; ++nf) {
                const int col = wn * 64 + nf * 16 + fr;
                seq[r * 256 + col] = f2b((acc[mf][nf][i] - mean) * inv * g[col] + b[col]);
            }
        }
}

// =====================================================================
// CSR build: edges grouped by global target row tf = g*NN + tgt
// =====================================================================
__global__ void csr_init(int* __restrict__ cnt, int* __restrict__ fill) {
    int gid = blockIdx.x * blockDim.x + threadIdx.x;
    if (gid < NM) { cnt[gid] = 0; fill[gid] = 0; }
}

__global__ void csr_count(const int* __restrict__ eidx, int* __restrict__ cnt) {
    long el = (long)blockIdx.x * blockDim.x + threadIdx.x;
    if (el >= NE) return;
    int g = (int)(el >> 15), e = (int)(el & (EE - 1));
    int tgt = eidx[((long)g * 2 + 1) * EE + e];
    atomicAdd(&cnt[g * NN + tgt], 1);
}

__global__ __launch_bounds__(1024) void csr_scan(const int* __restrict__ cnt, int* __restrict__ off) {
    __shared__ int part[1024];
    const int t = threadIdx.x;
    const int base = t * (NM / 1024);
    int s = 0;
    for (int i = 0; i < NM / 1024; ++i) s += cnt[base + i];
    part[t] = s;
    __syncthreads();
    for (int d = 1; d < 1024; d <<= 1) {
        int v = (t >= d) ? part[t - d] : 0;
        __syncthreads();
        part[t] += v;
        __syncthreads();
    }
    int run = (t == 0) ? 0 : part[t - 1];
    for (int i = 0; i < NM / 1024; ++i) { off[base + i] = run; run += cnt[base + i]; }
    if (t == 1023) off[NM] = run;
}

__global__ void csr_scatter(const int* __restrict__ eidx, const int* __restrict__ off,
                            int* __restrict__ fill, int* __restrict__ csr) {
    long el = (long)blockIdx.x * blockDim.x + threadIdx.x;
    if (el >= NE) return;
    int g = (int)(el >> 15), e = (int)(el & (EE - 1));
    int tgt = eidx[((long)g * 2 + 1) * EE + e];
    int tf = g * NN + tgt;
    int pos = atomicAdd(&fill[tf], 1);
    csr[off[tf] + pos] = (int)el;
}

// =====================================================================
// Fused TransformerConv (R10 config: 256 threads, single-edge prefetch)
// on interleaved qkv [NM][768]. Writes conv output over the q slice.
// =====================================================================
__global__ __launch_bounds__(256) void conv_fused(
    unsigned short* __restrict__ Z,
    const int* __restrict__ eidx, const float* __restrict__ eattr,
    const float* __restrict__ W_edge, const float* __restrict__ b_edge,
    const int* __restrict__ off, const int* __restrict__ csr)
{
    const int tid = threadIdx.x;
    const int wave = tid >> 6, lane = tid & 63;
    const int bid = (blockIdx.x & 7) * (NM / 4 / 8) + (blockIdx.x >> 3);
    const long tf = (long)bid * 4 + wave;
    const int d0 = lane * 4;
    unsigned short* qrow = &Z[tf * 768];
    const ushort4 q4 = *(const ushort4*)&qrow[d0];
    const float q0 = b2f(q4.x), q1 = b2f(q4.y), q2 = b2f(q4.z), q3 = b2f(q4.w);
    const float be0 = b_edge[d0], be1 = b_edge[d0 + 1],
                be2 = b_edge[d0 + 2], be3 = b_edge[d0 + 3];
    float w0[6], w1r[6], w2r[6], w3r[6];
#pragma unroll
    for (int j2 = 0; j2 < 6; ++j2) {
        const float* wp = &W_edge[j2 * 256 + d0];
        w0[j2] = wp[0]; w1r[j2] = wp[1]; w2r[j2] = wp[2]; w3r[j2] = wp[3];
    }
    float qb = q0 * be0 + q1 * be1 + q2 * be2 + q3 * be3;
    float qw[6];
#pragma unroll
    for (int j2 = 0; j2 < 6; ++j2)
        qw[j2] = q0 * w0[j2] + q1 * w1r[j2] + q2 * w2r[j2] + q3 * w3r[j2];
#pragma unroll
    for (int mm = 1; mm <= 4; mm <<= 1) {
        qb += __shfl_xor(qb, mm, 64);
#pragma unroll
        for (int j2 = 0; j2 < 6; ++j2) qw[j2] += __shfl_xor(qw[j2], mm, 64);
    }
    const float scale = 0.17677669529663687f;  // 1/sqrt(32)
    float s = 0.f, a0 = 0.f, a1 = 0.f, a2 = 0.f, a3 = 0.f;
    float t0 = 0.f, t1 = 0.f, t2 = 0.f, t3 = 0.f, t4 = 0.f, t5 = 0.f;
    const int jb = off[tf], je = off[tf + 1];
    ushort4 kc, vc; float eac[6];
    if (jb < je) {
        const int el = csr[jb];
        const int g = el >> 15, e = el & (EE - 1);
        const long sf = (long)g * NN + eidx[((long)g * 2) * EE + e];
        kc = *(const ushort4*)&Z[sf * 768 + 256 + d0];
        vc = *(const ushort4*)&Z[sf * 768 + 512 + d0];
#pragma unroll
        for (int t = 0; t < 6; ++t) eac[t] = eattr[(long)el * 6 + t];
    }
    for (int j = jb; j < je; ++j) {
        ushort4 kn, vn; float ean[6];
        if (j + 1 < je) {  // prefetch next edge (wave-uniform branch)
            const int el = csr[j + 1];
            const int g = el >> 15, e = el & (EE - 1);
            const long sf = (long)g * NN + eidx[((long)g * 2) * EE + e];
            kn = *(const ushort4*)&Z[sf * 768 + 256 + d0];
            vn = *(const ushort4*)&Z[sf * 768 + 512 + d0];
#pragma unroll
            for (int t = 0; t < 6; ++t) ean[t] = eattr[(long)el * 6 + t];
        }
        float p = q0 * b2f(kc.x) + q1 * b2f(kc.y) + q2 * b2f(kc.z) + q3 * b2f(kc.w);
        p += __shfl_xor(p, 1, 64);
        p += __shfl_xor(p, 2, 64);
        p += __shfl_xor(p, 4, 64);
        float alpha = p + qb;
        alpha += eac[0] * qw[0] + eac[1] * qw[1] + eac[2] * qw[2]
               + eac[3] * qw[3] + eac[4] * qw[4] + eac[5] * qw[5];
        const float a = __expf(alpha * scale);
        s += a;
        a0 += a * b2f(vc.x); a1 += a * b2f(vc.y);
        a2 += a * b2f(vc.z); a3 += a * b2f(vc.w);
        t0 += a * eac[0]; t1 += a * eac[1]; t2 += a * eac[2];
        t3 += a * eac[3]; t4 += a * eac[4]; t5 += a * eac[5];
        kc = kn; vc = vn;
#pragma unroll
        for (int t = 0; t < 6; ++t) eac[t] = ean[t];
    }
    const float inv = (s > 0.f) ? 1.f / s : 0.f;
    float o0 = a0 + be0 * s, o1 = a1 + be1 * s, o2 = a2 + be2 * s, o3 = a3 + be3 * s;
    o0 += w0[0]*t0 + w0[1]*t1 + w0[2]*t2 + w0[3]*t3 + w0[4]*t4 + w0[5]*t5;
    o1 += w1r[0]*t0 + w1r[1]*t1 + w1r[2]*t2 + w1r[3]*t3 + w1r[4]*t4 + w1r[5]*t5;
    o2 += w2r[0]*t0 + w2r[1]*t1 + w2r[2]*t2 + w2r[3]*t3 + w2r[4]*t4 + w2r[5]*t5;
    o3 += w3r[0]*t0 + w3r[1]*t1 + w3r[2]*t2 + w3r[3]*t3 + w3r[4]*t4 + w3r[5]*t5;
    ushort4 o;
    o.x = f2b(o0 * inv); o.y = f2b(o1 * inv);
    o.z = f2b(o2 * inv); o.w = f2b(o3 * inv);
    *(ushort4*)&qrow[d0] = o;
}

// seq(bf16, [t*BN+b*N+n][256]) = conv(q-slice of Z) + skip(k-slice of Z)
__global__ void transpose_add(const unsigned short* __restrict__ Z,
                              unsigned short* __restrict__ out) {
    long gid = (long)blockIdx.x * blockDim.x + threadIdx.x;
    long row = gid >> 6;
    int c4 = (int)(gid & 63);
    int n = (int)(row % NN);
    int bt = (int)(row / NN);
    int t = bt % TT, b = bt / TT;
    long orow = (long)t * BN + (long)b * NN + n;
    ushort4 cv = ((const ushort4*)&Z[row * 768])[c4];
    ushort4 sv = ((const ushort4*)&Z[row * 768 + 256])[c4];
    ushort4 o;
    o.x = f2b(b2f(cv.x) + b2f(sv.x));
    o.y = f2b(b2f(cv.y) + b2f(sv.y));
    o.z = f2b(b2f(cv.z) + b2f(sv.z));
    o.w = f2b(b2f(cv.w) + b2f(sv.w));
    ((ushort4*)out)[orow * 64 + c4] = o;
}

// temporal attention over T=5 on interleaved qkv [NM][768]; o over q-slice.
__global__ __launch_bounds__(256) void mha_time(unsigned short* __restrict__ Z)
{
    const int tid = threadIdx.x;
    const int grp = tid >> 5, c = tid & 31;
    long pair = (long)blockIdx.x * 8 + grp;
    int h = (int)(pair & 7);
    long bn = pair >> 3;
    const float scale = 0.17677669529663687f;
    float qv[TT], kv[TT], vv[TT];
    long r[TT];
#pragma unroll
    for (int t = 0; t < TT; ++t) {
        r[t] = ((long)t * BN + bn) * 768 + h * 32 + c;
        qv[t] = b2f(Z[r[t]]); kv[t] = b2f(Z[r[t] + 256]); vv[t] = b2f(Z[r[t] + 512]);
    }
    float s[TT][TT];
#pragma unroll
    for (int t = 0; t < TT; ++t)
#pragma unroll
        for (int u = 0; u < TT; ++u) {
            float p = qv[t] * kv[u];
#pragma unroll
            for (int m = 16; m >= 1; m >>= 1) p += __shfl_xor(p, m, 64);
            s[t][u] = p * scale;
        }
#pragma unroll
    for (int t = 0; t < TT; ++t) {
        float mx = s[t][0];
#pragma unroll
        for (int u = 1; u < TT; ++u) mx = fmaxf(mx, s[t][u]);
        float sm = 0.f;
#pragma unroll
        for (int u = 0; u < TT; ++u) { s[t][u] = expf(s[t][u] - mx); sm += s[t][u]; }
        float inv = 1.f / sm;
        float o = 0.f;
#pragma unroll
        for (int u = 0; u < TT; ++u) o += s[t][u] * vv[u];
        Z[r[t]] = f2b(o * inv);
    }
}

// out[row][0..9] = seq[t=T-1 rows](bf16) @ W_out + b_out ; one block per row
__global__ __launch_bounds__(256) void final_out(
    const unsigned short* __restrict__ seq, const float* __restrict__ Wd,
    const float* __restrict__ bd, float* __restrict__ out)
{
    __shared__ float xs[256];
    long row = blockIdx.x;
    xs[threadIdx.x] = b2f(seq[((long)(TT - 1) * BN + row) * 256 + threadIdx.x]);
    __syncthreads();
    const int wv = threadIdx.x >> 6, lane = threadIdx.x & 63;
    for (int o = wv; o < NCLS; o += 4) {
        float p = 0.f;
#pragma unroll
        for (int i = 0; i < 4; ++i) {
            int kk = lane + 64 * i;
            p += xs[kk] * Wd[kk * NCLS + o];
        }
#pragma unroll
        for (int m = 32; m >= 1; m >>= 1) p += __shfl_xor(p, m, 64);
        if (lane == 0) out[row * NCLS + o] = p + bd[o];
    }
}

__global__ void fill_sentinel(float* __restrict__ out, int n) {
    int gid = blockIdx.x * blockDim.x + threadIdx.x;
    if (gid < n) out[gid] = 1.0e6f;
}

// =====================================================================
extern "C" void kernel_launch(void* const* d_in, const int* in_sizes, int n_in,
                              void* d_out, int out_size, void* d_ws, size_t ws_size,
                              hipStream_t stream) {
    const float* xseq  = (const float*)d_in[0];
    const int*   eidx  = (const int*)d_in[1];
    const float* eattr = (const float*)d_in[2];
    const float* W_node = (const float*)d_in[3];
    const float* b_node = (const float*)d_in[4];
    const float* W_edge = (const float*)d_in[5];
    const float* b_edge = (const float*)d_in[6];
    const float* Wq = (const float*)d_in[7];  const float* bq = (const float*)d_in[8];
    const float* Wk = (const float*)d_in[9];  const float* bk = (const float*)d_in[10];
    const float* Wv = (const float*)d_in[11]; const float* bv = (const float*)d_in[12];
    const float* Ws = (const float*)d_in[13]; const float* bs = (const float*)d_in[14];
    const float* Wqkv = (const float*)d_in[15]; const float* bqkv = (const float*)d_in[16];
    const float* Wo = (const float*)d_in[17];   const float* bo = (const float*)d_in[18];
    const float* W1 = (const float*)d_in[19];   const float* b1 = (const float*)d_in[20];
    const float* W2 = (const float*)d_in[21];   const float* b2 = (const float*)d_in[22];
    const float* g_ln1 = (const float*)d_in[23]; const float* b_ln1 = (const float*)d_in[24];
    const float* g_ln2 = (const float*)d_in[25]; const float* b_ln2 = (const float*)d_in[26];
    const float* W_out = (const float*)d_in[27]; const float* b_out = (const float*)d_in[28];
    float* out = (float*)d_out;

    // ---- workspace layout ----
    const long SZ = (long)NM * DD;            // 20,971,520 elements
    unsigned short* Abf = (unsigned short*)d_ws;     // seq activations bf16 (40MB)
    unsigned short* Zu  = Abf + SZ;                  // qkv interleaved [NM][768] (120MB)
    unsigned short* Hid = Zu;                        // FFN hidden bf16 [MR][2048] (64MB)
    unsigned short* WX = Zu + 3 * SZ;
    unsigned short* xbf = WX;                             // 81920*64
    unsigned short* wtN = xbf + (long)NM * FIN;           // [256][64]
    unsigned short* wtQ = wtN + 256 * 64;                 // [768][256] stacked q,k,v
    unsigned short* wtK = wtQ + 65536;
    unsigned short* wtV = wtK + 65536;
    unsigned short* wtS = wtV + 65536;
    unsigned short* wtQKV = wtS + 65536;                  // 3 * [768][256]
    unsigned short* wtO = wtQKV + 3L * 768 * 256;         // 3 * [256][256]
    unsigned short* wtW1 = wtO + 3L * 65536;              // 3 * [2048][256]
    unsigned short* wtW2 = wtW1 + 3L * 2048 * 256;        // 3 * [256][2048]
    int* cnt  = (int*)(wtW2 + 3L * 256 * 2048);
    int* coff = cnt + NM;                                 // NM+1
    int* cfil = coff + NM + 1;
    int* csr  = cfil + NM;                                // NE ints
    float* qkvb = (float*)(csr + NE);                     // 768 packed bias
    char* wend = (char*)(qkvb + 768);
    const size_t need = (size_t)(wend - (char*)d_ws);
    if (ws_size < need) {
        fill_sentinel<<<dim3((out_size + 255) / 256), dim3(256), 0, stream>>>(out, out_size);
        return;
    }

    dim3 blk(256);
    dim3 tb(32, 8);

    // ---- prologue ----
    xconvert<<<dim3((unsigned)((long)NM * FIN / 4 / 256)), blk, 0, stream>>>(xseq, xbf, (long)NM * FIN / 4);
    wtrans<<<dim3(DD / 32, FIN / 32), tb, 0, stream>>>(W_node, wtN, FIN, DD);
    wtrans<<<dim3(DD / 32, DD / 32), tb, 0, stream>>>(Wq, wtQ, DD, DD);
    wtrans<<<dim3(DD / 32, DD / 32), tb, 0, stream>>>(Wk, wtK, DD, DD);
    wtrans<<<dim3(DD / 32, DD / 32), tb, 0, stream>>>(Wv, wtV, DD, DD);
    wtrans<<<dim3(DD / 32, DD / 32), tb, 0, stream>>>(Ws, wtS, DD, DD);
    pack3<<<dim3(1), blk, 0, stream>>>(bq, bk, bv, qkvb);
    for (int l = 0; l < 3; ++l) {
        wtrans<<<dim3(768 / 32, DD / 32), tb, 0, stream>>>(Wqkv + (long)l * DD * 768, wtQKV + (long)l * 768 * 256, DD, 768);
        wtrans<<<dim3(DD / 32, DD / 32), tb, 0, stream>>>(Wo + (long)l * DD * DD, wtO + (long)l * 65536, DD, DD);
        wtrans<<<dim3(FFD / 32, DD / 32), tb, 0, stream>>>(W1 + (long)l * DD * FFD, wtW1 + (long)l * 2048 * 256, DD, FFD);
        wtrans<<<dim3(DD / 32, FFD / 32), tb, 0, stream>>>(W2 + (long)l * FFD * DD, wtW2 + (long)l * 256 * 2048, FFD, DD);
    }

    // ---- CSR build ----
    csr_init<<<dim3((NM + 255) / 256), blk, 0, stream>>>(cnt, cfil);
    csr_count<<<dim3((unsigned)(NE / 256)), blk, 0, stream>>>(eidx, cnt);
    csr_scan<<<dim3(1), dim3(1024), 0, stream>>>(cnt, coff);
    csr_scatter<<<dim3((unsigned)(NE / 256)), blk, 0, stream>>>(eidx, coff, cfil, csr);

    // ---- stage 1 ----
    gemm_mfma<false, true><<<dim3(NM / 128, DD / 128), blk, 0, stream>>>(
        xbf, FIN, wtN, b_node, Abf, DD, FIN);
    gemm_mfma<false, true><<<dim3(NM / 128, 768 / 128), blk, 0, stream>>>(
        Abf, DD, wtQ, qkvb, Zu, 768, DD);
    conv_fused<<<dim3(NM / 4), blk, 0, stream>>>(
        Zu, eidx, eattr, W_edge, b_edge, coff, csr);
    gemm_mfma<false, true><<<dim3(NM / 128, DD / 128), blk, 0, stream>>>(
        Abf, DD, wtS, bs, (void*)(Zu + 256), 768, DD);
    transpose_add<<<dim3(NM * 64 / 256), blk, 0, stream>>>(Zu, Abf);

    // ---- stage 2: 3 temporal transformer encoder layers ----
    for (int l = 0; l < 3; ++l) {
        gemm_mfma<false, true><<<dim3(NM / 128, 768 / 128), blk, 0, stream>>>(
            Abf, DD, wtQKV + (long)l * 768 * 256, bqkv + (long)l * 768, Zu, 768, DD);
        mha_time<<<dim3(BN * HH / 8), blk, 0, stream>>>(Zu);
        // fused Wo + residual + LN1 (in-place over Abf)
        gemm_ln<<<dim3(NM / 64), blk, 0, stream>>>(
            Zu, 768, wtO + (long)l * 65536, bo + (long)l * DD,
            Abf, g_ln1 + l * DD, b_ln1 + l * DD, DD);
        // FFN: W1 (relu) -> Hid, then fused W2 + residual + LN2
        for (int mr = 0; mr < NM / MR; ++mr) {
            const long r0 = (long)mr * MR;
            gemm_mfma<true, true><<<dim3(MR / 128, FFD / 128), blk, 0, stream>>>(
                Abf + r0 * DD, DD, wtW1 + (long)l * 2048 * 256, b1 + (long)l * FFD, Hid, FFD, DD);
            gemm_ln<<<dim3(MR / 64), blk, 0, stream>>>(
                Hid, FFD, wtW2 + (long)l * 256 * 2048, b2 + (long)l * DD,
                Abf + r0 * DD, g_ln2 + l * DD, b_ln2 + l * DD, FFD);
        }
    }

    // ---- output head ----
    final_out<<<dim3(BN), blk, 0, stream>>>(Abf, W_out, b_out, out);
}

// Round 14
// 2286.772 us; speedup vs baseline: 1.0961x; 1.0961x over previous
//
#include <hip/hip_runtime.h>
#include <math.h>

// ---- problem constants ----
#define BB   8
#define TT   5
#define NN   2048
#define FIN  64
#define EE   32768
#define DD   256
#define HH   8
#define FFD  2048
#define NCLS 10
#define GG   (BB*TT)        // 40 graphs
#define BN   (BB*NN)        // 16384
#define NM   (GG*NN)        // 81920 rows (= TT*BN)
#define NE   ((long)GG*EE)  // 1310720 edges

#define MR        16384           // rows per FFN chunk (5 chunks)

typedef __attribute__((ext_vector_type(8))) short short8;
typedef __attribute__((ext_vector_type(4))) float f32x4;

// ---- bf16 helpers (RNE) ----
__device__ __forceinline__ unsigned short f2b(float f) {
    unsigned u = __float_as_uint(f);
    u = (u + 0x7fffu + ((u >> 16) & 1u)) >> 16;
    return (unsigned short)u;
}
__device__ __forceinline__ float b2f(unsigned short b) {
    return __uint_as_float(((unsigned)b) << 16);
}

// async global->LDS, 16B per lane (dest must be wave-uniform base + lane*16)
__device__ __forceinline__ void gload_lds16(const void* g, void* l) {
    __builtin_amdgcn_global_load_lds(
        (__attribute__((address_space(1))) void*)g,
        (__attribute__((address_space(3))) void*)l, 16, 0, 0);
}

// =====================================================================
// Weight transpose+convert: in fp32 [K][N] row-major -> out bf16 [N][K]
// =====================================================================
__global__ void wtrans(const float* __restrict__ in, unsigned short* __restrict__ out,
                       int K, int N) {
    __shared__ float t[32][33];
    const int n0 = blockIdx.x * 32, k0 = blockIdx.y * 32;
    const int tx = threadIdx.x, ty = threadIdx.y;
    for (int i = ty; i < 32; i += 8) t[i][tx] = in[(long)(k0 + i) * N + n0 + tx];
    __syncthreads();
    for (int i = ty; i < 32; i += 8)
        out[(long)(n0 + i) * K + k0 + tx] = f2b(t[tx][i]);
}

// fp32 -> bf16 elementwise (n4 float4 groups)
__global__ void xconvert(const float* __restrict__ in, unsigned short* __restrict__ out, long n4) {
    long gid = (long)blockIdx.x * blockDim.x + threadIdx.x;
    if (gid >= n4) return;
    float4 v = ((const float4*)in)[gid];
    ushort4 o;
    o.x = f2b(v.x); o.y = f2b(v.y); o.z = f2b(v.z); o.w = f2b(v.w);
    ((ushort4*)out)[gid] = o;
}

// pack 3 bias vectors of 256 into one 768 buffer
__global__ void pack3(const float* __restrict__ a, const float* __restrict__ b,
                      const float* __restrict__ c, float* __restrict__ o) {
    int i = threadIdx.x;
    o[i] = a[i]; o[256 + i] = b[i]; o[512 + i] = c[i];
}

// =====================================================================
// bf16 MFMA GEMM, BK=64 + XOR-swizzled LDS (rule-21 compliant).
// C[M x N] = A[M x K] @ W[K x N] + bias. K % 64 == 0.
// Tile 128 x (32*NF): NF=4 -> 128x128 (default), NF=2 -> 128x64 (used for
// W2 whose 128x128 grid would be exactly 1 block/CU -> barrier-drain bound).
// 256 threads = 4 waves (2 x 2), 16x16x32 MFMA, XCD swizzle.
// =====================================================================
template <bool RELU, bool OUTBF, int NF>
__global__ __launch_bounds__(256) void gemm_mfma(
    const unsigned short* __restrict__ A, int lda,
    const unsigned short* __restrict__ WT,
    const float* __restrict__ bias,
    void* __restrict__ Cv, int ldc, int K)
{
    __shared__ unsigned short As[128 * 64];
    __shared__ unsigned short Bs[32 * NF * 64];
    const int tid = threadIdx.x;
    const int wid = tid >> 6, lane = tid & 63;
    const int wm = wid >> 1, wn = wid & 1;
    const int gx = gridDim.x, gy = gridDim.y;
    int bx = blockIdx.x, by = blockIdx.y;
    if ((gx & 7) == 0) {
        const int lbid = bx + gx * by;
        const int xcd = lbid & 7;
        const int i = lbid >> 3;
        const int CX = gx >> 3;
        bx = xcd * CX + i / gy;
        by = i - (i / gy) * gy;
    }
    const long row0 = (long)bx * 128;
    const long col0 = (long)by * (32 * NF);
    const int srow = tid >> 3;            // 0..31 (per pass)
    const int schunk = tid & 7;           // 16B chunk in 128B row
    const int fr = lane & 15;
    const int q = lane >> 4;
    f32x4 acc[4][NF] = {};
    for (int k0 = 0; k0 < K; k0 += 64) {
        __syncthreads();
#pragma unroll
        for (int p = 0; p < 4; ++p) {
            const int row = p * 32 + srow;
            const int sc = (schunk ^ (row & 7)) * 8;
            gload_lds16(&A[(row0 + row) * (long)lda + k0 + sc], As + row * 64 + schunk * 8);
        }
#pragma unroll
        for (int p = 0; p < NF; ++p) {
            const int row = p * 32 + srow;
            const int sc = (schunk ^ (row & 7)) * 8;
            gload_lds16(&WT[(col0 + row) * (long)K + k0 + sc], Bs + row * 64 + schunk * 8);
        }
        __syncthreads();
#pragma unroll
        for (int kk = 0; kk < 2; ++kk) {
            short8 af[4], bfr[NF];
#pragma unroll
            for (int mf = 0; mf < 4; ++mf) {
                const int row = wm * 64 + mf * 16 + fr;
                const int byo = (row * 128 + kk * 64 + q * 16) ^ ((row & 7) << 4);
                af[mf] = *(const short8*)((const char*)As + byo);
            }
#pragma unroll
            for (int nf = 0; nf < NF; ++nf) {
                const int row = wn * (NF * 16) + nf * 16 + fr;
                const int byo = (row * 128 + kk * 64 + q * 16) ^ ((row & 7) << 4);
                bfr[nf] = *(const short8*)((const char*)Bs + byo);
            }
#pragma unroll
            for (int mf = 0; mf < 4; ++mf)
#pragma unroll
                for (int nf = 0; nf < NF; ++nf)
                    acc[mf][nf] = __builtin_amdgcn_mfma_f32_16x16x32_bf16(
                        af[mf], bfr[nf], acc[mf][nf], 0, 0, 0);
        }
    }
#pragma unroll
    for (int nf = 0; nf < NF; ++nf) {
        const long col = col0 + wn * (NF * 16) + nf * 16 + fr;
        const float bv = bias[col];
#pragma unroll
        for (int mf = 0; mf < 4; ++mf) {
#pragma unroll
            for (int i = 0; i < 4; ++i) {
                const long r = row0 + wm * 64 + mf * 16 + q * 4 + i;
                float vv = acc[mf][nf][i] + bv;
                if (RELU) vv = fmaxf(vv, 0.f);
                if (OUTBF) ((unsigned short*)Cv)[r * ldc + col] = f2b(vv);
                else       ((float*)Cv)[r * ldc + col] = vv;
            }
        }
    }
}

// =====================================================================
// CSR build: edges grouped by global target row tf = g*NN + tgt
// =====================================================================
__global__ void csr_init(int* __restrict__ cnt, int* __restrict__ fill) {
    int gid = blockIdx.x * blockDim.x + threadIdx.x;
    if (gid < NM) { cnt[gid] = 0; fill[gid] = 0; }
}

__global__ void csr_count(const int* __restrict__ eidx, int* __restrict__ cnt) {
    long el = (long)blockIdx.x * blockDim.x + threadIdx.x;
    if (el >= NE) return;
    int g = (int)(el >> 15), e = (int)(el & (EE - 1));
    int tgt = eidx[((long)g * 2 + 1) * EE + e];
    atomicAdd(&cnt[g * NN + tgt], 1);
}

__global__ __launch_bounds__(1024) void csr_scan(const int* __restrict__ cnt, int* __restrict__ off) {
    __shared__ int part[1024];
    const int t = threadIdx.x;
    const int base = t * (NM / 1024);
    int s = 0;
    for (int i = 0; i < NM / 1024; ++i) s += cnt[base + i];
    part[t] = s;
    __syncthreads();
    for (int d = 1; d < 1024; d <<= 1) {
        int v = (t >= d) ? part[t - d] : 0;
        __syncthreads();
        part[t] += v;
        __syncthreads();
    }
    int run = (t == 0) ? 0 : part[t - 1];
    for (int i = 0; i < NM / 1024; ++i) { off[base + i] = run; run += cnt[base + i]; }
    if (t == 1023) off[NM] = run;
}

__global__ void csr_scatter(const int* __restrict__ eidx, const int* __restrict__ off,
                            int* __restrict__ fill, int* __restrict__ csr) {
    long el = (long)blockIdx.x * blockDim.x + threadIdx.x;
    if (el >= NE) return;
    int g = (int)(el >> 15), e = (int)(el & (EE - 1));
    int tgt = eidx[((long)g * 2 + 1) * EE + e];
    int tf = g * NN + tgt;
    int pos = atomicAdd(&fill[tf], 1);
    csr[off[tf] + pos] = (int)el;
}

// =====================================================================
// Fused TransformerConv (R10 config: 256 threads, single-edge prefetch)
// on interleaved qkv [NM][768]. Writes conv output over the q slice.
// =====================================================================
__global__ __launch_bounds__(256) void conv_fused(
    unsigned short* __restrict__ Z,
    const int* __restrict__ eidx, const float* __restrict__ eattr,
    const float* __restrict__ W_edge, const float* __restrict__ b_edge,
    const int* __restrict__ off, const int* __restrict__ csr)
{
    const int tid = threadIdx.x;
    const int wave = tid >> 6, lane = tid & 63;
    const int bid = (blockIdx.x & 7) * (NM / 4 / 8) + (blockIdx.x >> 3);
    const long tf = (long)bid * 4 + wave;
    const int d0 = lane * 4;
    unsigned short* qrow = &Z[tf * 768];
    const ushort4 q4 = *(const ushort4*)&qrow[d0];
    const float q0 = b2f(q4.x), q1 = b2f(q4.y), q2 = b2f(q4.z), q3 = b2f(q4.w);
    const float be0 = b_edge[d0], be1 = b_edge[d0 + 1],
                be2 = b_edge[d0 + 2], be3 = b_edge[d0 + 3];
    float w0[6], w1r[6], w2r[6], w3r[6];
#pragma unroll
    for (int j2 = 0; j2 < 6; ++j2) {
        const float* wp = &W_edge[j2 * 256 + d0];
        w0[j2] = wp[0]; w1r[j2] = wp[1]; w2r[j2] = wp[2]; w3r[j2] = wp[3];
    }
    float qb = q0 * be0 + q1 * be1 + q2 * be2 + q3 * be3;
    float qw[6];
#pragma unroll
    for (int j2 = 0; j2 < 6; ++j2)
        qw[j2] = q0 * w0[j2] + q1 * w1r[j2] + q2 * w2r[j2] + q3 * w3r[j2];
#pragma unroll
    for (int mm = 1; mm <= 4; mm <<= 1) {
        qb += __shfl_xor(qb, mm, 64);
#pragma unroll
        for (int j2 = 0; j2 < 6; ++j2) qw[j2] += __shfl_xor(qw[j2], mm, 64);
    }
    const float scale = 0.17677669529663687f;  // 1/sqrt(32)
    float s = 0.f, a0 = 0.f, a1 = 0.f, a2 = 0.f, a3 = 0.f;
    float t0 = 0.f, t1 = 0.f, t2 = 0.f, t3 = 0.f, t4 = 0.f, t5 = 0.f;
    const int jb = off[tf], je = off[tf + 1];
    ushort4 kc, vc; float eac[6];
    if (jb < je) {
        const int el = csr[jb];
        const int g = el >> 15, e = el & (EE - 1);
        const long sf = (long)g * NN + eidx[((long)g * 2) * EE + e];
        kc = *(const ushort4*)&Z[sf * 768 + 256 + d0];
        vc = *(const ushort4*)&Z[sf * 768 + 512 + d0];
#pragma unroll
        for (int t = 0; t < 6; ++t) eac[t] = eattr[(long)el * 6 + t];
    }
    for (int j = jb; j < je; ++j) {
        ushort4 kn, vn; float ean[6];
        if (j + 1 < je) {  // prefetch next edge (wave-uniform branch)
            const int el = csr[j + 1];
            const int g = el >> 15, e = el & (EE - 1);
            const long sf = (long)g * NN + eidx[((long)g * 2) * EE + e];
            kn = *(const ushort4*)&Z[sf * 768 + 256 + d0];
            vn = *(const ushort4*)&Z[sf * 768 + 512 + d0];
#pragma unroll
            for (int t = 0; t < 6; ++t) ean[t] = eattr[(long)el * 6 + t];
        }
        float p = q0 * b2f(kc.x) + q1 * b2f(kc.y) + q2 * b2f(kc.z) + q3 * b2f(kc.w);
        p += __shfl_xor(p, 1, 64);
        p += __shfl_xor(p, 2, 64);
        p += __shfl_xor(p, 4, 64);
        float alpha = p + qb;
        alpha += eac[0] * qw[0] + eac[1] * qw[1] + eac[2] * qw[2]
               + eac[3] * qw[3] + eac[4] * qw[4] + eac[5] * qw[5];
        const float a = __expf(alpha * scale);
        s += a;
        a0 += a * b2f(vc.x); a1 += a * b2f(vc.y);
        a2 += a * b2f(vc.z); a3 += a * b2f(vc.w);
        t0 += a * eac[0]; t1 += a * eac[1]; t2 += a * eac[2];
        t3 += a * eac[3]; t4 += a * eac[4]; t5 += a * eac[5];
        kc = kn; vc = vn;
#pragma unroll
        for (int t = 0; t < 6; ++t) eac[t] = ean[t];
    }
    const float inv = (s > 0.f) ? 1.f / s : 0.f;
    float o0 = a0 + be0 * s, o1 = a1 + be1 * s, o2 = a2 + be2 * s, o3 = a3 + be3 * s;
    o0 += w0[0]*t0 + w0[1]*t1 + w0[2]*t2 + w0[3]*t3 + w0[4]*t4 + w0[5]*t5;
    o1 += w1r[0]*t0 + w1r[1]*t1 + w1r[2]*t2 + w1r[3]*t3 + w1r[4]*t4 + w1r[5]*t5;
    o2 += w2r[0]*t0 + w2r[1]*t1 + w2r[2]*t2 + w2r[3]*t3 + w2r[4]*t4 + w2r[5]*t5;
    o3 += w3r[0]*t0 + w3r[1]*t1 + w3r[2]*t2 + w3r[3]*t3 + w3r[4]*t4 + w3r[5]*t5;
    ushort4 o;
    o.x = f2b(o0 * inv); o.y = f2b(o1 * inv);
    o.z = f2b(o2 * inv); o.w = f2b(o3 * inv);
    *(ushort4*)&qrow[d0] = o;
}

// seq(bf16, [t*BN+b*N+n][256]) = conv(q-slice of Z) + skip(k-slice of Z)
__global__ void transpose_add(const unsigned short* __restrict__ Z,
                              unsigned short* __restrict__ out) {
    long gid = (long)blockIdx.x * blockDim.x + threadIdx.x;
    long row = gid >> 6;
    int c4 = (int)(gid & 63);
    int n = (int)(row % NN);
    int bt = (int)(row / NN);
    int t = bt % TT, b = bt / TT;
    long orow = (long)t * BN + (long)b * NN + n;
    ushort4 cv = ((const ushort4*)&Z[row * 768])[c4];
    ushort4 sv = ((const ushort4*)&Z[row * 768 + 256])[c4];
    ushort4 o;
    o.x = f2b(b2f(cv.x) + b2f(sv.x));
    o.y = f2b(b2f(cv.y) + b2f(sv.y));
    o.z = f2b(b2f(cv.z) + b2f(sv.z));
    o.w = f2b(b2f(cv.w) + b2f(sv.w));
    ((ushort4*)out)[orow * 64 + c4] = o;
}

// temporal attention over T=5 on interleaved qkv [NM][768]; o over q-slice.
__global__ __launch_bounds__(256) void mha_time(unsigned short* __restrict__ Z)
{
    const int tid = threadIdx.x;
    const int grp = tid >> 5, c = tid & 31;
    long pair = (long)blockIdx.x * 8 + grp;
    int h = (int)(pair & 7);
    long bn = pair >> 3;
    const float scale = 0.17677669529663687f;
    float qv[TT], kv[TT], vv[TT];
    long r[TT];
#pragma unroll
    for (int t = 0; t < TT; ++t) {
        r[t] = ((long)t * BN + bn) * 768 + h * 32 + c;
        qv[t] = b2f(Z[r[t]]); kv[t] = b2f(Z[r[t] + 256]); vv[t] = b2f(Z[r[t] + 512]);
    }
    float s[TT][TT];
#pragma unroll
    for (int t = 0; t < TT; ++t)
#pragma unroll
        for (int u = 0; u < TT; ++u) {
            float p = qv[t] * kv[u];
#pragma unroll
            for (int m = 16; m >= 1; m >>= 1) p += __shfl_xor(p, m, 64);
            s[t][u] = p * scale;
        }
#pragma unroll
    for (int t = 0; t < TT; ++t) {
        float mx = s[t][0];
#pragma unroll
        for (int u = 1; u < TT; ++u) mx = fmaxf(mx, s[t][u]);
        float sm = 0.f;
#pragma unroll
        for (int u = 0; u < TT; ++u) { s[t][u] = expf(s[t][u] - mx); sm += s[t][u]; }
        float inv = 1.f / sm;
        float o = 0.f;
#pragma unroll
        for (int u = 0; u < TT; ++u) o += s[t][u] * vv[u];
        Z[r[t]] = f2b(o * inv);
    }
}

// seq(bf16) = LayerNorm(seq + res(bf16, row-stride rstride)) * g + b
__global__ __launch_bounds__(256) void ln_residual(
    unsigned short* __restrict__ seq, const unsigned short* __restrict__ res,
    int rstride, const float* __restrict__ g, const float* __restrict__ b)
{
    const int wave = threadIdx.x >> 6, lane = threadIdx.x & 63;
    long row = (long)blockIdx.x * 4 + wave;
    const ushort4 s4 = *(const ushort4*)&seq[row * 256 + lane * 4];
    const ushort4 r4 = *(const ushort4*)&res[row * (long)rstride + lane * 4];
    float x[4] = { b2f(s4.x) + b2f(r4.x), b2f(s4.y) + b2f(r4.y),
                   b2f(s4.z) + b2f(r4.z), b2f(s4.w) + b2f(r4.w) };
    float sum = x[0] + x[1] + x[2] + x[3];
#pragma unroll
    for (int m = 32; m >= 1; m >>= 1) sum += __shfl_xor(sum, m, 64);
    float mean = sum * (1.f / 256.f);
    float vs = 0.f;
#pragma unroll
    for (int i = 0; i < 4; ++i) { float dl = x[i] - mean; vs += dl * dl; }
#pragma unroll
    for (int m = 32; m >= 1; m >>= 1) vs += __shfl_xor(vs, m, 64);
    float inv = rsqrtf(vs * (1.f / 256.f) + 1e-5f);
    ushort4 o;
    o.x = f2b((x[0] - mean) * inv * g[lane * 4 + 0] + b[lane * 4 + 0]);
    o.y = f2b((x[1] - mean) * inv * g[lane * 4 + 1] + b[lane * 4 + 1]);
    o.z = f2b((x[2] - mean) * inv * g[lane * 4 + 2] + b[lane * 4 + 2]);
    o.w = f2b((x[3] - mean) * inv * g[lane * 4 + 3] + b[lane * 4 + 3]);
    *(ushort4*)&seq[row * 256 + lane * 4] = o;
}

// out[row][0..9] = seq[t=T-1 rows](bf16) @ W_out + b_out ; one block per row
__global__ __launch_bounds__(256) void final_out(
    const unsigned short* __restrict__ seq, const float* __restrict__ Wd,
    const float* __restrict__ bd, float* __restrict__ out)
{
    __shared__ float xs[256];
    long row = blockIdx.x;
    xs[threadIdx.x] = b2f(seq[((long)(TT - 1) * BN + row) * 256 + threadIdx.x]);
    __syncthreads();
    const int wv = threadIdx.x >> 6, lane = threadIdx.x & 63;
    for (int o = wv; o < NCLS; o += 4) {
        float p = 0.f;
#pragma unroll
        for (int i = 0; i < 4; ++i) {
            int kk = lane + 64 * i;
            p += xs[kk] * Wd[kk * NCLS + o];
        }
#pragma unroll
        for (int m = 32; m >= 1; m >>= 1) p += __shfl_xor(p, m, 64);
        if (lane == 0) out[row * NCLS + o] = p + bd[o];
    }
}

__global__ void fill_sentinel(float* __restrict__ out, int n) {
    int gid = blockIdx.x * blockDim.x + threadIdx.x;
    if (gid < n) out[gid] = 1.0e6f;
}

// =====================================================================
extern "C" void kernel_launch(void* const* d_in, const int* in_sizes, int n_in,
                              void* d_out, int out_size, void* d_ws, size_t ws_size,
                              hipStream_t stream) {
    const float* xseq  = (const float*)d_in[0];
    const int*   eidx  = (const int*)d_in[1];
    const float* eattr = (const float*)d_in[2];
    const float* W_node = (const float*)d_in[3];
    const float* b_node = (const float*)d_in[4];
    const float* W_edge = (const float*)d_in[5];
    const float* b_edge = (const float*)d_in[6];
    const float* Wq = (const float*)d_in[7];  const float* bq = (const float*)d_in[8];
    const float* Wk = (const float*)d_in[9];  const float* bk = (const float*)d_in[10];
    const float* Wv = (const float*)d_in[11]; const float* bv = (const float*)d_in[12];
    const float* Ws = (const float*)d_in[13]; const float* bs = (const float*)d_in[14];
    const float* Wqkv = (const float*)d_in[15]; const float* bqkv = (const float*)d_in[16];
    const float* Wo = (const float*)d_in[17];   const float* bo = (const float*)d_in[18];
    const float* W1 = (const float*)d_in[19];   const float* b1 = (const float*)d_in[20];
    const float* W2 = (const float*)d_in[21];   const float* b2 = (const float*)d_in[22];
    const float* g_ln1 = (const float*)d_in[23]; const float* b_ln1 = (const float*)d_in[24];
    const float* g_ln2 = (const float*)d_in[25]; const float* b_ln2 = (const float*)d_in[26];
    const float* W_out = (const float*)d_in[27]; const float* b_out = (const float*)d_in[28];
    float* out = (float*)d_out;

    // ---- workspace layout ----
    const long SZ = (long)NM * DD;            // 20,971,520 elements
    unsigned short* Abf = (unsigned short*)d_ws;     // seq activations bf16 (40MB)
    unsigned short* Zu  = Abf + SZ;                  // qkv interleaved [NM][768] (120MB)
    unsigned short* Hid = Zu;                        // FFN hidden bf16 [MR][2048] (64MB)
    unsigned short* res2B = Zu + (long)MR * FFD;     // FFN residual bf16 [MR][256] (8MB)
    unsigned short* WX = Zu + 3 * SZ;
    unsigned short* xbf = WX;                             // 81920*64
    unsigned short* wtN = xbf + (long)NM * FIN;           // [256][64]
    unsigned short* wtQ = wtN + 256 * 64;                 // [768][256] stacked q,k,v
    unsigned short* wtK = wtQ + 65536;
    unsigned short* wtV = wtK + 65536;
    unsigned short* wtS = wtV + 65536;
    unsigned short* wtQKV = wtS + 65536;                  // 3 * [768][256]
    unsigned short* wtO = wtQKV + 3L * 768 * 256;         // 3 * [256][256]
    unsigned short* wtW1 = wtO + 3L * 65536;              // 3 * [2048][256]
    unsigned short* wtW2 = wtW1 + 3L * 2048 * 256;        // 3 * [256][2048]
    int* cnt  = (int*)(wtW2 + 3L * 256 * 2048);
    int* coff = cnt + NM;                                 // NM+1
    int* cfil = coff + NM + 1;
    int* csr  = cfil + NM;                                // NE ints
    float* qkvb = (float*)(csr + NE);                     // 768 packed bias
    char* wend = (char*)(qkvb + 768);
    const size_t need = (size_t)(wend - (char*)d_ws);
    if (ws_size < need) {
        fill_sentinel<<<dim3((out_size + 255) / 256), dim3(256), 0, stream>>>(out, out_size);
        return;
    }

    dim3 blk(256);
    dim3 tb(32, 8);

    // ---- prologue ----
    xconvert<<<dim3((unsigned)((long)NM * FIN / 4 / 256)), blk, 0, stream>>>(xseq, xbf, (long)NM * FIN / 4);
    wtrans<<<dim3(DD / 32, FIN / 32), tb, 0, stream>>>(W_node, wtN, FIN, DD);
    wtrans<<<dim3(DD / 32, DD / 32), tb, 0, stream>>>(Wq, wtQ, DD, DD);
    wtrans<<<dim3(DD / 32, DD / 32), tb, 0, stream>>>(Wk, wtK, DD, DD);
    wtrans<<<dim3(DD / 32, DD / 32), tb, 0, stream>>>(Wv, wtV, DD, DD);
    wtrans<<<dim3(DD / 32, DD / 32), tb, 0, stream>>>(Ws, wtS, DD, DD);
    pack3<<<dim3(1), blk, 0, stream>>>(bq, bk, bv, qkvb);
    for (int l = 0; l < 3; ++l) {
        wtrans<<<dim3(768 / 32, DD / 32), tb, 0, stream>>>(Wqkv + (long)l * DD * 768, wtQKV + (long)l * 768 * 256, DD, 768);
        wtrans<<<dim3(DD / 32, DD / 32), tb, 0, stream>>>(Wo + (long)l * DD * DD, wtO + (long)l * 65536, DD, DD);
        wtrans<<<dim3(FFD / 32, DD / 32), tb, 0, stream>>>(W1 + (long)l * DD * FFD, wtW1 + (long)l * 2048 * 256, DD, FFD);
        wtrans<<<dim3(DD / 32, FFD / 32), tb, 0, stream>>>(W2 + (long)l * FFD * DD, wtW2 + (long)l * 256 * 2048, FFD, DD);
    }

    // ---- CSR build ----
    csr_init<<<dim3((NM + 255) / 256), blk, 0, stream>>>(cnt, cfil);
    csr_count<<<dim3((unsigned)(NE / 256)), blk, 0, stream>>>(eidx, cnt);
    csr_scan<<<dim3(1), dim3(1024), 0, stream>>>(cnt, coff);
    csr_scatter<<<dim3((unsigned)(NE / 256)), blk, 0, stream>>>(eidx, coff, cfil, csr);

    // ---- stage 1 ----
    gemm_mfma<false, true, 4><<<dim3(NM / 128, DD / 128), blk, 0, stream>>>(
        xbf, FIN, wtN, b_node, Abf, DD, FIN);
    gemm_mfma<false, true, 4><<<dim3(NM / 128, 768 / 128), blk, 0, stream>>>(
        Abf, DD, wtQ, qkvb, Zu, 768, DD);
    conv_fused<<<dim3(NM / 4), blk, 0, stream>>>(
        Zu, eidx, eattr, W_edge, b_edge, coff, csr);
    gemm_mfma<false, true, 4><<<dim3(NM / 128, DD / 128), blk, 0, stream>>>(
        Abf, DD, wtS, bs, (void*)(Zu + 256), 768, DD);
    transpose_add<<<dim3(NM * 64 / 256), blk, 0, stream>>>(Zu, Abf);

    // ---- stage 2: 3 temporal transformer encoder layers ----
    for (int l = 0; l < 3; ++l) {
        gemm_mfma<false, true, 4><<<dim3(NM / 128, 768 / 128), blk, 0, stream>>>(
            Abf, DD, wtQKV + (long)l * 768 * 256, bqkv + (long)l * 768, Zu, 768, DD);
        mha_time<<<dim3(BN * HH / 8), blk, 0, stream>>>(Zu);
        gemm_mfma<false, true, 4><<<dim3(NM / 128, DD / 128), blk, 0, stream>>>(
            Zu, 768, wtO + (long)l * 65536, bo + (long)l * DD, (void*)(Zu + 512), 768, DD);
        ln_residual<<<dim3(NM / 4), blk, 0, stream>>>(
            Abf, Zu + 512, 768, g_ln1 + l * DD, b_ln1 + l * DD);
        // unfused FFN; W2 uses the 128x64 tile (512 blocks = 2/CU vs 256 = 1/CU)
        for (int mr = 0; mr < NM / MR; ++mr) {
            const long r0 = (long)mr * MR;
            gemm_mfma<true, true, 4><<<dim3(MR / 128, FFD / 128), blk, 0, stream>>>(
                Abf + r0 * DD, DD, wtW1 + (long)l * 2048 * 256, b1 + (long)l * FFD, Hid, FFD, DD);
            gemm_mfma<false, true, 2><<<dim3(MR / 128, DD / 64), blk, 0, stream>>>(
                Hid, FFD, wtW2 + (long)l * 256 * 2048, b2 + (long)l * DD, res2B, DD, FFD);
            ln_residual<<<dim3(MR / 4), blk, 0, stream>>>(
                Abf + r0 * DD, res2B, DD, g_ln2 + l * DD, b_ln2 + l * DD);
        }
    }

    // ---- output head ----
    final_out<<<dim3(BN), blk, 0, stream>>>(Abf, W_out, b_out, out);
}

// Round 15
// 2106.358 us; speedup vs baseline: 1.1899x; 1.0857x over previous
//
#include <hip/hip_runtime.h>
#include <math.h>

// ---- problem constants ----
#define BB   8
#define TT   5
#define NN   2048
#define FIN  64
#define EE   32768
#define DD   256
#define HH   8
#define FFD  2048
#define NCLS 10
#define GG   (BB*TT)        // 40 graphs
#define BN   (BB*NN)        // 16384
#define NM   (GG*NN)        // 81920 rows (= TT*BN)
#define NE   ((long)GG*EE)  // 1310720 edges

#define MR        16384           // rows per FFN chunk (5 chunks)

typedef __attribute__((ext_vector_type(8))) short short8;
typedef __attribute__((ext_vector_type(4))) float f32x4;

// ---- bf16 helpers (RNE) ----
__device__ __forceinline__ unsigned short f2b(float f) {
    unsigned u = __float_as_uint(f);
    u = (u + 0x7fffu + ((u >> 16) & 1u)) >> 16;
    return (unsigned short)u;
}
__device__ __forceinline__ float b2f(unsigned short b) {
    return __uint_as_float(((unsigned)b) << 16);
}

// async global->LDS, 16B per lane (dest must be wave-uniform base + lane*16)
__device__ __forceinline__ void gload_lds16(const void* g, void* l) {
    __builtin_amdgcn_global_load_lds(
        (__attribute__((address_space(1))) void*)g,
        (__attribute__((address_space(3))) void*)l, 16, 0, 0);
}

// =====================================================================
// Weight transpose+convert: in fp32 [K][N] row-major -> out bf16 [N][K]
// =====================================================================
__global__ void wtrans(const float* __restrict__ in, unsigned short* __restrict__ out,
                       int K, int N) {
    __shared__ float t[32][33];
    const int n0 = blockIdx.x * 32, k0 = blockIdx.y * 32;
    const int tx = threadIdx.x, ty = threadIdx.y;
    for (int i = ty; i < 32; i += 8) t[i][tx] = in[(long)(k0 + i) * N + n0 + tx];
    __syncthreads();
    for (int i = ty; i < 32; i += 8)
        out[(long)(n0 + i) * K + k0 + tx] = f2b(t[tx][i]);
}

// fp32 -> bf16 elementwise (n4 float4 groups)
__global__ void xconvert(const float* __restrict__ in, unsigned short* __restrict__ out, long n4) {
    long gid = (long)blockIdx.x * blockDim.x + threadIdx.x;
    if (gid >= n4) return;
    float4 v = ((const float4*)in)[gid];
    ushort4 o;
    o.x = f2b(v.x); o.y = f2b(v.y); o.z = f2b(v.z); o.w = f2b(v.w);
    ((ushort4*)out)[gid] = o;
}

// pack 3 bias vectors of 256 into one 768 buffer
__global__ void pack3(const float* __restrict__ a, const float* __restrict__ b,
                      const float* __restrict__ c, float* __restrict__ o) {
    int i = threadIdx.x;
    o[i] = a[i]; o[256 + i] = b[i]; o[512 + i] = c[i];
}

// =====================================================================
// bf16 MFMA GEMM, BK=64 + XOR-swizzled LDS (rule-21 compliant).
// C[M x N] = A[M x K] @ W[K x N] + bias. K % 64 == 0.
// Tile 128 x (32*NF): NF=4 -> 128x128 (default), NF=2 -> 128x64 (W2).
// 256 threads = 4 waves (2 x 2), 16x16x32 MFMA, XCD swizzle.
// =====================================================================
template <bool RELU, bool OUTBF, int NF>
__global__ __launch_bounds__(256) void gemm_mfma(
    const unsigned short* __restrict__ A, int lda,
    const unsigned short* __restrict__ WT,
    const float* __restrict__ bias,
    void* __restrict__ Cv, int ldc, int K)
{
    __shared__ unsigned short As[128 * 64];
    __shared__ unsigned short Bs[32 * NF * 64];
    const int tid = threadIdx.x;
    const int wid = tid >> 6, lane = tid & 63;
    const int wm = wid >> 1, wn = wid & 1;
    const int gx = gridDim.x, gy = gridDim.y;
    int bx = blockIdx.x, by = blockIdx.y;
    if ((gx & 7) == 0) {
        const int lbid = bx + gx * by;
        const int xcd = lbid & 7;
        const int i = lbid >> 3;
        const int CX = gx >> 3;
        bx = xcd * CX + i / gy;
        by = i - (i / gy) * gy;
    }
    const long row0 = (long)bx * 128;
    const long col0 = (long)by * (32 * NF);
    const int srow = tid >> 3;            // 0..31 (per pass)
    const int schunk = tid & 7;           // 16B chunk in 128B row
    const int fr = lane & 15;
    const int q = lane >> 4;
    f32x4 acc[4][NF] = {};
    for (int k0 = 0; k0 < K; k0 += 64) {
        __syncthreads();
#pragma unroll
        for (int p = 0; p < 4; ++p) {
            const int row = p * 32 + srow;
            const int sc = (schunk ^ (row & 7)) * 8;
            gload_lds16(&A[(row0 + row) * (long)lda + k0 + sc], As + row * 64 + schunk * 8);
        }
#pragma unroll
        for (int p = 0; p < NF; ++p) {
            const int row = p * 32 + srow;
            const int sc = (schunk ^ (row & 7)) * 8;
            gload_lds16(&WT[(col0 + row) * (long)K + k0 + sc], Bs + row * 64 + schunk * 8);
        }
        __syncthreads();
#pragma unroll
        for (int kk = 0; kk < 2; ++kk) {
            short8 af[4], bfr[NF];
#pragma unroll
            for (int mf = 0; mf < 4; ++mf) {
                const int row = wm * 64 + mf * 16 + fr;
                const int byo = (row * 128 + kk * 64 + q * 16) ^ ((row & 7) << 4);
                af[mf] = *(const short8*)((const char*)As + byo);
            }
#pragma unroll
            for (int nf = 0; nf < NF; ++nf) {
                const int row = wn * (NF * 16) + nf * 16 + fr;
                const int byo = (row * 128 + kk * 64 + q * 16) ^ ((row & 7) << 4);
                bfr[nf] = *(const short8*)((const char*)Bs + byo);
            }
#pragma unroll
            for (int mf = 0; mf < 4; ++mf)
#pragma unroll
                for (int nf = 0; nf < NF; ++nf)
                    acc[mf][nf] = __builtin_amdgcn_mfma_f32_16x16x32_bf16(
                        af[mf], bfr[nf], acc[mf][nf], 0, 0, 0);
        }
    }
#pragma unroll
    for (int nf = 0; nf < NF; ++nf) {
        const long col = col0 + wn * (NF * 16) + nf * 16 + fr;
        const float bv = bias[col];
#pragma unroll
        for (int mf = 0; mf < 4; ++mf) {
#pragma unroll
            for (int i = 0; i < 4; ++i) {
                const long r = row0 + wm * 64 + mf * 16 + q * 4 + i;
                float vv = acc[mf][nf][i] + bv;
                if (RELU) vv = fmaxf(vv, 0.f);
                if (OUTBF) ((unsigned short*)Cv)[r * ldc + col] = f2b(vv);
                else       ((float*)Cv)[r * ldc + col] = vv;
            }
        }
    }
}

// =====================================================================
// CSR build: edges grouped by global target row tf = g*NN + tgt
// =====================================================================
__global__ void csr_init(int* __restrict__ cnt, int* __restrict__ fill) {
    int gid = blockIdx.x * blockDim.x + threadIdx.x;
    if (gid < NM) { cnt[gid] = 0; fill[gid] = 0; }
}

__global__ void csr_count(const int* __restrict__ eidx, int* __restrict__ cnt) {
    long el = (long)blockIdx.x * blockDim.x + threadIdx.x;
    if (el >= NE) return;
    int g = (int)(el >> 15), e = (int)(el & (EE - 1));
    int tgt = eidx[((long)g * 2 + 1) * EE + e];
    atomicAdd(&cnt[g * NN + tgt], 1);
}

__global__ __launch_bounds__(1024) void csr_scan(const int* __restrict__ cnt, int* __restrict__ off) {
    __shared__ int part[1024];
    const int t = threadIdx.x;
    const int base = t * (NM / 1024);
    int s = 0;
    for (int i = 0; i < NM / 1024; ++i) s += cnt[base + i];
    part[t] = s;
    __syncthreads();
    for (int d = 1; d < 1024; d <<= 1) {
        int v = (t >= d) ? part[t - d] : 0;
        __syncthreads();
        part[t] += v;
        __syncthreads();
    }
    int run = (t == 0) ? 0 : part[t - 1];
    for (int i = 0; i < NM / 1024; ++i) { off[base + i] = run; run += cnt[base + i]; }
    if (t == 1023) off[NM] = run;
}

__global__ void csr_scatter(const int* __restrict__ eidx, const int* __restrict__ off,
                            int* __restrict__ fill, int* __restrict__ csr) {
    long el = (long)blockIdx.x * blockDim.x + threadIdx.x;
    if (el >= NE) return;
    int g = (int)(el >> 15), e = (int)(el & (EE - 1));
    int tgt = eidx[((long)g * 2 + 1) * EE + e];
    int tf = g * NN + tgt;
    int pos = atomicAdd(&fill[tf], 1);
    csr[off[tf] + pos] = (int)el;
}

// =====================================================================
// Fused TransformerConv (R10 config: 256 threads, single-edge prefetch)
// on interleaved qkv [NM][768]. Writes conv output over the q slice.
// =====================================================================
__global__ __launch_bounds__(256) void conv_fused(
    unsigned short* __restrict__ Z,
    const int* __restrict__ eidx, const float* __restrict__ eattr,
    const float* __restrict__ W_edge, const float* __restrict__ b_edge,
    const int* __restrict__ off, const int* __restrict__ csr)
{
    const int tid = threadIdx.x;
    const int wave = tid >> 6, lane = tid & 63;
    const int bid = (blockIdx.x & 7) * (NM / 4 / 8) + (blockIdx.x >> 3);
    const long tf = (long)bid * 4 + wave;
    const int d0 = lane * 4;
    unsigned short* qrow = &Z[tf * 768];
    const ushort4 q4 = *(const ushort4*)&qrow[d0];
    const float q0 = b2f(q4.x), q1 = b2f(q4.y), q2 = b2f(q4.z), q3 = b2f(q4.w);
    const float be0 = b_edge[d0], be1 = b_edge[d0 + 1],
                be2 = b_edge[d0 + 2], be3 = b_edge[d0 + 3];
    float w0[6], w1r[6], w2r[6], w3r[6];
#pragma unroll
    for (int j2 = 0; j2 < 6; ++j2) {
        const float* wp = &W_edge[j2 * 256 + d0];
        w0[j2] = wp[0]; w1r[j2] = wp[1]; w2r[j2] = wp[2]; w3r[j2] = wp[3];
    }
    float qb = q0 * be0 + q1 * be1 + q2 * be2 + q3 * be3;
    float qw[6];
#pragma unroll
    for (int j2 = 0; j2 < 6; ++j2)
        qw[j2] = q0 * w0[j2] + q1 * w1r[j2] + q2 * w2r[j2] + q3 * w3r[j2];
#pragma unroll
    for (int mm = 1; mm <= 4; mm <<= 1) {
        qb += __shfl_xor(qb, mm, 64);
#pragma unroll
        for (int j2 = 0; j2 < 6; ++j2) qw[j2] += __shfl_xor(qw[j2], mm, 64);
    }
    const float scale = 0.17677669529663687f;  // 1/sqrt(32)
    float s = 0.f, a0 = 0.f, a1 = 0.f, a2 = 0.f, a3 = 0.f;
    float t0 = 0.f, t1 = 0.f, t2 = 0.f, t3 = 0.f, t4 = 0.f, t5 = 0.f;
    const int jb = off[tf], je = off[tf + 1];
    ushort4 kc, vc; float eac[6];
    if (jb < je) {
        const int el = csr[jb];
        const int g = el >> 15, e = el & (EE - 1);
        const long sf = (long)g * NN + eidx[((long)g * 2) * EE + e];
        kc = *(const ushort4*)&Z[sf * 768 + 256 + d0];
        vc = *(const ushort4*)&Z[sf * 768 + 512 + d0];
#pragma unroll
        for (int t = 0; t < 6; ++t) eac[t] = eattr[(long)el * 6 + t];
    }
    for (int j = jb; j < je; ++j) {
        ushort4 kn, vn; float ean[6];
        if (j + 1 < je) {  // prefetch next edge (wave-uniform branch)
            const int el = csr[j + 1];
            const int g = el >> 15, e = el & (EE - 1);
            const long sf = (long)g * NN + eidx[((long)g * 2) * EE + e];
            kn = *(const ushort4*)&Z[sf * 768 + 256 + d0];
            vn = *(const ushort4*)&Z[sf * 768 + 512 + d0];
#pragma unroll
            for (int t = 0; t < 6; ++t) ean[t] = eattr[(long)el * 6 + t];
        }
        float p = q0 * b2f(kc.x) + q1 * b2f(kc.y) + q2 * b2f(kc.z) + q3 * b2f(kc.w);
        p += __shfl_xor(p, 1, 64);
        p += __shfl_xor(p, 2, 64);
        p += __shfl_xor(p, 4, 64);
        float alpha = p + qb;
        alpha += eac[0] * qw[0] + eac[1] * qw[1] + eac[2] * qw[2]
               + eac[3] * qw[3] + eac[4] * qw[4] + eac[5] * qw[5];
        const float a = __expf(alpha * scale);
        s += a;
        a0 += a * b2f(vc.x); a1 += a * b2f(vc.y);
        a2 += a * b2f(vc.z); a3 += a * b2f(vc.w);
        t0 += a * eac[0]; t1 += a * eac[1]; t2 += a * eac[2];
        t3 += a * eac[3]; t4 += a * eac[4]; t5 += a * eac[5];
        kc = kn; vc = vn;
#pragma unroll
        for (int t = 0; t < 6; ++t) eac[t] = ean[t];
    }
    const float inv = (s > 0.f) ? 1.f / s : 0.f;
    float o0 = a0 + be0 * s, o1 = a1 + be1 * s, o2 = a2 + be2 * s, o3 = a3 + be3 * s;
    o0 += w0[0]*t0 + w0[1]*t1 + w0[2]*t2 + w0[3]*t3 + w0[4]*t4 + w0[5]*t5;
    o1 += w1r[0]*t0 + w1r[1]*t1 + w1r[2]*t2 + w1r[3]*t3 + w1r[4]*t4 + w1r[5]*t5;
    o2 += w2r[0]*t0 + w2r[1]*t1 + w2r[2]*t2 + w2r[3]*t3 + w2r[4]*t4 + w2r[5]*t5;
    o3 += w3r[0]*t0 + w3r[1]*t1 + w3r[2]*t2 + w3r[3]*t3 + w3r[4]*t4 + w3r[5]*t5;
    ushort4 o;
    o.x = f2b(o0 * inv); o.y = f2b(o1 * inv);
    o.z = f2b(o2 * inv); o.w = f2b(o3 * inv);
    *(ushort4*)&qrow[d0] = o;
}

// seq(bf16, [t*BN+b*N+n][256]) = conv(q-slice of Z) + skip(k-slice of Z)
__global__ void transpose_add(const unsigned short* __restrict__ Z,
                              unsigned short* __restrict__ out) {
    long gid = (long)blockIdx.x * blockDim.x + threadIdx.x;
    long row = gid >> 6;
    int c4 = (int)(gid & 63);
    int n = (int)(row % NN);
    int bt = (int)(row / NN);
    int t = bt % TT, b = bt / TT;
    long orow = (long)t * BN + (long)b * NN + n;
    ushort4 cv = ((const ushort4*)&Z[row * 768])[c4];
    ushort4 sv = ((const ushort4*)&Z[row * 768 + 256])[c4];
    ushort4 o;
    o.x = f2b(b2f(cv.x) + b2f(sv.x));
    o.y = f2b(b2f(cv.y) + b2f(sv.y));
    o.z = f2b(b2f(cv.z) + b2f(sv.z));
    o.w = f2b(b2f(cv.w) + b2f(sv.w));
    ((ushort4*)out)[orow * 64 + c4] = o;
}

// =====================================================================
// temporal attention v2: one 64-lane wave per node bn; lane owns dims
// d0=lane*4 (head = lane>>3; 8-lane group = one 32-dim head). ushort4
// loads (8B/lane, coalesced), 3-shfl head reduction. o over q-slice.
// =====================================================================
__global__ __launch_bounds__(256) void mha_time(unsigned short* __restrict__ Z)
{
    const int tid = threadIdx.x;
    const int wave = tid >> 6, lane = tid & 63;
    const long bn = (long)blockIdx.x * 4 + wave;
    const int d0 = lane * 4;
    const float scale = 0.17677669529663687f;
    float qv[TT][4], kv[TT][4], vv[TT][4];
    long r[TT];
#pragma unroll
    for (int t = 0; t < TT; ++t) {
        r[t] = ((long)t * BN + bn) * 768 + d0;
        const ushort4 qq = *(const ushort4*)&Z[r[t]];
        const ushort4 kk = *(const ushort4*)&Z[r[t] + 256];
        const ushort4 vx = *(const ushort4*)&Z[r[t] + 512];
        qv[t][0] = b2f(qq.x); qv[t][1] = b2f(qq.y); qv[t][2] = b2f(qq.z); qv[t][3] = b2f(qq.w);
        kv[t][0] = b2f(kk.x); kv[t][1] = b2f(kk.y); kv[t][2] = b2f(kk.z); kv[t][3] = b2f(kk.w);
        vv[t][0] = b2f(vx.x); vv[t][1] = b2f(vx.y); vv[t][2] = b2f(vx.z); vv[t][3] = b2f(vx.w);
    }
    float s[TT][TT];
#pragma unroll
    for (int t = 0; t < TT; ++t)
#pragma unroll
        for (int u = 0; u < TT; ++u) {
            float p = qv[t][0] * kv[u][0] + qv[t][1] * kv[u][1]
                    + qv[t][2] * kv[u][2] + qv[t][3] * kv[u][3];
            p += __shfl_xor(p, 1, 64);
            p += __shfl_xor(p, 2, 64);
            p += __shfl_xor(p, 4, 64);   // 8-lane group = one head
            s[t][u] = p * scale;
        }
#pragma unroll
    for (int t = 0; t < TT; ++t) {
        float mx = s[t][0];
#pragma unroll
        for (int u = 1; u < TT; ++u) mx = fmaxf(mx, s[t][u]);
        float sm = 0.f;
#pragma unroll
        for (int u = 0; u < TT; ++u) { s[t][u] = __expf(s[t][u] - mx); sm += s[t][u]; }
        const float inv = 1.f / sm;
        float o0 = 0.f, o1 = 0.f, o2 = 0.f, o3 = 0.f;
#pragma unroll
        for (int u = 0; u < TT; ++u) {
            o0 += s[t][u] * vv[u][0]; o1 += s[t][u] * vv[u][1];
            o2 += s[t][u] * vv[u][2]; o3 += s[t][u] * vv[u][3];
        }
        ushort4 o;
        o.x = f2b(o0 * inv); o.y = f2b(o1 * inv);
        o.z = f2b(o2 * inv); o.w = f2b(o3 * inv);
        *(ushort4*)&Z[r[t]] = o;
    }
}

// seq(bf16) = LayerNorm(seq + res(bf16, row-stride rstride)) * g + b
__global__ __launch_bounds__(256) void ln_residual(
    unsigned short* __restrict__ seq, const unsigned short* __restrict__ res,
    int rstride, const float* __restrict__ g, const float* __restrict__ b)
{
    const int wave = threadIdx.x >> 6, lane = threadIdx.x & 63;
    long row = (long)blockIdx.x * 4 + wave;
    const ushort4 s4 = *(const ushort4*)&seq[row * 256 + lane * 4];
    const ushort4 r4 = *(const ushort4*)&res[row * (long)rstride + lane * 4];
    float x[4] = { b2f(s4.x) + b2f(r4.x), b2f(s4.y) + b2f(r4.y),
                   b2f(s4.z) + b2f(r4.z), b2f(s4.w) + b2f(r4.w) };
    float sum = x[0] + x[1] + x[2] + x[3];
#pragma unroll
    for (int m = 32; m >= 1; m >>= 1) sum += __shfl_xor(sum, m, 64);
    float mean = sum * (1.f / 256.f);
    float vs = 0.f;
#pragma unroll
    for (int i = 0; i < 4; ++i) { float dl = x[i] - mean; vs += dl * dl; }
#pragma unroll
    for (int m = 32; m >= 1; m >>= 1) vs += __shfl_xor(vs, m, 64);
    float inv = rsqrtf(vs * (1.f / 256.f) + 1e-5f);
    ushort4 o;
    o.x = f2b((x[0] - mean) * inv * g[lane * 4 + 0] + b[lane * 4 + 0]);
    o.y = f2b((x[1] - mean) * inv * g[lane * 4 + 1] + b[lane * 4 + 1]);
    o.z = f2b((x[2] - mean) * inv * g[lane * 4 + 2] + b[lane * 4 + 2]);
    o.w = f2b((x[3] - mean) * inv * g[lane * 4 + 3] + b[lane * 4 + 3]);
    *(ushort4*)&seq[row * 256 + lane * 4] = o;
}

// out[row][0..9] = seq[t=T-1 rows](bf16) @ W_out + b_out ; one block per row
__global__ __launch_bounds__(256) void final_out(
    const unsigned short* __restrict__ seq, const float* __restrict__ Wd,
    const float* __restrict__ bd, float* __restrict__ out)
{
    __shared__ float xs[256];
    long row = blockIdx.x;
    xs[threadIdx.x] = b2f(seq[((long)(TT - 1) * BN + row) * 256 + threadIdx.x]);
    __syncthreads();
    const int wv = threadIdx.x >> 6, lane = threadIdx.x & 63;
    for (int o = wv; o < NCLS; o += 4) {
        float p = 0.f;
#pragma unroll
        for (int i = 0; i < 4; ++i) {
            int kk = lane + 64 * i;
            p += xs[kk] * Wd[kk * NCLS + o];
        }
#pragma unroll
        for (int m = 32; m >= 1; m >>= 1) p += __shfl_xor(p, m, 64);
        if (lane == 0) out[row * NCLS + o] = p + bd[o];
    }
}

__global__ void fill_sentinel(float* __restrict__ out, int n) {
    int gid = blockIdx.x * blockDim.x + threadIdx.x;
    if (gid < n) out[gid] = 1.0e6f;
}

// =====================================================================
extern "C" void kernel_launch(void* const* d_in, const int* in_sizes, int n_in,
                              void* d_out, int out_size, void* d_ws, size_t ws_size,
                              hipStream_t stream) {
    const float* xseq  = (const float*)d_in[0];
    const int*   eidx  = (const int*)d_in[1];
    const float* eattr = (const float*)d_in[2];
    const float* W_node = (const float*)d_in[3];
    const float* b_node = (const float*)d_in[4];
    const float* W_edge = (const float*)d_in[5];
    const float* b_edge = (const float*)d_in[6];
    const float* Wq = (const float*)d_in[7];  const float* bq = (const float*)d_in[8];
    const float* Wk = (const float*)d_in[9];  const float* bk = (const float*)d_in[10];
    const float* Wv = (const float*)d_in[11]; const float* bv = (const float*)d_in[12];
    const float* Ws = (const float*)d_in[13]; const float* bs = (const float*)d_in[14];
    const float* Wqkv = (const float*)d_in[15]; const float* bqkv = (const float*)d_in[16];
    const float* Wo = (const float*)d_in[17];   const float* bo = (const float*)d_in[18];
    const float* W1 = (const float*)d_in[19];   const float* b1 = (const float*)d_in[20];
    const float* W2 = (const float*)d_in[21];   const float* b2 = (const float*)d_in[22];
    const float* g_ln1 = (const float*)d_in[23]; const float* b_ln1 = (const float*)d_in[24];
    const float* g_ln2 = (const float*)d_in[25]; const float* b_ln2 = (const float*)d_in[26];
    const float* W_out = (const float*)d_in[27]; const float* b_out = (const float*)d_in[28];
    float* out = (float*)d_out;

    // ---- workspace layout ----
    const long SZ = (long)NM * DD;            // 20,971,520 elements
    unsigned short* Abf = (unsigned short*)d_ws;     // seq activations bf16 (40MB)
    unsigned short* Zu  = Abf + SZ;                  // qkv interleaved [NM][768] (120MB)
    unsigned short* Hid = Zu;                        // FFN hidden bf16 [MR][2048] (64MB)
    unsigned short* res2B = Zu + (long)MR * FFD;     // FFN residual bf16 [MR][256] (8MB)
    unsigned short* WX = Zu + 3 * SZ;
    unsigned short* xbf = WX;                             // 81920*64
    unsigned short* wtN = xbf + (long)NM * FIN;           // [256][64]
    unsigned short* wtQ = wtN + 256 * 64;                 // [768][256] stacked q,k,v
    unsigned short* wtK = wtQ + 65536;
    unsigned short* wtV = wtK + 65536;
    unsigned short* wtS = wtV + 65536;
    unsigned short* wtQKV = wtS + 65536;                  // 3 * [768][256]
    unsigned short* wtO = wtQKV + 3L * 768 * 256;         // 3 * [256][256]
    unsigned short* wtW1 = wtO + 3L * 65536;              // 3 * [2048][256]
    unsigned short* wtW2 = wtW1 + 3L * 2048 * 256;        // 3 * [256][2048]
    int* cnt  = (int*)(wtW2 + 3L * 256 * 2048);
    int* coff = cnt + NM;                                 // NM+1
    int* cfil = coff + NM + 1;
    int* csr  = cfil + NM;                                // NE ints
    float* qkvb = (float*)(csr + NE);                     // 768 packed bias
    char* wend = (char*)(qkvb + 768);
    const size_t need = (size_t)(wend - (char*)d_ws);
    if (ws_size < need) {
        fill_sentinel<<<dim3((out_size + 255) / 256), dim3(256), 0, stream>>>(out, out_size);
        return;
    }

    dim3 blk(256);
    dim3 tb(32, 8);

    // ---- prologue ----
    xconvert<<<dim3((unsigned)((long)NM * FIN / 4 / 256)), blk, 0, stream>>>(xseq, xbf, (long)NM * FIN / 4);
    wtrans<<<dim3(DD / 32, FIN / 32), tb, 0, stream>>>(W_node, wtN, FIN, DD);
    wtrans<<<dim3(DD / 32, DD / 32), tb, 0, stream>>>(Wq, wtQ, DD, DD);
    wtrans<<<dim3(DD / 32, DD / 32), tb, 0, stream>>>(Wk, wtK, DD, DD);
    wtrans<<<dim3(DD / 32, DD / 32), tb, 0, stream>>>(Wv, wtV, DD, DD);
    wtrans<<<dim3(DD / 32, DD / 32), tb, 0, stream>>>(Ws, wtS, DD, DD);
    pack3<<<dim3(1), blk, 0, stream>>>(bq, bk, bv, qkvb);
    for (int l = 0; l < 3; ++l) {
        wtrans<<<dim3(768 / 32, DD / 32), tb, 0, stream>>>(Wqkv + (long)l * DD * 768, wtQKV + (long)l * 768 * 256, DD, 768);
        wtrans<<<dim3(DD / 32, DD / 32), tb, 0, stream>>>(Wo + (long)l * DD * DD, wtO + (long)l * 65536, DD, DD);
        wtrans<<<dim3(FFD / 32, DD / 32), tb, 0, stream>>>(W1 + (long)l * DD * FFD, wtW1 + (long)l * 2048 * 256, DD, FFD);
        wtrans<<<dim3(DD / 32, FFD / 32), tb, 0, stream>>>(W2 + (long)l * FFD * DD, wtW2 + (long)l * 256 * 2048, FFD, DD);
    }

    // ---- CSR build ----
    csr_init<<<dim3((NM + 255) / 256), blk, 0, stream>>>(cnt, cfil);
    csr_count<<<dim3((unsigned)(NE / 256)), blk, 0, stream>>>(eidx, cnt);
    csr_scan<<<dim3(1), dim3(1024), 0, stream>>>(cnt, coff);
    csr_scatter<<<dim3((unsigned)(NE / 256)), blk, 0, stream>>>(eidx, coff, cfil, csr);

    // ---- stage 1 ----
    gemm_mfma<false, true, 4><<<dim3(NM / 128, DD / 128), blk, 0, stream>>>(
        xbf, FIN, wtN, b_node, Abf, DD, FIN);
    gemm_mfma<false, true, 4><<<dim3(NM / 128, 768 / 128), blk, 0, stream>>>(
        Abf, DD, wtQ, qkvb, Zu, 768, DD);
    conv_fused<<<dim3(NM / 4), blk, 0, stream>>>(
        Zu, eidx, eattr, W_edge, b_edge, coff, csr);
    gemm_mfma<false, true, 4><<<dim3(NM / 128, DD / 128), blk, 0, stream>>>(
        Abf, DD, wtS, bs, (void*)(Zu + 256), 768, DD);
    transpose_add<<<dim3(NM * 64 / 256), blk, 0, stream>>>(Zu, Abf);

    // ---- stage 2: 3 temporal transformer encoder layers ----
    for (int l = 0; l < 3; ++l) {
        gemm_mfma<false, true, 4><<<dim3(NM / 128, 768 / 128), blk, 0, stream>>>(
            Abf, DD, wtQKV + (long)l * 768 * 256, bqkv + (long)l * 768, Zu, 768, DD);
        mha_time<<<dim3(BN / 4), blk, 0, stream>>>(Zu);
        gemm_mfma<false, true, 4><<<dim3(NM / 128, DD / 128), blk, 0, stream>>>(
            Zu, 768, wtO + (long)l * 65536, bo + (long)l * DD, (void*)(Zu + 512), 768, DD);
        ln_residual<<<dim3(NM / 4), blk, 0, stream>>>(
            Abf, Zu + 512, 768, g_ln1 + l * DD, b_ln1 + l * DD);
        // unfused FFN; W2 uses the 128x64 tile (512 blocks = 2/CU)
        for (int mr = 0; mr < NM / MR; ++mr) {
            const long r0 = (long)mr * MR;
            gemm_mfma<true, true, 4><<<dim3(MR / 128, FFD / 128), blk, 0, stream>>>(
                Abf + r0 * DD, DD, wtW1 + (long)l * 2048 * 256, b1 + (long)l * FFD, Hid, FFD, DD);
            gemm_mfma<false, true, 2><<<dim3(MR / 128, DD / 64), blk, 0, stream>>>(
                Hid, FFD, wtW2 + (long)l * 256 * 2048, b2 + (long)l * DD, res2B, DD, FFD);
            ln_residual<<<dim3(MR / 4), blk, 0, stream>>>(
                Abf + r0 * DD, res2B, DD, g_ln2 + l * DD, b_ln2 + l * DD);
        }
    }

    // ---- output head ----
    final_out<<<dim3(BN), blk, 0, stream>>>(Abf, W_out, b_out, out);
}

// Round 16
// 1959.142 us; speedup vs baseline: 1.2793x; 1.0751x over previous
//
#include <hip/hip_runtime.h>
#include <math.h>

// ---- problem constants ----
#define BB   8
#define TT   5
#define NN   2048
#define FIN  64
#define EE   32768
#define DD   256
#define HH   8
#define FFD  2048
#define NCLS 10
#define GG   (BB*TT)        // 40 graphs
#define BN   (BB*NN)        // 16384
#define NM   (GG*NN)        // 81920 rows (= TT*BN)
#define NE   ((long)GG*EE)  // 1310720 edges

#define MR        20480           // rows per FFN chunk (4 chunks)

typedef __attribute__((ext_vector_type(8))) short short8;
typedef __attribute__((ext_vector_type(4))) float f32x4;

// ---- bf16 helpers (RNE) ----
__device__ __forceinline__ unsigned short f2b(float f) {
    unsigned u = __float_as_uint(f);
    u = (u + 0x7fffu + ((u >> 16) & 1u)) >> 16;
    return (unsigned short)u;
}
__device__ __forceinline__ float b2f(unsigned short b) {
    return __uint_as_float(((unsigned)b) << 16);
}

// async global->LDS, 16B per lane (dest must be wave-uniform base + lane*16)
__device__ __forceinline__ void gload_lds16(const void* g, void* l) {
    __builtin_amdgcn_global_load_lds(
        (__attribute__((address_space(1))) void*)g,
        (__attribute__((address_space(3))) void*)l, 16, 0, 0);
}

// =====================================================================
// Weight transpose+convert: fp32 [K][N] -> bf16 [N][K]
// =====================================================================
__device__ __forceinline__ void wtrans_body(const float* in, unsigned short* out,
                                            int K, int N, int bx, int by) {
    __shared__ float t[32][33];
    const int n0 = bx * 32, k0 = by * 32;
    const int tx = threadIdx.x, ty = threadIdx.y;
    for (int i = ty; i < 32; i += 8) t[i][tx] = in[(long)(k0 + i) * N + n0 + tx];
    __syncthreads();
    for (int i = ty; i < 32; i += 8)
        out[(long)(n0 + i) * K + k0 + tx] = f2b(t[tx][i]);
}

__global__ void wtrans(const float* __restrict__ in, unsigned short* __restrict__ out,
                       int K, int N) {
    wtrans_body(in, out, K, N, blockIdx.x, blockIdx.y);
}

// 4 same-shape [256][256] matrices, z selects
__global__ void wtrans4(const float* __restrict__ a, const float* __restrict__ b,
                        const float* __restrict__ c, const float* __restrict__ d,
                        unsigned short* __restrict__ out) {
    const float* src = (blockIdx.z == 0) ? a : (blockIdx.z == 1) ? b
                     : (blockIdx.z == 2) ? c : d;
    wtrans_body(src, out + (long)blockIdx.z * 65536, DD, DD, blockIdx.x, blockIdx.y);
}

// layer-strided: z = layer
__global__ void wtrans_s(const float* __restrict__ in, long sstride,
                         unsigned short* __restrict__ out, long dstride,
                         int K, int N) {
    wtrans_body(in + (long)blockIdx.z * sstride, out + (long)blockIdx.z * dstride,
                K, N, blockIdx.x, blockIdx.y);
}

// fp32 -> bf16 elementwise (n4 float4 groups)
__global__ void xconvert(const float* __restrict__ in, unsigned short* __restrict__ out, long n4) {
    long gid = (long)blockIdx.x * blockDim.x + threadIdx.x;
    if (gid >= n4) return;
    float4 v = ((const float4*)in)[gid];
    ushort4 o;
    o.x = f2b(v.x); o.y = f2b(v.y); o.z = f2b(v.z); o.w = f2b(v.w);
    ((ushort4*)out)[gid] = o;
}

// pack 3 bias vectors of 256 into one 768 buffer
__global__ void pack3(const float* __restrict__ a, const float* __restrict__ b,
                      const float* __restrict__ c, float* __restrict__ o) {
    int i = threadIdx.x;
    o[i] = a[i]; o[256 + i] = b[i]; o[512 + i] = c[i];
}

// =====================================================================
// bf16 MFMA GEMM, BK=64 + XOR-swizzled LDS (rule-21 compliant).
// Tile 128 x (32*NF): NF=4 default, NF=2 for W2 (2 blocks/CU).
// =====================================================================
template <bool RELU, bool OUTBF, int NF>
__global__ __launch_bounds__(256) void gemm_mfma(
    const unsigned short* __restrict__ A, int lda,
    const unsigned short* __restrict__ WT,
    const float* __restrict__ bias,
    void* __restrict__ Cv, int ldc, int K)
{
    __shared__ unsigned short As[128 * 64];
    __shared__ unsigned short Bs[32 * NF * 64];
    const int tid = threadIdx.x;
    const int wid = tid >> 6, lane = tid & 63;
    const int wm = wid >> 1, wn = wid & 1;
    const int gx = gridDim.x, gy = gridDim.y;
    int bx = blockIdx.x, by = blockIdx.y;
    if ((gx & 7) == 0) {
        const int lbid = bx + gx * by;
        const int xcd = lbid & 7;
        const int i = lbid >> 3;
        const int CX = gx >> 3;
        bx = xcd * CX + i / gy;
        by = i - (i / gy) * gy;
    }
    const long row0 = (long)bx * 128;
    const long col0 = (long)by * (32 * NF);
    const int srow = tid >> 3;            // 0..31 (per pass)
    const int schunk = tid & 7;           // 16B chunk in 128B row
    const int fr = lane & 15;
    const int q = lane >> 4;
    f32x4 acc[4][NF] = {};
    for (int k0 = 0; k0 < K; k0 += 64) {
        __syncthreads();
#pragma unroll
        for (int p = 0; p < 4; ++p) {
            const int row = p * 32 + srow;
            const int sc = (schunk ^ (row & 7)) * 8;
            gload_lds16(&A[(row0 + row) * (long)lda + k0 + sc], As + row * 64 + schunk * 8);
        }
#pragma unroll
        for (int p = 0; p < NF; ++p) {
            const int row = p * 32 + srow;
            const int sc = (schunk ^ (row & 7)) * 8;
            gload_lds16(&WT[(col0 + row) * (long)K + k0 + sc], Bs + row * 64 + schunk * 8);
        }
        __syncthreads();
#pragma unroll
        for (int kk = 0; kk < 2; ++kk) {
            short8 af[4], bfr[NF];
#pragma unroll
            for (int mf = 0; mf < 4; ++mf) {
                const int row = wm * 64 + mf * 16 + fr;
                const int byo = (row * 128 + kk * 64 + q * 16) ^ ((row & 7) << 4);
                af[mf] = *(const short8*)((const char*)As + byo);
            }
#pragma unroll
            for (int nf = 0; nf < NF; ++nf) {
                const int row = wn * (NF * 16) + nf * 16 + fr;
                const int byo = (row * 128 + kk * 64 + q * 16) ^ ((row & 7) << 4);
                bfr[nf] = *(const short8*)((const char*)Bs + byo);
            }
#pragma unroll
            for (int mf = 0; mf < 4; ++mf)
#pragma unroll
                for (int nf = 0; nf < NF; ++nf)
                    acc[mf][nf] = __builtin_amdgcn_mfma_f32_16x16x32_bf16(
                        af[mf], bfr[nf], acc[mf][nf], 0, 0, 0);
        }
    }
#pragma unroll
    for (int nf = 0; nf < NF; ++nf) {
        const long col = col0 + wn * (NF * 16) + nf * 16 + fr;
        const float bv = bias[col];
#pragma unroll
        for (int mf = 0; mf < 4; ++mf) {
#pragma unroll
            for (int i = 0; i < 4; ++i) {
                const long r = row0 + wm * 64 + mf * 16 + q * 4 + i;
                float vv = acc[mf][nf][i] + bv;
                if (RELU) vv = fmaxf(vv, 0.f);
                if (OUTBF) ((unsigned short*)Cv)[r * ldc + col] = f2b(vv);
                else       ((float*)Cv)[r * ldc + col] = vv;
            }
        }
    }
}

// =====================================================================
// CSR build. pcsr entry packs (srcrow << 15) | e  (17+15 = 32 bits):
// srcrow = g*NN+src < 81920 (17b), e < 32768 (15b). Removes the eidx
// hop from conv's gather chain; el = (srcrow>>11)*EE + e for eattr.
// =====================================================================
__global__ void csr_init(int* __restrict__ cnt, int* __restrict__ fill) {
    int gid = blockIdx.x * blockDim.x + threadIdx.x;
    if (gid < NM) { cnt[gid] = 0; fill[gid] = 0; }
}

__global__ void csr_count(const int* __restrict__ eidx, int* __restrict__ cnt) {
    long el = (long)blockIdx.x * blockDim.x + threadIdx.x;
    if (el >= NE) return;
    int g = (int)(el >> 15), e = (int)(el & (EE - 1));
    int tgt = eidx[((long)g * 2 + 1) * EE + e];
    atomicAdd(&cnt[g * NN + tgt], 1);
}

__global__ __launch_bounds__(1024) void csr_scan(const int* __restrict__ cnt, int* __restrict__ off) {
    __shared__ int part[1024];
    const int t = threadIdx.x;
    const int base = t * (NM / 1024);
    int s = 0;
    for (int i = 0; i < NM / 1024; ++i) s += cnt[base + i];
    part[t] = s;
    __syncthreads();
    for (int d = 1; d < 1024; d <<= 1) {
        int v = (t >= d) ? part[t - d] : 0;
        __syncthreads();
        part[t] += v;
        __syncthreads();
    }
    int run = (t == 0) ? 0 : part[t - 1];
    for (int i = 0; i < NM / 1024; ++i) { off[base + i] = run; run += cnt[base + i]; }
    if (t == 1023) off[NM] = run;
}

__global__ void csr_scatter(const int* __restrict__ eidx, const int* __restrict__ off,
                            int* __restrict__ fill, unsigned* __restrict__ pcsr) {
    long el = (long)blockIdx.x * blockDim.x + threadIdx.x;
    if (el >= NE) return;
    int g = (int)(el >> 15), e = (int)(el & (EE - 1));
    int src = eidx[((long)g * 2 + 0) * EE + e];
    int tgt = eidx[((long)g * 2 + 1) * EE + e];
    int tf = g * NN + tgt;
    int pos = atomicAdd(&fill[tf], 1);
    pcsr[off[tf] + pos] = ((unsigned)(g * NN + src) << 15) | (unsigned)e;
}

// =====================================================================
// Fused TransformerConv on interleaved qkv [NM][768]; packed CSR records
// (2-level gather chain: pcsr[j] -> {k, v, eattr} all parallel).
// =====================================================================
__global__ __launch_bounds__(256) void conv_fused(
    unsigned short* __restrict__ Z,
    const float* __restrict__ eattr,
    const float* __restrict__ W_edge, const float* __restrict__ b_edge,
    const int* __restrict__ off, const unsigned* __restrict__ pcsr)
{
    const int tid = threadIdx.x;
    const int wave = tid >> 6, lane = tid & 63;
    const int bid = (blockIdx.x & 7) * (NM / 4 / 8) + (blockIdx.x >> 3);
    const long tf = (long)bid * 4 + wave;
    const int d0 = lane * 4;
    unsigned short* qrow = &Z[tf * 768];
    const ushort4 q4 = *(const ushort4*)&qrow[d0];
    const float q0 = b2f(q4.x), q1 = b2f(q4.y), q2 = b2f(q4.z), q3 = b2f(q4.w);
    const float be0 = b_edge[d0], be1 = b_edge[d0 + 1],
                be2 = b_edge[d0 + 2], be3 = b_edge[d0 + 3];
    float w0[6], w1r[6], w2r[6], w3r[6];
#pragma unroll
    for (int j2 = 0; j2 < 6; ++j2) {
        const float* wp = &W_edge[j2 * 256 + d0];
        w0[j2] = wp[0]; w1r[j2] = wp[1]; w2r[j2] = wp[2]; w3r[j2] = wp[3];
    }
    float qb = q0 * be0 + q1 * be1 + q2 * be2 + q3 * be3;
    float qw[6];
#pragma unroll
    for (int j2 = 0; j2 < 6; ++j2)
        qw[j2] = q0 * w0[j2] + q1 * w1r[j2] + q2 * w2r[j2] + q3 * w3r[j2];
#pragma unroll
    for (int mm = 1; mm <= 4; mm <<= 1) {
        qb += __shfl_xor(qb, mm, 64);
#pragma unroll
        for (int j2 = 0; j2 < 6; ++j2) qw[j2] += __shfl_xor(qw[j2], mm, 64);
    }
    const float scale = 0.17677669529663687f;  // 1/sqrt(32)
    float s = 0.f, a0 = 0.f, a1 = 0.f, a2 = 0.f, a3 = 0.f;
    float t0 = 0.f, t1 = 0.f, t2 = 0.f, t3 = 0.f, t4 = 0.f, t5 = 0.f;
    const int jb = off[tf], je = off[tf + 1];
    ushort4 kc, vc; float eac[6];
    if (jb < je) {
        const unsigned pk = pcsr[jb];
        const long sf = pk >> 15;
        kc = *(const ushort4*)&Z[sf * 768 + 256 + d0];
        vc = *(const ushort4*)&Z[sf * 768 + 512 + d0];
        const long el = (sf >> 11) * EE + (pk & 32767u);
#pragma unroll
        for (int t = 0; t < 6; ++t) eac[t] = eattr[el * 6 + t];
    }
    for (int j = jb; j < je; ++j) {
        ushort4 kn, vn; float ean[6];
        if (j + 1 < je) {  // prefetch next edge (wave-uniform branch)
            const unsigned pk = pcsr[j + 1];
            const long sf = pk >> 15;
            kn = *(const ushort4*)&Z[sf * 768 + 256 + d0];
            vn = *(const ushort4*)&Z[sf * 768 + 512 + d0];
            const long el = (sf >> 11) * EE + (pk & 32767u);
#pragma unroll
            for (int t = 0; t < 6; ++t) ean[t] = eattr[el * 6 + t];
        }
        float p = q0 * b2f(kc.x) + q1 * b2f(kc.y) + q2 * b2f(kc.z) + q3 * b2f(kc.w);
        p += __shfl_xor(p, 1, 64);
        p += __shfl_xor(p, 2, 64);
        p += __shfl_xor(p, 4, 64);
        float alpha = p + qb;
        alpha += eac[0] * qw[0] + eac[1] * qw[1] + eac[2] * qw[2]
               + eac[3] * qw[3] + eac[4] * qw[4] + eac[5] * qw[5];
        const float a = __expf(alpha * scale);
        s += a;
        a0 += a * b2f(vc.x); a1 += a * b2f(vc.y);
        a2 += a * b2f(vc.z); a3 += a * b2f(vc.w);
        t0 += a * eac[0]; t1 += a * eac[1]; t2 += a * eac[2];
        t3 += a * eac[3]; t4 += a * eac[4]; t5 += a * eac[5];
        kc = kn; vc = vn;
#pragma unroll
        for (int t = 0; t < 6; ++t) eac[t] = ean[t];
    }
    const float inv = (s > 0.f) ? 1.f / s : 0.f;
    float o0 = a0 + be0 * s, o1 = a1 + be1 * s, o2 = a2 + be2 * s, o3 = a3 + be3 * s;
    o0 += w0[0]*t0 + w0[1]*t1 + w0[2]*t2 + w0[3]*t3 + w0[4]*t4 + w0[5]*t5;
    o1 += w1r[0]*t0 + w1r[1]*t1 + w1r[2]*t2 + w1r[3]*t3 + w1r[4]*t4 + w1r[5]*t5;
    o2 += w2r[0]*t0 + w2r[1]*t1 + w2r[2]*t2 + w2r[3]*t3 + w2r[4]*t4 + w2r[5]*t5;
    o3 += w3r[0]*t0 + w3r[1]*t1 + w3r[2]*t2 + w3r[3]*t3 + w3r[4]*t4 + w3r[5]*t5;
    ushort4 o;
    o.x = f2b(o0 * inv); o.y = f2b(o1 * inv);
    o.z = f2b(o2 * inv); o.w = f2b(o3 * inv);
    *(ushort4*)&qrow[d0] = o;
}

// seq(bf16, [t*BN+b*N+n][256]) = conv(q-slice of Z) + skip(k-slice of Z)
__global__ void transpose_add(const unsigned short* __restrict__ Z,
                              unsigned short* __restrict__ out) {
    long gid = (long)blockIdx.x * blockDim.x + threadIdx.x;
    long row = gid >> 6;
    int c4 = (int)(gid & 63);
    int n = (int)(row % NN);
    int bt = (int)(row / NN);
    int t = bt % TT, b = bt / TT;
    long orow = (long)t * BN + (long)b * NN + n;
    ushort4 cv = ((const ushort4*)&Z[row * 768])[c4];
    ushort4 sv = ((const ushort4*)&Z[row * 768 + 256])[c4];
    ushort4 o;
    o.x = f2b(b2f(cv.x) + b2f(sv.x));
    o.y = f2b(b2f(cv.y) + b2f(sv.y));
    o.z = f2b(b2f(cv.z) + b2f(sv.z));
    o.w = f2b(b2f(cv.w) + b2f(sv.w));
    ((ushort4*)out)[orow * 64 + c4] = o;
}

// =====================================================================
// temporal attention v2: one 64-lane wave per node bn; lane owns dims
// d0=lane*4 (8-lane group = one 32-dim head). ushort4 loads, 3-shfl reduce.
// =====================================================================
__global__ __launch_bounds__(256) void mha_time(unsigned short* __restrict__ Z)
{
    const int tid = threadIdx.x;
    const int wave = tid >> 6, lane = tid & 63;
    const long bn = (long)blockIdx.x * 4 + wave;
    const int d0 = lane * 4;
    const float scale = 0.17677669529663687f;
    float qv[TT][4], kv[TT][4], vv[TT][4];
    long r[TT];
#pragma unroll
    for (int t = 0; t < TT; ++t) {
        r[t] = ((long)t * BN + bn) * 768 + d0;
        const ushort4 qq = *(const ushort4*)&Z[r[t]];
        const ushort4 kk = *(const ushort4*)&Z[r[t] + 256];
        const ushort4 vx = *(const ushort4*)&Z[r[t] + 512];
        qv[t][0] = b2f(qq.x); qv[t][1] = b2f(qq.y); qv[t][2] = b2f(qq.z); qv[t][3] = b2f(qq.w);
        kv[t][0] = b2f(kk.x); kv[t][1] = b2f(kk.y); kv[t][2] = b2f(kk.z); kv[t][3] = b2f(kk.w);
        vv[t][0] = b2f(vx.x); vv[t][1] = b2f(vx.y); vv[t][2] = b2f(vx.z); vv[t][3] = b2f(vx.w);
    }
    float s[TT][TT];
#pragma unroll
    for (int t = 0; t < TT; ++t)
#pragma unroll
        for (int u = 0; u < TT; ++u) {
            float p = qv[t][0] * kv[u][0] + qv[t][1] * kv[u][1]
                    + qv[t][2] * kv[u][2] + qv[t][3] * kv[u][3];
            p += __shfl_xor(p, 1, 64);
            p += __shfl_xor(p, 2, 64);
            p += __shfl_xor(p, 4, 64);   // 8-lane group = one head
            s[t][u] = p * scale;
        }
#pragma unroll
    for (int t = 0; t < TT; ++t) {
        float mx = s[t][0];
#pragma unroll
        for (int u = 1; u < TT; ++u) mx = fmaxf(mx, s[t][u]);
        float sm = 0.f;
#pragma unroll
        for (int u = 0; u < TT; ++u) { s[t][u] = __expf(s[t][u] - mx); sm += s[t][u]; }
        const float inv = 1.f / sm;
        float o0 = 0.f, o1 = 0.f, o2 = 0.f, o3 = 0.f;
#pragma unroll
        for (int u = 0; u < TT; ++u) {
            o0 += s[t][u] * vv[u][0]; o1 += s[t][u] * vv[u][1];
            o2 += s[t][u] * vv[u][2]; o3 += s[t][u] * vv[u][3];
        }
        ushort4 o;
        o.x = f2b(o0 * inv); o.y = f2b(o1 * inv);
        o.z = f2b(o2 * inv); o.w = f2b(o3 * inv);
        *(ushort4*)&Z[r[t]] = o;
    }
}

// seq(bf16) = LayerNorm(seq + res(bf16, row-stride rstride)) * g + b
__global__ __launch_bounds__(256) void ln_residual(
    unsigned short* __restrict__ seq, const unsigned short* __restrict__ res,
    int rstride, const float* __restrict__ g, const float* __restrict__ b)
{
    const int wave = threadIdx.x >> 6, lane = threadIdx.x & 63;
    long row = (long)blockIdx.x * 4 + wave;
    const ushort4 s4 = *(const ushort4*)&seq[row * 256 + lane * 4];
    const ushort4 r4 = *(const ushort4*)&res[row * (long)rstride + lane * 4];
    float x[4] = { b2f(s4.x) + b2f(r4.x), b2f(s4.y) + b2f(r4.y),
                   b2f(s4.z) + b2f(r4.z), b2f(s4.w) + b2f(r4.w) };
    float sum = x[0] + x[1] + x[2] + x[3];
#pragma unroll
    for (int m = 32; m >= 1; m >>= 1) sum += __shfl_xor(sum, m, 64);
    float mean = sum * (1.f / 256.f);
    float vs = 0.f;
#pragma unroll
    for (int i = 0; i < 4; ++i) { float dl = x[i] - mean; vs += dl * dl; }
#pragma unroll
    for (int m = 32; m >= 1; m >>= 1) vs += __shfl_xor(vs, m, 64);
    float inv = rsqrtf(vs * (1.f / 256.f) + 1e-5f);
    ushort4 o;
    o.x = f2b((x[0] - mean) * inv * g[lane * 4 + 0] + b[lane * 4 + 0]);
    o.y = f2b((x[1] - mean) * inv * g[lane * 4 + 1] + b[lane * 4 + 1]);
    o.z = f2b((x[2] - mean) * inv * g[lane * 4 + 2] + b[lane * 4 + 2]);
    o.w = f2b((x[3] - mean) * inv * g[lane * 4 + 3] + b[lane * 4 + 3]);
    *(ushort4*)&seq[row * 256 + lane * 4] = o;
}

// out[row][0..9] = seq[t=T-1 rows](bf16) @ W_out + b_out ; one block per row
__global__ __launch_bounds__(256) void final_out(
    const unsigned short* __restrict__ seq, const float* __restrict__ Wd,
    const float* __restrict__ bd, float* __restrict__ out)
{
    __shared__ float xs[256];
    long row = blockIdx.x;
    xs[threadIdx.x] = b2f(seq[((long)(TT - 1) * BN + row) * 256 + threadIdx.x]);
    __syncthreads();
    const int wv = threadIdx.x >> 6, lane = threadIdx.x & 63;
    for (int o = wv; o < NCLS; o += 4) {
        float p = 0.f;
#pragma unroll
        for (int i = 0; i < 4; ++i) {
            int kk = lane + 64 * i;
            p += xs[kk] * Wd[kk * NCLS + o];
        }
#pragma unroll
        for (int m = 32; m >= 1; m >>= 1) p += __shfl_xor(p, m, 64);
        if (lane == 0) out[row * NCLS + o] = p + bd[o];
    }
}

__global__ void fill_sentinel(float* __restrict__ out, int n) {
    int gid = blockIdx.x * blockDim.x + threadIdx.x;
    if (gid < n) out[gid] = 1.0e6f;
}

// =====================================================================
extern "C" void kernel_launch(void* const* d_in, const int* in_sizes, int n_in,
                              void* d_out, int out_size, void* d_ws, size_t ws_size,
                              hipStream_t stream) {
    const float* xseq  = (const float*)d_in[0];
    const int*   eidx  = (const int*)d_in[1];
    const float* eattr = (const float*)d_in[2];
    const float* W_node = (const float*)d_in[3];
    const float* b_node = (const float*)d_in[4];
    const float* W_edge = (const float*)d_in[5];
    const float* b_edge = (const float*)d_in[6];
    const float* Wq = (const float*)d_in[7];  const float* bq = (const float*)d_in[8];
    const float* Wk = (const float*)d_in[9];  const float* bk = (const float*)d_in[10];
    const float* Wv = (const float*)d_in[11]; const float* bv = (const float*)d_in[12];
    const float* Ws = (const float*)d_in[13]; const float* bs = (const float*)d_in[14];
    const float* Wqkv = (const float*)d_in[15]; const float* bqkv = (const float*)d_in[16];
    const float* Wo = (const float*)d_in[17];   const float* bo = (const float*)d_in[18];
    const float* W1 = (const float*)d_in[19];   const float* b1 = (const float*)d_in[20];
    const float* W2 = (const float*)d_in[21];   const float* b2 = (const float*)d_in[22];
    const float* g_ln1 = (const float*)d_in[23]; const float* b_ln1 = (const float*)d_in[24];
    const float* g_ln2 = (const float*)d_in[25]; const float* b_ln2 = (const float*)d_in[26];
    const float* W_out = (const float*)d_in[27]; const float* b_out = (const float*)d_in[28];
    float* out = (float*)d_out;

    // ---- workspace layout ----
    const long SZ = (long)NM * DD;            // 20,971,520 elements
    unsigned short* Abf = (unsigned short*)d_ws;     // seq activations bf16 (40MB)
    unsigned short* Zu  = Abf + SZ;                  // qkv interleaved [NM][768] (120MB)
    unsigned short* Hid = Zu;                        // FFN hidden bf16 [MR][2048] (80MB)
    unsigned short* res2B = Zu + (long)MR * FFD;     // FFN residual bf16 [MR][256] (10MB)
    unsigned short* WX = Zu + 3 * SZ;
    unsigned short* xbf = WX;                             // 81920*64
    unsigned short* wtN = xbf + (long)NM * FIN;           // [256][64]
    unsigned short* wtQ = wtN + 256 * 64;                 // [768][256] stacked q,k,v
    unsigned short* wtS = wtQ + 3L * 65536;
    unsigned short* wtQKV = wtS + 65536;                  // 3 * [768][256]
    unsigned short* wtO = wtQKV + 3L * 768 * 256;         // 3 * [256][256]
    unsigned short* wtW1 = wtO + 3L * 65536;              // 3 * [2048][256]
    unsigned short* wtW2 = wtW1 + 3L * 2048 * 256;        // 3 * [256][2048]
    int* cnt  = (int*)(wtW2 + 3L * 256 * 2048);
    int* coff = cnt + NM;                                 // NM+1
    int* cfil = coff + NM + 1;
    unsigned* pcsr = (unsigned*)(cfil + NM);              // NE packed records
    float* qkvb = (float*)(pcsr + NE);                    // 768 packed bias
    char* wend = (char*)(qkvb + 768);
    const size_t need = (size_t)(wend - (char*)d_ws);
    if (ws_size < need) {
        fill_sentinel<<<dim3((out_size + 255) / 256), dim3(256), 0, stream>>>(out, out_size);
        return;
    }

    dim3 blk(256);
    dim3 tb(32, 8);

    // ---- prologue (batched weight conversion: 8 launches) ----
    xconvert<<<dim3((unsigned)((long)NM * FIN / 4 / 256)), blk, 0, stream>>>(xseq, xbf, (long)NM * FIN / 4);
    wtrans<<<dim3(DD / 32, FIN / 32), tb, 0, stream>>>(W_node, wtN, FIN, DD);
    wtrans4<<<dim3(DD / 32, DD / 32, 4), tb, 0, stream>>>(Wq, Wk, Wv, Ws, wtQ);
    wtrans_s<<<dim3(768 / 32, DD / 32, 3), tb, 0, stream>>>(Wqkv, (long)DD * 768, wtQKV, 768L * 256, DD, 768);
    wtrans_s<<<dim3(DD / 32, DD / 32, 3), tb, 0, stream>>>(Wo, (long)DD * DD, wtO, 65536L, DD, DD);
    wtrans_s<<<dim3(FFD / 32, DD / 32, 3), tb, 0, stream>>>(W1, (long)DD * FFD, wtW1, 2048L * 256, DD, FFD);
    wtrans_s<<<dim3(DD / 32, FFD / 32, 3), tb, 0, stream>>>(W2, (long)FFD * DD, wtW2, 256L * 2048, FFD, DD);
    pack3<<<dim3(1), blk, 0, stream>>>(bq, bk, bv, qkvb);

    // ---- CSR build (packed records) ----
    csr_init<<<dim3((NM + 255) / 256), blk, 0, stream>>>(cnt, cfil);
    csr_count<<<dim3((unsigned)(NE / 256)), blk, 0, stream>>>(eidx, cnt);
    csr_scan<<<dim3(1), dim3(1024), 0, stream>>>(cnt, coff);
    csr_scatter<<<dim3((unsigned)(NE / 256)), blk, 0, stream>>>(eidx, coff, cfil, pcsr);

    // ---- stage 1 ----
    gemm_mfma<false, true, 4><<<dim3(NM / 128, DD / 128), blk, 0, stream>>>(
        xbf, FIN, wtN, b_node, Abf, DD, FIN);
    gemm_mfma<false, true, 4><<<dim3(NM / 128, 768 / 128), blk, 0, stream>>>(
        Abf, DD, wtQ, qkvb, Zu, 768, DD);
    conv_fused<<<dim3(NM / 4), blk, 0, stream>>>(
        Zu, eattr, W_edge, b_edge, coff, pcsr);
    gemm_mfma<false, true, 4><<<dim3(NM / 128, DD / 128), blk, 0, stream>>>(
        Abf, DD, wtS, bs, (void*)(Zu + 256), 768, DD);
    transpose_add<<<dim3(NM * 64 / 256), blk, 0, stream>>>(Zu, Abf);

    // ---- stage 2: 3 temporal transformer encoder layers ----
    for (int l = 0; l < 3; ++l) {
        gemm_mfma<false, true, 4><<<dim3(NM / 128, 768 / 128), blk, 0, stream>>>(
            Abf, DD, wtQKV + (long)l * 768 * 256, bqkv + (long)l * 768, Zu, 768, DD);
        mha_time<<<dim3(BN / 4), blk, 0, stream>>>(Zu);
        gemm_mfma<false, true, 4><<<dim3(NM / 128, DD / 128), blk, 0, stream>>>(
            Zu, 768, wtO + (long)l * 65536, bo + (long)l * DD, (void*)(Zu + 512), 768, DD);
        ln_residual<<<dim3(NM / 4), blk, 0, stream>>>(
            Abf, Zu + 512, 768, g_ln1 + l * DD, b_ln1 + l * DD);
        // unfused FFN (4 chunks of 20480 rows); W2 uses the 128x64 tile
        for (int mr = 0; mr < NM / MR; ++mr) {
            const long r0 = (long)mr * MR;
            gemm_mfma<true, true, 4><<<dim3(MR / 128, FFD / 128), blk, 0, stream>>>(
                Abf + r0 * DD, DD, wtW1 + (long)l * 2048 * 256, b1 + (long)l * FFD, Hid, FFD, DD);
            gemm_mfma<false, true, 2><<<dim3(MR / 128, DD / 64), blk, 0, stream>>>(
                Hid, FFD, wtW2 + (long)l * 256 * 2048, b2 + (long)l * DD, res2B, DD, FFD);
            ln_residual<<<dim3(MR / 4), blk, 0, stream>>>(
                Abf + r0 * DD, res2B, DD, g_ln2 + l * DD, b_ln2 + l * DD);
        }
    }

    // ---- output head ----
    final_out<<<dim3(BN), blk, 0, stream>>>(Abf, W_out, b_out, out);
}

// Round 17
// 1909.012 us; speedup vs baseline: 1.3129x; 1.0263x over previous
//
#include <hip/hip_runtime.h>
#include <math.h>

// ---- problem constants ----
#define BB   8
#define TT   5
#define NN   2048
#define FIN  64
#define EE   32768
#define DD   256
#define HH   8
#define FFD  2048
#define NCLS 10
#define GG   (BB*TT)        // 40 graphs
#define BN   (BB*NN)        // 16384
#define NM   (GG*NN)        // 81920 rows (= TT*BN)
#define NE   ((long)GG*EE)  // 1310720 edges

#define MR        20480           // rows per FFN chunk (4 chunks)

typedef __attribute__((ext_vector_type(8))) short short8;
typedef __attribute__((ext_vector_type(4))) float f32x4;

// ---- bf16 helpers (RNE) ----
__device__ __forceinline__ unsigned short f2b(float f) {
    unsigned u = __float_as_uint(f);
    u = (u + 0x7fffu + ((u >> 16) & 1u)) >> 16;
    return (unsigned short)u;
}
__device__ __forceinline__ float b2f(unsigned short b) {
    return __uint_as_float(((unsigned)b) << 16);
}

// async global->LDS, 16B per lane (dest must be wave-uniform base + lane*16)
__device__ __forceinline__ void gload_lds16(const void* g, void* l) {
    __builtin_amdgcn_global_load_lds(
        (__attribute__((address_space(1))) void*)g,
        (__attribute__((address_space(3))) void*)l, 16, 0, 0);
}

// =====================================================================
// Weight transpose+convert: fp32 [K][N] -> bf16 [N][K]
// =====================================================================
__device__ __forceinline__ void wtrans_body(const float* in, unsigned short* out,
                                            int K, int N, int bx, int by) {
    __shared__ float t[32][33];
    const int n0 = bx * 32, k0 = by * 32;
    const int tx = threadIdx.x, ty = threadIdx.y;
    for (int i = ty; i < 32; i += 8) t[i][tx] = in[(long)(k0 + i) * N + n0 + tx];
    __syncthreads();
    for (int i = ty; i < 32; i += 8)
        out[(long)(n0 + i) * K + k0 + tx] = f2b(t[tx][i]);
}

__global__ void wtrans(const float* __restrict__ in, unsigned short* __restrict__ out,
                       int K, int N) {
    wtrans_body(in, out, K, N, blockIdx.x, blockIdx.y);
}

// 4 same-shape [256][256] matrices, z selects
__global__ void wtrans4(const float* __restrict__ a, const float* __restrict__ b,
                        const float* __restrict__ c, const float* __restrict__ d,
                        unsigned short* __restrict__ out) {
    const float* src = (blockIdx.z == 0) ? a : (blockIdx.z == 1) ? b
                     : (blockIdx.z == 2) ? c : d;
    wtrans_body(src, out + (long)blockIdx.z * 65536, DD, DD, blockIdx.x, blockIdx.y);
}

// layer-strided: z = layer
__global__ void wtrans_s(const float* __restrict__ in, long sstride,
                         unsigned short* __restrict__ out, long dstride,
                         int K, int N) {
    wtrans_body(in + (long)blockIdx.z * sstride, out + (long)blockIdx.z * dstride,
                K, N, blockIdx.x, blockIdx.y);
}

// fp32 -> bf16 elementwise (n4 float4 groups)
__global__ void xconvert(const float* __restrict__ in, unsigned short* __restrict__ out, long n4) {
    long gid = (long)blockIdx.x * blockDim.x + threadIdx.x;
    if (gid >= n4) return;
    float4 v = ((const float4*)in)[gid];
    ushort4 o;
    o.x = f2b(v.x); o.y = f2b(v.y); o.z = f2b(v.z); o.w = f2b(v.w);
    ((ushort4*)out)[gid] = o;
}

// pack 3 bias vectors of 256 into one 768 buffer
__global__ void pack3(const float* __restrict__ a, const float* __restrict__ b,
                      const float* __restrict__ c, float* __restrict__ o) {
    int i = threadIdx.x;
    o[i] = a[i]; o[256 + i] = b[i]; o[512 + i] = c[i];
}

// =====================================================================
// bf16 MFMA GEMM v2: 256x128 tile, 512 threads = 8 waves (4M x 2N),
// BK=64 + rule-21 XOR swizzle. Doubles MFMA work per barrier-pair vs the
// 128x128 tile (key for short-K shapes). M%256==0, N%128==0, K%64==0.
// =====================================================================
template <bool RELU, bool OUTBF>
__global__ __launch_bounds__(512) void gemm_mfma2(
    const unsigned short* __restrict__ A, int lda,
    const unsigned short* __restrict__ WT,
    const float* __restrict__ bias,
    void* __restrict__ Cv, int ldc, int K)
{
    __shared__ unsigned short As[256 * 64];
    __shared__ unsigned short Bs[128 * 64];
    const int tid = threadIdx.x;
    const int wid = tid >> 6, lane = tid & 63;
    const int wm = wid >> 1, wn = wid & 1;     // 4 x 2 wave grid
    const int gx = gridDim.x, gy = gridDim.y;
    int bx = blockIdx.x, by = blockIdx.y;
    if ((gx & 7) == 0) {
        const int lbid = bx + gx * by;
        const int xcd = lbid & 7;
        const int i = lbid >> 3;
        const int CX = gx >> 3;
        bx = xcd * CX + i / gy;
        by = i - (i / gy) * gy;
    }
    const long row0 = (long)bx * 256;
    const long col0 = (long)by * 128;
    const int srow = tid >> 3;            // 0..63 (per pass)
    const int schunk = tid & 7;           // 16B chunk in 128B row
    const int fr = lane & 15;
    const int q = lane >> 4;
    f32x4 acc[4][4] = {};
    for (int k0 = 0; k0 < K; k0 += 64) {
        __syncthreads();
#pragma unroll
        for (int p = 0; p < 4; ++p) {
            const int row = p * 64 + srow;
            const int sc = (schunk ^ (row & 7)) * 8;
            gload_lds16(&A[(row0 + row) * (long)lda + k0 + sc], As + row * 64 + schunk * 8);
        }
#pragma unroll
        for (int p = 0; p < 2; ++p) {
            const int row = p * 64 + srow;
            const int sc = (schunk ^ (row & 7)) * 8;
            gload_lds16(&WT[(col0 + row) * (long)K + k0 + sc], Bs + row * 64 + schunk * 8);
        }
        __syncthreads();
#pragma unroll
        for (int kk = 0; kk < 2; ++kk) {
            short8 af[4], bfr[4];
#pragma unroll
            for (int mf = 0; mf < 4; ++mf) {
                const int row = wm * 64 + mf * 16 + fr;
                const int byo = (row * 128 + kk * 64 + q * 16) ^ ((row & 7) << 4);
                af[mf] = *(const short8*)((const char*)As + byo);
            }
#pragma unroll
            for (int nf = 0; nf < 4; ++nf) {
                const int row = wn * 64 + nf * 16 + fr;
                const int byo = (row * 128 + kk * 64 + q * 16) ^ ((row & 7) << 4);
                bfr[nf] = *(const short8*)((const char*)Bs + byo);
            }
#pragma unroll
            for (int mf = 0; mf < 4; ++mf)
#pragma unroll
                for (int nf = 0; nf < 4; ++nf)
                    acc[mf][nf] = __builtin_amdgcn_mfma_f32_16x16x32_bf16(
                        af[mf], bfr[nf], acc[mf][nf], 0, 0, 0);
        }
    }
#pragma unroll
    for (int nf = 0; nf < 4; ++nf) {
        const long col = col0 + wn * 64 + nf * 16 + fr;
        const float bv = bias[col];
#pragma unroll
        for (int mf = 0; mf < 4; ++mf) {
#pragma unroll
            for (int i = 0; i < 4; ++i) {
                const long r = row0 + wm * 64 + mf * 16 + q * 4 + i;
                float vv = acc[mf][nf][i] + bv;
                if (RELU) vv = fmaxf(vv, 0.f);
                if (OUTBF) ((unsigned short*)Cv)[r * ldc + col] = f2b(vv);
                else       ((float*)Cv)[r * ldc + col] = vv;
            }
        }
    }
}

// =====================================================================
// bf16 MFMA GEMM (128 x 64, NF=2) — kept for W2 (2 blocks/CU win, R14).
// =====================================================================
template <bool RELU, bool OUTBF, int NF>
__global__ __launch_bounds__(256) void gemm_mfma(
    const unsigned short* __restrict__ A, int lda,
    const unsigned short* __restrict__ WT,
    const float* __restrict__ bias,
    void* __restrict__ Cv, int ldc, int K)
{
    __shared__ unsigned short As[128 * 64];
    __shared__ unsigned short Bs[32 * NF * 64];
    const int tid = threadIdx.x;
    const int wid = tid >> 6, lane = tid & 63;
    const int wm = wid >> 1, wn = wid & 1;
    const int gx = gridDim.x, gy = gridDim.y;
    int bx = blockIdx.x, by = blockIdx.y;
    if ((gx & 7) == 0) {
        const int lbid = bx + gx * by;
        const int xcd = lbid & 7;
        const int i = lbid >> 3;
        const int CX = gx >> 3;
        bx = xcd * CX + i / gy;
        by = i - (i / gy) * gy;
    }
    const long row0 = (long)bx * 128;
    const long col0 = (long)by * (32 * NF);
    const int srow = tid >> 3;
    const int schunk = tid & 7;
    const int fr = lane & 15;
    const int q = lane >> 4;
    f32x4 acc[4][NF] = {};
    for (int k0 = 0; k0 < K; k0 += 64) {
        __syncthreads();
#pragma unroll
        for (int p = 0; p < 4; ++p) {
            const int row = p * 32 + srow;
            const int sc = (schunk ^ (row & 7)) * 8;
            gload_lds16(&A[(row0 + row) * (long)lda + k0 + sc], As + row * 64 + schunk * 8);
        }
#pragma unroll
        for (int p = 0; p < NF; ++p) {
            const int row = p * 32 + srow;
            const int sc = (schunk ^ (row & 7)) * 8;
            gload_lds16(&WT[(col0 + row) * (long)K + k0 + sc], Bs + row * 64 + schunk * 8);
        }
        __syncthreads();
#pragma unroll
        for (int kk = 0; kk < 2; ++kk) {
            short8 af[4], bfr[NF];
#pragma unroll
            for (int mf = 0; mf < 4; ++mf) {
                const int row = wm * 64 + mf * 16 + fr;
                const int byo = (row * 128 + kk * 64 + q * 16) ^ ((row & 7) << 4);
                af[mf] = *(const short8*)((const char*)As + byo);
            }
#pragma unroll
            for (int nf = 0; nf < NF; ++nf) {
                const int row = wn * (NF * 16) + nf * 16 + fr;
                const int byo = (row * 128 + kk * 64 + q * 16) ^ ((row & 7) << 4);
                bfr[nf] = *(const short8*)((const char*)Bs + byo);
            }
#pragma unroll
            for (int mf = 0; mf < 4; ++mf)
#pragma unroll
                for (int nf = 0; nf < NF; ++nf)
                    acc[mf][nf] = __builtin_amdgcn_mfma_f32_16x16x32_bf16(
                        af[mf], bfr[nf], acc[mf][nf], 0, 0, 0);
        }
    }
#pragma unroll
    for (int nf = 0; nf < NF; ++nf) {
        const long col = col0 + wn * (NF * 16) + nf * 16 + fr;
        const float bv = bias[col];
#pragma unroll
        for (int mf = 0; mf < 4; ++mf) {
#pragma unroll
            for (int i = 0; i < 4; ++i) {
                const long r = row0 + wm * 64 + mf * 16 + q * 4 + i;
                float vv = acc[mf][nf][i] + bv;
                if (RELU) vv = fmaxf(vv, 0.f);
                if (OUTBF) ((unsigned short*)Cv)[r * ldc + col] = f2b(vv);
                else       ((float*)Cv)[r * ldc + col] = vv;
            }
        }
    }
}

// =====================================================================
// CSR build. pcsr entry packs (srcrow << 15) | e.
// =====================================================================
__global__ void csr_init(int* __restrict__ cnt, int* __restrict__ fill) {
    int gid = blockIdx.x * blockDim.x + threadIdx.x;
    if (gid < NM) { cnt[gid] = 0; fill[gid] = 0; }
}

__global__ void csr_count(const int* __restrict__ eidx, int* __restrict__ cnt) {
    long el = (long)blockIdx.x * blockDim.x + threadIdx.x;
    if (el >= NE) return;
    int g = (int)(el >> 15), e = (int)(el & (EE - 1));
    int tgt = eidx[((long)g * 2 + 1) * EE + e];
    atomicAdd(&cnt[g * NN + tgt], 1);
}

__global__ __launch_bounds__(1024) void csr_scan(const int* __restrict__ cnt, int* __restrict__ off) {
    __shared__ int part[1024];
    const int t = threadIdx.x;
    const int base = t * (NM / 1024);
    int s = 0;
    for (int i = 0; i < NM / 1024; ++i) s += cnt[base + i];
    part[t] = s;
    __syncthreads();
    for (int d = 1; d < 1024; d <<= 1) {
        int v = (t >= d) ? part[t - d] : 0;
        __syncthreads();
        part[t] += v;
        __syncthreads();
    }
    int run = (t == 0) ? 0 : part[t - 1];
    for (int i = 0; i < NM / 1024; ++i) { off[base + i] = run; run += cnt[base + i]; }
    if (t == 1023) off[NM] = run;
}

__global__ void csr_scatter(const int* __restrict__ eidx, const int* __restrict__ off,
                            int* __restrict__ fill, unsigned* __restrict__ pcsr) {
    long el = (long)blockIdx.x * blockDim.x + threadIdx.x;
    if (el >= NE) return;
    int g = (int)(el >> 15), e = (int)(el & (EE - 1));
    int src = eidx[((long)g * 2 + 0) * EE + e];
    int tgt = eidx[((long)g * 2 + 1) * EE + e];
    int tf = g * NN + tgt;
    int pos = atomicAdd(&fill[tf], 1);
    pcsr[off[tf] + pos] = ((unsigned)(g * NN + src) << 15) | (unsigned)e;
}

// =====================================================================
// Fused TransformerConv on interleaved qkv [NM][768]; packed CSR records.
// =====================================================================
__global__ __launch_bounds__(256) void conv_fused(
    unsigned short* __restrict__ Z,
    const float* __restrict__ eattr,
    const float* __restrict__ W_edge, const float* __restrict__ b_edge,
    const int* __restrict__ off, const unsigned* __restrict__ pcsr)
{
    const int tid = threadIdx.x;
    const int wave = tid >> 6, lane = tid & 63;
    const int bid = (blockIdx.x & 7) * (NM / 4 / 8) + (blockIdx.x >> 3);
    const long tf = (long)bid * 4 + wave;
    const int d0 = lane * 4;
    unsigned short* qrow = &Z[tf * 768];
    const ushort4 q4 = *(const ushort4*)&qrow[d0];
    const float q0 = b2f(q4.x), q1 = b2f(q4.y), q2 = b2f(q4.z), q3 = b2f(q4.w);
    const float be0 = b_edge[d0], be1 = b_edge[d0 + 1],
                be2 = b_edge[d0 + 2], be3 = b_edge[d0 + 3];
    float w0[6], w1r[6], w2r[6], w3r[6];
#pragma unroll
    for (int j2 = 0; j2 < 6; ++j2) {
        const float* wp = &W_edge[j2 * 256 + d0];
        w0[j2] = wp[0]; w1r[j2] = wp[1]; w2r[j2] = wp[2]; w3r[j2] = wp[3];
    }
    float qb = q0 * be0 + q1 * be1 + q2 * be2 + q3 * be3;
    float qw[6];
#pragma unroll
    for (int j2 = 0; j2 < 6; ++j2)
        qw[j2] = q0 * w0[j2] + q1 * w1r[j2] + q2 * w2r[j2] + q3 * w3r[j2];
#pragma unroll
    for (int mm = 1; mm <= 4; mm <<= 1) {
        qb += __shfl_xor(qb, mm, 64);
#pragma unroll
        for (int j2 = 0; j2 < 6; ++j2) qw[j2] += __shfl_xor(qw[j2], mm, 64);
    }
    const float scale = 0.17677669529663687f;  // 1/sqrt(32)
    float s = 0.f, a0 = 0.f, a1 = 0.f, a2 = 0.f, a3 = 0.f;
    float t0 = 0.f, t1 = 0.f, t2 = 0.f, t3 = 0.f, t4 = 0.f, t5 = 0.f;
    const int jb = off[tf], je = off[tf + 1];
    ushort4 kc, vc; float eac[6];
    if (jb < je) {
        const unsigned pk = pcsr[jb];
        const long sf = pk >> 15;
        kc = *(const ushort4*)&Z[sf * 768 + 256 + d0];
        vc = *(const ushort4*)&Z[sf * 768 + 512 + d0];
        const long el = (sf >> 11) * EE + (pk & 32767u);
#pragma unroll
        for (int t = 0; t < 6; ++t) eac[t] = eattr[el * 6 + t];
    }
    for (int j = jb; j < je; ++j) {
        ushort4 kn, vn; float ean[6];
        if (j + 1 < je) {  // prefetch next edge (wave-uniform branch)
            const unsigned pk = pcsr[j + 1];
            const long sf = pk >> 15;
            kn = *(const ushort4*)&Z[sf * 768 + 256 + d0];
            vn = *(const ushort4*)&Z[sf * 768 + 512 + d0];
            const long el = (sf >> 11) * EE + (pk & 32767u);
#pragma unroll
            for (int t = 0; t < 6; ++t) ean[t] = eattr[el * 6 + t];
        }
        float p = q0 * b2f(kc.x) + q1 * b2f(kc.y) + q2 * b2f(kc.z) + q3 * b2f(kc.w);
        p += __shfl_xor(p, 1, 64);
        p += __shfl_xor(p, 2, 64);
        p += __shfl_xor(p, 4, 64);
        float alpha = p + qb;
        alpha += eac[0] * qw[0] + eac[1] * qw[1] + eac[2] * qw[2]
               + eac[3] * qw[3] + eac[4] * qw[4] + eac[5] * qw[5];
        const float a = __expf(alpha * scale);
        s += a;
        a0 += a * b2f(vc.x); a1 += a * b2f(vc.y);
        a2 += a * b2f(vc.z); a3 += a * b2f(vc.w);
        t0 += a * eac[0]; t1 += a * eac[1]; t2 += a * eac[2];
        t3 += a * eac[3]; t4 += a * eac[4]; t5 += a * eac[5];
        kc = kn; vc = vn;
#pragma unroll
        for (int t = 0; t < 6; ++t) eac[t] = ean[t];
    }
    const float inv = (s > 0.f) ? 1.f / s : 0.f;
    float o0 = a0 + be0 * s, o1 = a1 + be1 * s, o2 = a2 + be2 * s, o3 = a3 + be3 * s;
    o0 += w0[0]*t0 + w0[1]*t1 + w0[2]*t2 + w0[3]*t3 + w0[4]*t4 + w0[5]*t5;
    o1 += w1r[0]*t0 + w1r[1]*t1 + w1r[2]*t2 + w1r[3]*t3 + w1r[4]*t4 + w1r[5]*t5;
    o2 += w2r[0]*t0 + w2r[1]*t1 + w2r[2]*t2 + w2r[3]*t3 + w2r[4]*t4 + w2r[5]*t5;
    o3 += w3r[0]*t0 + w3r[1]*t1 + w3r[2]*t2 + w3r[3]*t3 + w3r[4]*t4 + w3r[5]*t5;
    ushort4 o;
    o.x = f2b(o0 * inv); o.y = f2b(o1 * inv);
    o.z = f2b(o2 * inv); o.w = f2b(o3 * inv);
    *(ushort4*)&qrow[d0] = o;
}

// seq(bf16, [t*BN+b*N+n][256]) = conv(q-slice of Z) + skip(k-slice of Z)
__global__ void transpose_add(const unsigned short* __restrict__ Z,
                              unsigned short* __restrict__ out) {
    long gid = (long)blockIdx.x * blockDim.x + threadIdx.x;
    long row = gid >> 6;
    int c4 = (int)(gid & 63);
    int n = (int)(row % NN);
    int bt = (int)(row / NN);
    int t = bt % TT, b = bt / TT;
    long orow = (long)t * BN + (long)b * NN + n;
    ushort4 cv = ((const ushort4*)&Z[row * 768])[c4];
    ushort4 sv = ((const ushort4*)&Z[row * 768 + 256])[c4];
    ushort4 o;
    o.x = f2b(b2f(cv.x) + b2f(sv.x));
    o.y = f2b(b2f(cv.y) + b2f(sv.y));
    o.z = f2b(b2f(cv.z) + b2f(sv.z));
    o.w = f2b(b2f(cv.w) + b2f(sv.w));
    ((ushort4*)out)[orow * 64 + c4] = o;
}

// =====================================================================
// temporal attention v2: one 64-lane wave per node bn.
// =====================================================================
__global__ __launch_bounds__(256) void mha_time(unsigned short* __restrict__ Z)
{
    const int tid = threadIdx.x;
    const int wave = tid >> 6, lane = tid & 63;
    const long bn = (long)blockIdx.x * 4 + wave;
    const int d0 = lane * 4;
    const float scale = 0.17677669529663687f;
    float qv[TT][4], kv[TT][4], vv[TT][4];
    long r[TT];
#pragma unroll
    for (int t = 0; t < TT; ++t) {
        r[t] = ((long)t * BN + bn) * 768 + d0;
        const ushort4 qq = *(const ushort4*)&Z[r[t]];
        const ushort4 kk = *(const ushort4*)&Z[r[t] + 256];
        const ushort4 vx = *(const ushort4*)&Z[r[t] + 512];
        qv[t][0] = b2f(qq.x); qv[t][1] = b2f(qq.y); qv[t][2] = b2f(qq.z); qv[t][3] = b2f(qq.w);
        kv[t][0] = b2f(kk.x); kv[t][1] = b2f(kk.y); kv[t][2] = b2f(kk.z); kv[t][3] = b2f(kk.w);
        vv[t][0] = b2f(vx.x); vv[t][1] = b2f(vx.y); vv[t][2] = b2f(vx.z); vv[t][3] = b2f(vx.w);
    }
    float s[TT][TT];
#pragma unroll
    for (int t = 0; t < TT; ++t)
#pragma unroll
        for (int u = 0; u < TT; ++u) {
            float p = qv[t][0] * kv[u][0] + qv[t][1] * kv[u][1]
                    + qv[t][2] * kv[u][2] + qv[t][3] * kv[u][3];
            p += __shfl_xor(p, 1, 64);
            p += __shfl_xor(p, 2, 64);
            p += __shfl_xor(p, 4, 64);   // 8-lane group = one head
            s[t][u] = p * scale;
        }
#pragma unroll
    for (int t = 0; t < TT; ++t) {
        float mx = s[t][0];
#pragma unroll
        for (int u = 1; u < TT; ++u) mx = fmaxf(mx, s[t][u]);
        float sm = 0.f;
#pragma unroll
        for (int u = 0; u < TT; ++u) { s[t][u] = __expf(s[t][u] - mx); sm += s[t][u]; }
        const float inv = 1.f / sm;
        float o0 = 0.f, o1 = 0.f, o2 = 0.f, o3 = 0.f;
#pragma unroll
        for (int u = 0; u < TT; ++u) {
            o0 += s[t][u] * vv[u][0]; o1 += s[t][u] * vv[u][1];
            o2 += s[t][u] * vv[u][2]; o3 += s[t][u] * vv[u][3];
        }
        ushort4 o;
        o.x = f2b(o0 * inv); o.y = f2b(o1 * inv);
        o.z = f2b(o2 * inv); o.w = f2b(o3 * inv);
        *(ushort4*)&Z[r[t]] = o;
    }
}

// seq(bf16) = LayerNorm(seq + res(bf16, row-stride rstride)) * g + b
__global__ __launch_bounds__(256) void ln_residual(
    unsigned short* __restrict__ seq, const unsigned short* __restrict__ res,
    int rstride, const float* __restrict__ g, const float* __restrict__ b)
{
    const int wave = threadIdx.x >> 6, lane = threadIdx.x & 63;
    long row = (long)blockIdx.x * 4 + wave;
    const ushort4 s4 = *(const ushort4*)&seq[row * 256 + lane * 4];
    const ushort4 r4 = *(const ushort4*)&res[row * (long)rstride + lane * 4];
    float x[4] = { b2f(s4.x) + b2f(r4.x), b2f(s4.y) + b2f(r4.y),
                   b2f(s4.z) + b2f(r4.z), b2f(s4.w) + b2f(r4.w) };
    float sum = x[0] + x[1] + x[2] + x[3];
#pragma unroll
    for (int m = 32; m >= 1; m >>= 1) sum += __shfl_xor(sum, m, 64);
    float mean = sum * (1.f / 256.f);
    float vs = 0.f;
#pragma unroll
    for (int i = 0; i < 4; ++i) { float dl = x[i] - mean; vs += dl * dl; }
#pragma unroll
    for (int m = 32; m >= 1; m >>= 1) vs += __shfl_xor(vs, m, 64);
    float inv = rsqrtf(vs * (1.f / 256.f) + 1e-5f);
    ushort4 o;
    o.x = f2b((x[0] - mean) * inv * g[lane * 4 + 0] + b[lane * 4 + 0]);
    o.y = f2b((x[1] - mean) * inv * g[lane * 4 + 1] + b[lane * 4 + 1]);
    o.z = f2b((x[2] - mean) * inv * g[lane * 4 + 2] + b[lane * 4 + 2]);
    o.w = f2b((x[3] - mean) * inv * g[lane * 4 + 3] + b[lane * 4 + 3]);
    *(ushort4*)&seq[row * 256 + lane * 4] = o;
}

// out[row][0..9] = seq[t=T-1 rows](bf16) @ W_out + b_out ; one block per row
__global__ __launch_bounds__(256) void final_out(
    const unsigned short* __restrict__ seq, const float* __restrict__ Wd,
    const float* __restrict__ bd, float* __restrict__ out)
{
    __shared__ float xs[256];
    long row = blockIdx.x;
    xs[threadIdx.x] = b2f(seq[((long)(TT - 1) * BN + row) * 256 + threadIdx.x]);
    __syncthreads();
    const int wv = threadIdx.x >> 6, lane = threadIdx.x & 63;
    for (int o = wv; o < NCLS; o += 4) {
        float p = 0.f;
#pragma unroll
        for (int i = 0; i < 4; ++i) {
            int kk = lane + 64 * i;
            p += xs[kk] * Wd[kk * NCLS + o];
        }
#pragma unroll
        for (int m = 32; m >= 1; m >>= 1) p += __shfl_xor(p, m, 64);
        if (lane == 0) out[row * NCLS + o] = p + bd[o];
    }
}

__global__ void fill_sentinel(float* __restrict__ out, int n) {
    int gid = blockIdx.x * blockDim.x + threadIdx.x;
    if (gid < n) out[gid] = 1.0e6f;
}

// =====================================================================
extern "C" void kernel_launch(void* const* d_in, const int* in_sizes, int n_in,
                              void* d_out, int out_size, void* d_ws, size_t ws_size,
                              hipStream_t stream) {
    const float* xseq  = (const float*)d_in[0];
    const int*   eidx  = (const int*)d_in[1];
    const float* eattr = (const float*)d_in[2];
    const float* W_node = (const float*)d_in[3];
    const float* b_node = (const float*)d_in[4];
    const float* W_edge = (const float*)d_in[5];
    const float* b_edge = (const float*)d_in[6];
    const float* Wq = (const float*)d_in[7];  const float* bq = (const float*)d_in[8];
    const float* Wk = (const float*)d_in[9];  const float* bk = (const float*)d_in[10];
    const float* Wv = (const float*)d_in[11]; const float* bv = (const float*)d_in[12];
    const float* Ws = (const float*)d_in[13]; const float* bs = (const float*)d_in[14];
    const float* Wqkv = (const float*)d_in[15]; const float* bqkv = (const float*)d_in[16];
    const float* Wo = (const float*)d_in[17];   const float* bo = (const float*)d_in[18];
    const float* W1 = (const float*)d_in[19];   const float* b1 = (const float*)d_in[20];
    const float* W2 = (const float*)d_in[21];   const float* b2 = (const float*)d_in[22];
    const float* g_ln1 = (const float*)d_in[23]; const float* b_ln1 = (const float*)d_in[24];
    const float* g_ln2 = (const float*)d_in[25]; const float* b_ln2 = (const float*)d_in[26];
    const float* W_out = (const float*)d_in[27]; const float* b_out = (const float*)d_in[28];
    float* out = (float*)d_out;

    // ---- workspace layout ----
    const long SZ = (long)NM * DD;            // 20,971,520 elements
    unsigned short* Abf = (unsigned short*)d_ws;     // seq activations bf16 (40MB)
    unsigned short* Zu  = Abf + SZ;                  // qkv interleaved [NM][768] (120MB)
    unsigned short* Hid = Zu;                        // FFN hidden bf16 [MR][2048] (80MB)
    unsigned short* res2B = Zu + (long)MR * FFD;     // FFN residual bf16 [MR][256] (10MB)
    unsigned short* WX = Zu + 3 * SZ;
    unsigned short* xbf = WX;                             // 81920*64
    unsigned short* wtN = xbf + (long)NM * FIN;           // [256][64]
    unsigned short* wtQ = wtN + 256 * 64;                 // [768][256] stacked q,k,v
    unsigned short* wtS = wtQ + 3L * 65536;
    unsigned short* wtQKV = wtS + 65536;                  // 3 * [768][256]
    unsigned short* wtO = wtQKV + 3L * 768 * 256;         // 3 * [256][256]
    unsigned short* wtW1 = wtO + 3L * 65536;              // 3 * [2048][256]
    unsigned short* wtW2 = wtW1 + 3L * 2048 * 256;        // 3 * [256][2048]
    int* cnt  = (int*)(wtW2 + 3L * 256 * 2048);
    int* coff = cnt + NM;                                 // NM+1
    int* cfil = coff + NM + 1;
    unsigned* pcsr = (unsigned*)(cfil + NM);              // NE packed records
    float* qkvb = (float*)(pcsr + NE);                    // 768 packed bias
    char* wend = (char*)(qkvb + 768);
    const size_t need = (size_t)(wend - (char*)d_ws);
    if (ws_size < need) {
        fill_sentinel<<<dim3((out_size + 255) / 256), dim3(256), 0, stream>>>(out, out_size);
        return;
    }

    dim3 blk(256);
    dim3 blk5(512);
    dim3 tb(32, 8);

    // ---- prologue (batched weight conversion) ----
    xconvert<<<dim3((unsigned)((long)NM * FIN / 4 / 256)), blk, 0, stream>>>(xseq, xbf, (long)NM * FIN / 4);
    wtrans<<<dim3(DD / 32, FIN / 32), tb, 0, stream>>>(W_node, wtN, FIN, DD);
    wtrans4<<<dim3(DD / 32, DD / 32, 4), tb, 0, stream>>>(Wq, Wk, Wv, Ws, wtQ);
    wtrans_s<<<dim3(768 / 32, DD / 32, 3), tb, 0, stream>>>(Wqkv, (long)DD * 768, wtQKV, 768L * 256, DD, 768);
    wtrans_s<<<dim3(DD / 32, DD / 32, 3), tb, 0, stream>>>(Wo, (long)DD * DD, wtO, 65536L, DD, DD);
    wtrans_s<<<dim3(FFD / 32, DD / 32, 3), tb, 0, stream>>>(W1, (long)DD * FFD, wtW1, 2048L * 256, DD, FFD);
    wtrans_s<<<dim3(DD / 32, FFD / 32, 3), tb, 0, stream>>>(W2, (long)FFD * DD, wtW2, 256L * 2048, FFD, DD);
    pack3<<<dim3(1), blk, 0, stream>>>(bq, bk, bv, qkvb);

    // ---- CSR build (packed records) ----
    csr_init<<<dim3((NM + 255) / 256), blk, 0, stream>>>(cnt, cfil);
    csr_count<<<dim3((unsigned)(NE / 256)), blk, 0, stream>>>(eidx, cnt);
    csr_scan<<<dim3(1), dim3(1024), 0, stream>>>(cnt, coff);
    csr_scatter<<<dim3((unsigned)(NE / 256)), blk, 0, stream>>>(eidx, coff, cfil, pcsr);

    // ---- stage 1 ----
    gemm_mfma2<false, true><<<dim3(NM / 256, DD / 128), blk5, 0, stream>>>(
        xbf, FIN, wtN, b_node, Abf, DD, FIN);
    gemm_mfma2<false, true><<<dim3(NM / 256, 768 / 128), blk5, 0, stream>>>(
        Abf, DD, wtQ, qkvb, Zu, 768, DD);
    conv_fused<<<dim3(NM / 4), blk, 0, stream>>>(
        Zu, eattr, W_edge, b_edge, coff, pcsr);
    gemm_mfma2<false, true><<<dim3(NM / 256, DD / 128), blk5, 0, stream>>>(
        Abf, DD, wtS, bs, (void*)(Zu + 256), 768, DD);
    transpose_add<<<dim3(NM * 64 / 256), blk, 0, stream>>>(Zu, Abf);

    // ---- stage 2: 3 temporal transformer encoder layers ----
    for (int l = 0; l < 3; ++l) {
        gemm_mfma2<false, true><<<dim3(NM / 256, 768 / 128), blk5, 0, stream>>>(
            Abf, DD, wtQKV + (long)l * 768 * 256, bqkv + (long)l * 768, Zu, 768, DD);
        mha_time<<<dim3(BN / 4), blk, 0, stream>>>(Zu);
        gemm_mfma2<false, true><<<dim3(NM / 256, DD / 128), blk5, 0, stream>>>(
            Zu, 768, wtO + (long)l * 65536, bo + (long)l * DD, (void*)(Zu + 512), 768, DD);
        ln_residual<<<dim3(NM / 4), blk, 0, stream>>>(
            Abf, Zu + 512, 768, g_ln1 + l * DD, b_ln1 + l * DD);
        // unfused FFN (4 chunks of 20480 rows); W2 keeps the NF=2 128x64 tile
        for (int mr = 0; mr < NM / MR; ++mr) {
            const long r0 = (long)mr * MR;
            gemm_mfma2<true, true><<<dim3(MR / 256, FFD / 128), blk5, 0, stream>>>(
                Abf + r0 * DD, DD, wtW1 + (long)l * 2048 * 256, b1 + (long)l * FFD, Hid, FFD, DD);
            gemm_mfma<false, true, 2><<<dim3(MR / 128, DD / 64), blk, 0, stream>>>(
                Hid, FFD, wtW2 + (long)l * 256 * 2048, b2 + (long)l * DD, res2B, DD, FFD);
            ln_residual<<<dim3(MR / 4), blk, 0, stream>>>(
                Abf + r0 * DD, res2B, DD, g_ln2 + l * DD, b_ln2 + l * DD);
        }
    }

    // ---- output head ----
    final_out<<<dim3(BN), blk, 0, stream>>>(Abf, W_out, b_out, out);
}

// Round 18
// 1863.412 us; speedup vs baseline: 1.3451x; 1.0245x over previous
//
#include <hip/hip_runtime.h>
#include <math.h>

// ---- problem constants ----
#define BB   8
#define TT   5
#define NN   2048
#define FIN  64
#define EE   32768
#define DD   256
#define HH   8
#define FFD  2048
#define NCLS 10
#define GG   (BB*TT)        // 40 graphs
#define BN   (BB*NN)        // 16384
#define NM   (GG*NN)        // 81920 rows (= TT*BN)
#define NE   ((long)GG*EE)  // 1310720 edges

#define MR        20480           // rows per FFN chunk (4 chunks)

typedef __attribute__((ext_vector_type(8))) short short8;
typedef __attribute__((ext_vector_type(4))) float f32x4;

// ---- bf16 helpers (RNE) ----
__device__ __forceinline__ unsigned short f2b(float f) {
    unsigned u = __float_as_uint(f);
    u = (u + 0x7fffu + ((u >> 16) & 1u)) >> 16;
    return (unsigned short)u;
}
__device__ __forceinline__ float b2f(unsigned short b) {
    return __uint_as_float(((unsigned)b) << 16);
}

// async global->LDS, 16B per lane (dest must be wave-uniform base + lane*16)
__device__ __forceinline__ void gload_lds16(const void* g, void* l) {
    __builtin_amdgcn_global_load_lds(
        (__attribute__((address_space(1))) void*)g,
        (__attribute__((address_space(3))) void*)l, 16, 0, 0);
}

// =====================================================================
// Weight transpose+convert: fp32 [K][N] -> bf16 [N][K]
// =====================================================================
__device__ __forceinline__ void wtrans_body(const float* in, unsigned short* out,
                                            int K, int N, int bx, int by) {
    __shared__ float t[32][33];
    const int n0 = bx * 32, k0 = by * 32;
    const int tx = threadIdx.x, ty = threadIdx.y;
    for (int i = ty; i < 32; i += 8) t[i][tx] = in[(long)(k0 + i) * N + n0 + tx];
    __syncthreads();
    for (int i = ty; i < 32; i += 8)
        out[(long)(n0 + i) * K + k0 + tx] = f2b(t[tx][i]);
}

__global__ void wtrans(const float* __restrict__ in, unsigned short* __restrict__ out,
                       int K, int N) {
    wtrans_body(in, out, K, N, blockIdx.x, blockIdx.y);
}

// 4 same-shape [256][256] matrices, z selects
__global__ void wtrans4(const float* __restrict__ a, const float* __restrict__ b,
                        const float* __restrict__ c, const float* __restrict__ d,
                        unsigned short* __restrict__ out) {
    const float* src = (blockIdx.z == 0) ? a : (blockIdx.z == 1) ? b
                     : (blockIdx.z == 2) ? c : d;
    wtrans_body(src, out + (long)blockIdx.z * 65536, DD, DD, blockIdx.x, blockIdx.y);
}

// layer-strided: z = layer
__global__ void wtrans_s(const float* __restrict__ in, long sstride,
                         unsigned short* __restrict__ out, long dstride,
                         int K, int N) {
    wtrans_body(in + (long)blockIdx.z * sstride, out + (long)blockIdx.z * dstride,
                K, N, blockIdx.x, blockIdx.y);
}

// fp32 -> bf16 elementwise (n4 float4 groups)
__global__ void xconvert(const float* __restrict__ in, unsigned short* __restrict__ out, long n4) {
    long gid = (long)blockIdx.x * blockDim.x + threadIdx.x;
    if (gid >= n4) return;
    float4 v = ((const float4*)in)[gid];
    ushort4 o;
    o.x = f2b(v.x); o.y = f2b(v.y); o.z = f2b(v.z); o.w = f2b(v.w);
    ((ushort4*)out)[gid] = o;
}

// pack 3 bias vectors of 256 into one 768 buffer
__global__ void pack3(const float* __restrict__ a, const float* __restrict__ b,
                      const float* __restrict__ c, float* __restrict__ o) {
    int i = threadIdx.x;
    o[i] = a[i]; o[256 + i] = b[i]; o[512 + i] = c[i];
}

// =====================================================================
// bf16 MFMA GEMM v2: 256x128 tile, 512 threads = 8 waves (4M x 2N),
// BK=64 + rule-21 XOR swizzle.
// =====================================================================
template <bool RELU, bool OUTBF>
__global__ __launch_bounds__(512) void gemm_mfma2(
    const unsigned short* __restrict__ A, int lda,
    const unsigned short* __restrict__ WT,
    const float* __restrict__ bias,
    void* __restrict__ Cv, int ldc, int K)
{
    __shared__ unsigned short As[256 * 64];
    __shared__ unsigned short Bs[128 * 64];
    const int tid = threadIdx.x;
    const int wid = tid >> 6, lane = tid & 63;
    const int wm = wid >> 1, wn = wid & 1;     // 4 x 2 wave grid
    const int gx = gridDim.x, gy = gridDim.y;
    int bx = blockIdx.x, by = blockIdx.y;
    if ((gx & 7) == 0) {
        const int lbid = bx + gx * by;
        const int xcd = lbid & 7;
        const int i = lbid >> 3;
        const int CX = gx >> 3;
        bx = xcd * CX + i / gy;
        by = i - (i / gy) * gy;
    }
    const long row0 = (long)bx * 256;
    const long col0 = (long)by * 128;
    const int srow = tid >> 3;            // 0..63 (per pass)
    const int schunk = tid & 7;           // 16B chunk in 128B row
    const int fr = lane & 15;
    const int q = lane >> 4;
    f32x4 acc[4][4] = {};
    for (int k0 = 0; k0 < K; k0 += 64) {
        __syncthreads();
#pragma unroll
        for (int p = 0; p < 4; ++p) {
            const int row = p * 64 + srow;
            const int sc = (schunk ^ (row & 7)) * 8;
            gload_lds16(&A[(row0 + row) * (long)lda + k0 + sc], As + row * 64 + schunk * 8);
        }
#pragma unroll
        for (int p = 0; p < 2; ++p) {
            const int row = p * 64 + srow;
            const int sc = (schunk ^ (row & 7)) * 8;
            gload_lds16(&WT[(col0 + row) * (long)K + k0 + sc], Bs + row * 64 + schunk * 8);
        }
        __syncthreads();
#pragma unroll
        for (int kk = 0; kk < 2; ++kk) {
            short8 af[4], bfr[4];
#pragma unroll
            for (int mf = 0; mf < 4; ++mf) {
                const int row = wm * 64 + mf * 16 + fr;
                const int byo = (row * 128 + kk * 64 + q * 16) ^ ((row & 7) << 4);
                af[mf] = *(const short8*)((const char*)As + byo);
            }
#pragma unroll
            for (int nf = 0; nf < 4; ++nf) {
                const int row = wn * 64 + nf * 16 + fr;
                const int byo = (row * 128 + kk * 64 + q * 16) ^ ((row & 7) << 4);
                bfr[nf] = *(const short8*)((const char*)Bs + byo);
            }
#pragma unroll
            for (int mf = 0; mf < 4; ++mf)
#pragma unroll
                for (int nf = 0; nf < 4; ++nf)
                    acc[mf][nf] = __builtin_amdgcn_mfma_f32_16x16x32_bf16(
                        af[mf], bfr[nf], acc[mf][nf], 0, 0, 0);
        }
    }
#pragma unroll
    for (int nf = 0; nf < 4; ++nf) {
        const long col = col0 + wn * 64 + nf * 16 + fr;
        const float bv = bias[col];
#pragma unroll
        for (int mf = 0; mf < 4; ++mf) {
#pragma unroll
            for (int i = 0; i < 4; ++i) {
                const long r = row0 + wm * 64 + mf * 16 + q * 4 + i;
                float vv = acc[mf][nf][i] + bv;
                if (RELU) vv = fmaxf(vv, 0.f);
                if (OUTBF) ((unsigned short*)Cv)[r * ldc + col] = f2b(vv);
                else       ((float*)Cv)[r * ldc + col] = vv;
            }
        }
    }
}

// =====================================================================
// Fused GEMM + residual + LayerNorm, 128x256 tile (full LN row), 512
// threads = 8 waves (2M x 4N). Same staging economics as gemm_mfma2.
// seq[M][256] = LN(seq + A @ W + bias) * g + b   (in place over seq)
// =====================================================================
__global__ __launch_bounds__(512) void gemm_wo_ln(
    const unsigned short* __restrict__ A, int lda,
    const unsigned short* __restrict__ WT,
    const float* __restrict__ bias,
    unsigned short* __restrict__ seq,
    const float* __restrict__ g, const float* __restrict__ b, int K)
{
    __shared__ unsigned short As[128 * 64];
    __shared__ unsigned short Bs[256 * 64];
    __shared__ float Lsum[128][4];
    __shared__ float Lsq[128][4];
    const int tid = threadIdx.x;
    const int wid = tid >> 6, lane = tid & 63;
    const int wm = wid >> 2, wn = wid & 3;     // 2 x 4 wave grid
    const int gx = gridDim.x;
    int bx = blockIdx.x;
    if ((gx & 7) == 0) bx = (bx & 7) * (gx >> 3) + (bx >> 3);
    const long row0 = (long)bx * 128;
    const int srow = tid >> 3;            // 0..63 per pass
    const int schunk = tid & 7;
    const int fr = lane & 15;
    const int q = lane >> 4;
    f32x4 acc[4][4] = {};
    for (int k0 = 0; k0 < K; k0 += 64) {
        __syncthreads();
#pragma unroll
        for (int p = 0; p < 2; ++p) {
            const int row = p * 64 + srow;
            const int sc = (schunk ^ (row & 7)) * 8;
            gload_lds16(&A[(row0 + row) * (long)lda + k0 + sc], As + row * 64 + schunk * 8);
        }
#pragma unroll
        for (int p = 0; p < 4; ++p) {
            const int row = p * 64 + srow;
            const int sc = (schunk ^ (row & 7)) * 8;
            gload_lds16(&WT[(long)row * K + k0 + sc], Bs + row * 64 + schunk * 8);
        }
        __syncthreads();
#pragma unroll
        for (int kk = 0; kk < 2; ++kk) {
            short8 af[4], bfr[4];
#pragma unroll
            for (int mf = 0; mf < 4; ++mf) {
                const int row = wm * 64 + mf * 16 + fr;
                const int byo = (row * 128 + kk * 64 + q * 16) ^ ((row & 7) << 4);
                af[mf] = *(const short8*)((const char*)As + byo);
            }
#pragma unroll
            for (int nf = 0; nf < 4; ++nf) {
                const int row = wn * 64 + nf * 16 + fr;
                const int byo = (row * 128 + kk * 64 + q * 16) ^ ((row & 7) << 4);
                bfr[nf] = *(const short8*)((const char*)Bs + byo);
            }
#pragma unroll
            for (int mf = 0; mf < 4; ++mf)
#pragma unroll
                for (int nf = 0; nf < 4; ++nf)
                    acc[mf][nf] = __builtin_amdgcn_mfma_f32_16x16x32_bf16(
                        af[mf], bfr[nf], acc[mf][nf], 0, 0, 0);
        }
    }
    // epilogue: acc += bias + residual(seq)
#pragma unroll
    for (int nf = 0; nf < 4; ++nf) {
        const int col = wn * 64 + nf * 16 + fr;
        const float bv = bias[col];
#pragma unroll
        for (int mf = 0; mf < 4; ++mf)
#pragma unroll
            for (int i = 0; i < 4; ++i) {
                const long r = row0 + wm * 64 + mf * 16 + q * 4 + i;
                acc[mf][nf][i] += bv + b2f(seq[r * 256 + col]);
            }
    }
    // per-row stats: in-thread over nf, shfl over fr group, LDS across wn
#pragma unroll
    for (int mf = 0; mf < 4; ++mf)
#pragma unroll
        for (int i = 0; i < 4; ++i) {
            float s = acc[mf][0][i] + acc[mf][1][i] + acc[mf][2][i] + acc[mf][3][i];
            float s2 = acc[mf][0][i] * acc[mf][0][i] + acc[mf][1][i] * acc[mf][1][i]
                     + acc[mf][2][i] * acc[mf][2][i] + acc[mf][3][i] * acc[mf][3][i];
#pragma unroll
            for (int m = 1; m <= 8; m <<= 1) {
                s += __shfl_xor(s, m, 64);
                s2 += __shfl_xor(s2, m, 64);
            }
            if (fr == 0) {
                const int lr = wm * 64 + mf * 16 + q * 4 + i;
                Lsum[lr][wn] = s;
                Lsq[lr][wn] = s2;
            }
        }
    __syncthreads();
#pragma unroll
    for (int mf = 0; mf < 4; ++mf)
#pragma unroll
        for (int i = 0; i < 4; ++i) {
            const int lr = wm * 64 + mf * 16 + q * 4 + i;
            const float sum = Lsum[lr][0] + Lsum[lr][1] + Lsum[lr][2] + Lsum[lr][3];
            const float sq  = Lsq[lr][0] + Lsq[lr][1] + Lsq[lr][2] + Lsq[lr][3];
            const float mean = sum * (1.f / 256.f);
            const float var = sq * (1.f / 256.f) - mean * mean;
            const float inv = rsqrtf(var + 1e-5f);
            const long r = row0 + lr;
#pragma unroll
            for (int nf = 0; nf < 4; ++nf) {
                const int col = wn * 64 + nf * 16 + fr;
                seq[r * 256 + col] = f2b((acc[mf][nf][i] - mean) * inv * g[col] + b[col]);
            }
        }
}

// =====================================================================
// bf16 MFMA GEMM (128 x 64, NF=2) — kept for W2 (2 blocks/CU win, R14).
// =====================================================================
template <bool RELU, bool OUTBF, int NF>
__global__ __launch_bounds__(256) void gemm_mfma(
    const unsigned short* __restrict__ A, int lda,
    const unsigned short* __restrict__ WT,
    const float* __restrict__ bias,
    void* __restrict__ Cv, int ldc, int K)
{
    __shared__ unsigned short As[128 * 64];
    __shared__ unsigned short Bs[32 * NF * 64];
    const int tid = threadIdx.x;
    const int wid = tid >> 6, lane = tid & 63;
    const int wm = wid >> 1, wn = wid & 1;
    const int gx = gridDim.x, gy = gridDim.y;
    int bx = blockIdx.x, by = blockIdx.y;
    if ((gx & 7) == 0) {
        const int lbid = bx + gx * by;
        const int xcd = lbid & 7;
        const int i = lbid >> 3;
        const int CX = gx >> 3;
        bx = xcd * CX + i / gy;
        by = i - (i / gy) * gy;
    }
    const long row0 = (long)bx * 128;
    const long col0 = (long)by * (32 * NF);
    const int srow = tid >> 3;
    const int schunk = tid & 7;
    const int fr = lane & 15;
    const int q = lane >> 4;
    f32x4 acc[4][NF] = {};
    for (int k0 = 0; k0 < K; k0 += 64) {
        __syncthreads();
#pragma unroll
        for (int p = 0; p < 4; ++p) {
            const int row = p * 32 + srow;
            const int sc = (schunk ^ (row & 7)) * 8;
            gload_lds16(&A[(row0 + row) * (long)lda + k0 + sc], As + row * 64 + schunk * 8);
        }
#pragma unroll
        for (int p = 0; p < NF; ++p) {
            const int row = p * 32 + srow;
            const int sc = (schunk ^ (row & 7)) * 8;
            gload_lds16(&WT[(col0 + row) * (long)K + k0 + sc], Bs + row * 64 + schunk * 8);
        }
        __syncthreads();
#pragma unroll
        for (int kk = 0; kk < 2; ++kk) {
            short8 af[4], bfr[NF];
#pragma unroll
            for (int mf = 0; mf < 4; ++mf) {
                const int row = wm * 64 + mf * 16 + fr;
                const int byo = (row * 128 + kk * 64 + q * 16) ^ ((row & 7) << 4);
                af[mf] = *(const short8*)((const char*)As + byo);
            }
#pragma unroll
            for (int nf = 0; nf < NF; ++nf) {
                const int row = wn * (NF * 16) + nf * 16 + fr;
                const int byo = (row * 128 + kk * 64 + q * 16) ^ ((row & 7) << 4);
                bfr[nf] = *(const short8*)((const char*)Bs + byo);
            }
#pragma unroll
            for (int mf = 0; mf < 4; ++mf)
#pragma unroll
                for (int nf = 0; nf < NF; ++nf)
                    acc[mf][nf] = __builtin_amdgcn_mfma_f32_16x16x32_bf16(
                        af[mf], bfr[nf], acc[mf][nf], 0, 0, 0);
        }
    }
#pragma unroll
    for (int nf = 0; nf < NF; ++nf) {
        const long col = col0 + wn * (NF * 16) + nf * 16 + fr;
        const float bv = bias[col];
#pragma unroll
        for (int mf = 0; mf < 4; ++mf) {
#pragma unroll
            for (int i = 0; i < 4; ++i) {
                const long r = row0 + wm * 64 + mf * 16 + q * 4 + i;
                float vv = acc[mf][nf][i] + bv;
                if (RELU) vv = fmaxf(vv, 0.f);
                if (OUTBF) ((unsigned short*)Cv)[r * ldc + col] = f2b(vv);
                else       ((float*)Cv)[r * ldc + col] = vv;
            }
        }
    }
}

// =====================================================================
// CSR build. pcsr entry packs (srcrow << 15) | e.
// =====================================================================
__global__ void csr_init(int* __restrict__ cnt, int* __restrict__ fill) {
    int gid = blockIdx.x * blockDim.x + threadIdx.x;
    if (gid < NM) { cnt[gid] = 0; fill[gid] = 0; }
}

__global__ void csr_count(const int* __restrict__ eidx, int* __restrict__ cnt) {
    long el = (long)blockIdx.x * blockDim.x + threadIdx.x;
    if (el >= NE) return;
    int g = (int)(el >> 15), e = (int)(el & (EE - 1));
    int tgt = eidx[((long)g * 2 + 1) * EE + e];
    atomicAdd(&cnt[g * NN + tgt], 1);
}

__global__ __launch_bounds__(1024) void csr_scan(const int* __restrict__ cnt, int* __restrict__ off) {
    __shared__ int part[1024];
    const int t = threadIdx.x;
    const int base = t * (NM / 1024);
    int s = 0;
    for (int i = 0; i < NM / 1024; ++i) s += cnt[base + i];
    part[t] = s;
    __syncthreads();
    for (int d = 1; d < 1024; d <<= 1) {
        int v = (t >= d) ? part[t - d] : 0;
        __syncthreads();
        part[t] += v;
        __syncthreads();
    }
    int run = (t == 0) ? 0 : part[t - 1];
    for (int i = 0; i < NM / 1024; ++i) { off[base + i] = run; run += cnt[base + i]; }
    if (t == 1023) off[NM] = run;
}

__global__ void csr_scatter(const int* __restrict__ eidx, const int* __restrict__ off,
                            int* __restrict__ fill, unsigned* __restrict__ pcsr) {
    long el = (long)blockIdx.x * blockDim.x + threadIdx.x;
    if (el >= NE) return;
    int g = (int)(el >> 15), e = (int)(el & (EE - 1));
    int src = eidx[((long)g * 2 + 0) * EE + e];
    int tgt = eidx[((long)g * 2 + 1) * EE + e];
    int tf = g * NN + tgt;
    int pos = atomicAdd(&fill[tf], 1);
    pcsr[off[tf] + pos] = ((unsigned)(g * NN + src) << 15) | (unsigned)e;
}

// =====================================================================
// Fused TransformerConv on interleaved qkv [NM][768]; packed CSR records.
// =====================================================================
__global__ __launch_bounds__(256) void conv_fused(
    unsigned short* __restrict__ Z,
    const float* __restrict__ eattr,
    const float* __restrict__ W_edge, const float* __restrict__ b_edge,
    const int* __restrict__ off, const unsigned* __restrict__ pcsr)
{
    const int tid = threadIdx.x;
    const int wave = tid >> 6, lane = tid & 63;
    const int bid = (blockIdx.x & 7) * (NM / 4 / 8) + (blockIdx.x >> 3);
    const long tf = (long)bid * 4 + wave;
    const int d0 = lane * 4;
    unsigned short* qrow = &Z[tf * 768];
    const ushort4 q4 = *(const ushort4*)&qrow[d0];
    const float q0 = b2f(q4.x), q1 = b2f(q4.y), q2 = b2f(q4.z), q3 = b2f(q4.w);
    const float be0 = b_edge[d0], be1 = b_edge[d0 + 1],
                be2 = b_edge[d0 + 2], be3 = b_edge[d0 + 3];
    float w0[6], w1r[6], w2r[6], w3r[6];
#pragma unroll
    for (int j2 = 0; j2 < 6; ++j2) {
        const float* wp = &W_edge[j2 * 256 + d0];
        w0[j2] = wp[0]; w1r[j2] = wp[1]; w2r[j2] = wp[2]; w3r[j2] = wp[3];
    }
    float qb = q0 * be0 + q1 * be1 + q2 * be2 + q3 * be3;
    float qw[6];
#pragma unroll
    for (int j2 = 0; j2 < 6; ++j2)
        qw[j2] = q0 * w0[j2] + q1 * w1r[j2] + q2 * w2r[j2] + q3 * w3r[j2];
#pragma unroll
    for (int mm = 1; mm <= 4; mm <<= 1) {
        qb += __shfl_xor(qb, mm, 64);
#pragma unroll
        for (int j2 = 0; j2 < 6; ++j2) qw[j2] += __shfl_xor(qw[j2], mm, 64);
    }
    const float scale = 0.17677669529663687f;  // 1/sqrt(32)
    float s = 0.f, a0 = 0.f, a1 = 0.f, a2 = 0.f, a3 = 0.f;
    float t0 = 0.f, t1 = 0.f, t2 = 0.f, t3 = 0.f, t4 = 0.f, t5 = 0.f;
    const int jb = off[tf], je = off[tf + 1];
    ushort4 kc, vc; float eac[6];
    if (jb < je) {
        const unsigned pk = pcsr[jb];
        const long sf = pk >> 15;
        kc = *(const ushort4*)&Z[sf * 768 + 256 + d0];
        vc = *(const ushort4*)&Z[sf * 768 + 512 + d0];
        const long el = (sf >> 11) * EE + (pk & 32767u);
#pragma unroll
        for (int t = 0; t < 6; ++t) eac[t] = eattr[el * 6 + t];
    }
    for (int j = jb; j < je; ++j) {
        ushort4 kn, vn; float ean[6];
        if (j + 1 < je) {  // prefetch next edge (wave-uniform branch)
            const unsigned pk = pcsr[j + 1];
            const long sf = pk >> 15;
            kn = *(const ushort4*)&Z[sf * 768 + 256 + d0];
            vn = *(const ushort4*)&Z[sf * 768 + 512 + d0];
            const long el = (sf >> 11) * EE + (pk & 32767u);
#pragma unroll
            for (int t = 0; t < 6; ++t) ean[t] = eattr[el * 6 + t];
        }
        float p = q0 * b2f(kc.x) + q1 * b2f(kc.y) + q2 * b2f(kc.z) + q3 * b2f(kc.w);
        p += __shfl_xor(p, 1, 64);
        p += __shfl_xor(p, 2, 64);
        p += __shfl_xor(p, 4, 64);
        float alpha = p + qb;
        alpha += eac[0] * qw[0] + eac[1] * qw[1] + eac[2] * qw[2]
               + eac[3] * qw[3] + eac[4] * qw[4] + eac[5] * qw[5];
        const float a = __expf(alpha * scale);
        s += a;
        a0 += a * b2f(vc.x); a1 += a * b2f(vc.y);
        a2 += a * b2f(vc.z); a3 += a * b2f(vc.w);
        t0 += a * eac[0]; t1 += a * eac[1]; t2 += a * eac[2];
        t3 += a * eac[3]; t4 += a * eac[4]; t5 += a * eac[5];
        kc = kn; vc = vn;
#pragma unroll
        for (int t = 0; t < 6; ++t) eac[t] = ean[t];
    }
    const float inv = (s > 0.f) ? 1.f / s : 0.f;
    float o0 = a0 + be0 * s, o1 = a1 + be1 * s, o2 = a2 + be2 * s, o3 = a3 + be3 * s;
    o0 += w0[0]*t0 + w0[1]*t1 + w0[2]*t2 + w0[3]*t3 + w0[4]*t4 + w0[5]*t5;
    o1 += w1r[0]*t0 + w1r[1]*t1 + w1r[2]*t2 + w1r[3]*t3 + w1r[4]*t4 + w1r[5]*t5;
    o2 += w2r[0]*t0 + w2r[1]*t1 + w2r[2]*t2 + w2r[3]*t3 + w2r[4]*t4 + w2r[5]*t5;
    o3 += w3r[0]*t0 + w3r[1]*t1 + w3r[2]*t2 + w3r[3]*t3 + w3r[4]*t4 + w3r[5]*t5;
    ushort4 o;
    o.x = f2b(o0 * inv); o.y = f2b(o1 * inv);
    o.z = f2b(o2 * inv); o.w = f2b(o3 * inv);
    *(ushort4*)&qrow[d0] = o;
}

// seq(bf16, [t*BN+b*N+n][256]) = conv(q-slice of Z) + skip(k-slice of Z)
__global__ void transpose_add(const unsigned short* __restrict__ Z,
                              unsigned short* __restrict__ out) {
    long gid = (long)blockIdx.x * blockDim.x + threadIdx.x;
    long row = gid >> 6;
    int c4 = (int)(gid & 63);
    int n = (int)(row % NN);
    int bt = (int)(row / NN);
    int t = bt % TT, b = bt / TT;
    long orow = (long)t * BN + (long)b * NN + n;
    ushort4 cv = ((const ushort4*)&Z[row * 768])[c4];
    ushort4 sv = ((const ushort4*)&Z[row * 768 + 256])[c4];
    ushort4 o;
    o.x = f2b(b2f(cv.x) + b2f(sv.x));
    o.y = f2b(b2f(cv.y) + b2f(sv.y));
    o.z = f2b(b2f(cv.z) + b2f(sv.z));
    o.w = f2b(b2f(cv.w) + b2f(sv.w));
    ((ushort4*)out)[orow * 64 + c4] = o;
}

// =====================================================================
// temporal attention v2: one 64-lane wave per node bn.
// =====================================================================
__global__ __launch_bounds__(256) void mha_time(unsigned short* __restrict__ Z)
{
    const int tid = threadIdx.x;
    const int wave = tid >> 6, lane = tid & 63;
    const long bn = (long)blockIdx.x * 4 + wave;
    const int d0 = lane * 4;
    const float scale = 0.17677669529663687f;
    float qv[TT][4], kv[TT][4], vv[TT][4];
    long r[TT];
#pragma unroll
    for (int t = 0; t < TT; ++t) {
        r[t] = ((long)t * BN + bn) * 768 + d0;
        const ushort4 qq = *(const ushort4*)&Z[r[t]];
        const ushort4 kk = *(const ushort4*)&Z[r[t] + 256];
        const ushort4 vx = *(const ushort4*)&Z[r[t] + 512];
        qv[t][0] = b2f(qq.x); qv[t][1] = b2f(qq.y); qv[t][2] = b2f(qq.z); qv[t][3] = b2f(qq.w);
        kv[t][0] = b2f(kk.x); kv[t][1] = b2f(kk.y); kv[t][2] = b2f(kk.z); kv[t][3] = b2f(kk.w);
        vv[t][0] = b2f(vx.x); vv[t][1] = b2f(vx.y); vv[t][2] = b2f(vx.z); vv[t][3] = b2f(vx.w);
    }
    float s[TT][TT];
#pragma unroll
    for (int t = 0; t < TT; ++t)
#pragma unroll
        for (int u = 0; u < TT; ++u) {
            float p = qv[t][0] * kv[u][0] + qv[t][1] * kv[u][1]
                    + qv[t][2] * kv[u][2] + qv[t][3] * kv[u][3];
            p += __shfl_xor(p, 1, 64);
            p += __shfl_xor(p, 2, 64);
            p += __shfl_xor(p, 4, 64);   // 8-lane group = one head
            s[t][u] = p * scale;
        }
#pragma unroll
    for (int t = 0; t < TT; ++t) {
        float mx = s[t][0];
#pragma unroll
        for (int u = 1; u < TT; ++u) mx = fmaxf(mx, s[t][u]);
        float sm = 0.f;
#pragma unroll
        for (int u = 0; u < TT; ++u) { s[t][u] = __expf(s[t][u] - mx); sm += s[t][u]; }
        const float inv = 1.f / sm;
        float o0 = 0.f, o1 = 0.f, o2 = 0.f, o3 = 0.f;
#pragma unroll
        for (int u = 0; u < TT; ++u) {
            o0 += s[t][u] * vv[u][0]; o1 += s[t][u] * vv[u][1];
            o2 += s[t][u] * vv[u][2]; o3 += s[t][u] * vv[u][3];
        }
        ushort4 o;
        o.x = f2b(o0 * inv); o.y = f2b(o1 * inv);
        o.z = f2b(o2 * inv); o.w = f2b(o3 * inv);
        *(ushort4*)&Z[r[t]] = o;
    }
}

// seq(bf16) = LayerNorm(seq + res(bf16, row-stride rstride)) * g + b
__global__ __launch_bounds__(256) void ln_residual(
    unsigned short* __restrict__ seq, const unsigned short* __restrict__ res,
    int rstride, const float* __restrict__ g, const float* __restrict__ b)
{
    const int wave = threadIdx.x >> 6, lane = threadIdx.x & 63;
    long row = (long)blockIdx.x * 4 + wave;
    const ushort4 s4 = *(const ushort4*)&seq[row * 256 + lane * 4];
    const ushort4 r4 = *(const ushort4*)&res[row * (long)rstride + lane * 4];
    float x[4] = { b2f(s4.x) + b2f(r4.x), b2f(s4.y) + b2f(r4.y),
                   b2f(s4.z) + b2f(r4.z), b2f(s4.w) + b2f(r4.w) };
    float sum = x[0] + x[1] + x[2] + x[3];
#pragma unroll
    for (int m = 32; m >= 1; m >>= 1) sum += __shfl_xor(sum, m, 64);
    float mean = sum * (1.f / 256.f);
    float vs = 0.f;
#pragma unroll
    for (int i = 0; i < 4; ++i) { float dl = x[i] - mean; vs += dl * dl; }
#pragma unroll
    for (int m = 32; m >= 1; m >>= 1) vs += __shfl_xor(vs, m, 64);
    float inv = rsqrtf(vs * (1.f / 256.f) + 1e-5f);
    ushort4 o;
    o.x = f2b((x[0] - mean) * inv * g[lane * 4 + 0] + b[lane * 4 + 0]);
    o.y = f2b((x[1] - mean) * inv * g[lane * 4 + 1] + b[lane * 4 + 1]);
    o.z = f2b((x[2] - mean) * inv * g[lane * 4 + 2] + b[lane * 4 + 2]);
    o.w = f2b((x[3] - mean) * inv * g[lane * 4 + 3] + b[lane * 4 + 3]);
    *(ushort4*)&seq[row * 256 + lane * 4] = o;
}

// out[row][0..9] = seq[t=T-1 rows](bf16) @ W_out + b_out ; one block per row
__global__ __launch_bounds__(256) void final_out(
    const unsigned short* __restrict__ seq, const float* __restrict__ Wd,
    const float* __restrict__ bd, float* __restrict__ out)
{
    __shared__ float xs[256];
    long row = blockIdx.x;
    xs[threadIdx.x] = b2f(seq[((long)(TT - 1) * BN + row) * 256 + threadIdx.x]);
    __syncthreads();
    const int wv = threadIdx.x >> 6, lane = threadIdx.x & 63;
    for (int o = wv; o < NCLS; o += 4) {
        float p = 0.f;
#pragma unroll
        for (int i = 0; i < 4; ++i) {
            int kk = lane + 64 * i;
            p += xs[kk] * Wd[kk * NCLS + o];
        }
#pragma unroll
        for (int m = 32; m >= 1; m >>= 1) p += __shfl_xor(p, m, 64);
        if (lane == 0) out[row * NCLS + o] = p + bd[o];
    }
}

__global__ void fill_sentinel(float* __restrict__ out, int n) {
    int gid = blockIdx.x * blockDim.x + threadIdx.x;
    if (gid < n) out[gid] = 1.0e6f;
}

// =====================================================================
extern "C" void kernel_launch(void* const* d_in, const int* in_sizes, int n_in,
                              void* d_out, int out_size, void* d_ws, size_t ws_size,
                              hipStream_t stream) {
    const float* xseq  = (const float*)d_in[0];
    const int*   eidx  = (const int*)d_in[1];
    const float* eattr = (const float*)d_in[2];
    const float* W_node = (const float*)d_in[3];
    const float* b_node = (const float*)d_in[4];
    const float* W_edge = (const float*)d_in[5];
    const float* b_edge = (const float*)d_in[6];
    const float* Wq = (const float*)d_in[7];  const float* bq = (const float*)d_in[8];
    const float* Wk = (const float*)d_in[9];  const float* bk = (const float*)d_in[10];
    const float* Wv = (const float*)d_in[11]; const float* bv = (const float*)d_in[12];
    const float* Ws = (const float*)d_in[13]; const float* bs = (const float*)d_in[14];
    const float* Wqkv = (const float*)d_in[15]; const float* bqkv = (const float*)d_in[16];
    const float* Wo = (const float*)d_in[17];   const float* bo = (const float*)d_in[18];
    const float* W1 = (const float*)d_in[19];   const float* b1 = (const float*)d_in[20];
    const float* W2 = (const float*)d_in[21];   const float* b2 = (const float*)d_in[22];
    const float* g_ln1 = (const float*)d_in[23]; const float* b_ln1 = (const float*)d_in[24];
    const float* g_ln2 = (const float*)d_in[25]; const float* b_ln2 = (const float*)d_in[26];
    const float* W_out = (const float*)d_in[27]; const float* b_out = (const float*)d_in[28];
    float* out = (float*)d_out;

    // ---- workspace layout ----
    const long SZ = (long)NM * DD;            // 20,971,520 elements
    unsigned short* Abf = (unsigned short*)d_ws;     // seq activations bf16 (40MB)
    unsigned short* Zu  = Abf + SZ;                  // qkv interleaved [NM][768] (120MB)
    unsigned short* Hid = Zu;                        // FFN hidden bf16 [MR][2048] (80MB)
    unsigned short* res2B = Zu + (long)MR * FFD;     // FFN residual bf16 [MR][256] (10MB)
    unsigned short* WX = Zu + 3 * SZ;
    unsigned short* xbf = WX;                             // 81920*64
    unsigned short* wtN = xbf + (long)NM * FIN;           // [256][64]
    unsigned short* wtQ = wtN + 256 * 64;                 // [768][256] stacked q,k,v
    unsigned short* wtS = wtQ + 3L * 65536;
    unsigned short* wtQKV = wtS + 65536;                  // 3 * [768][256]
    unsigned short* wtO = wtQKV + 3L * 768 * 256;         // 3 * [256][256]
    unsigned short* wtW1 = wtO + 3L * 65536;              // 3 * [2048][256]
    unsigned short* wtW2 = wtW1 + 3L * 2048 * 256;        // 3 * [256][2048]
    int* cnt  = (int*)(wtW2 + 3L * 256 * 2048);
    int* coff = cnt + NM;                                 // NM+1
    int* cfil = coff + NM + 1;
    unsigned* pcsr = (unsigned*)(cfil + NM);              // NE packed records
    float* qkvb = (float*)(pcsr + NE);                    // 768 packed bias
    char* wend = (char*)(qkvb + 768);
    const size_t need = (size_t)(wend - (char*)d_ws);
    if (ws_size < need) {
        fill_sentinel<<<dim3((out_size + 255) / 256), dim3(256), 0, stream>>>(out, out_size);
        return;
    }

    dim3 blk(256);
    dim3 blk5(512);
    dim3 tb(32, 8);

    // ---- prologue (batched weight conversion) ----
    xconvert<<<dim3((unsigned)((long)NM * FIN / 4 / 256)), blk, 0, stream>>>(xseq, xbf, (long)NM * FIN / 4);
    wtrans<<<dim3(DD / 32, FIN / 32), tb, 0, stream>>>(W_node, wtN, FIN, DD);
    wtrans4<<<dim3(DD / 32, DD / 32, 4), tb, 0, stream>>>(Wq, Wk, Wv, Ws, wtQ);
    wtrans_s<<<dim3(768 / 32, DD / 32, 3), tb, 0, stream>>>(Wqkv, (long)DD * 768, wtQKV, 768L * 256, DD, 768);
    wtrans_s<<<dim3(DD / 32, DD / 32, 3), tb, 0, stream>>>(Wo, (long)DD * DD, wtO, 65536L, DD, DD);
    wtrans_s<<<dim3(FFD / 32, DD / 32, 3), tb, 0, stream>>>(W1, (long)DD * FFD, wtW1, 2048L * 256, DD, FFD);
    wtrans_s<<<dim3(DD / 32, FFD / 32, 3), tb, 0, stream>>>(W2, (long)FFD * DD, wtW2, 256L * 2048, FFD, DD);
    pack3<<<dim3(1), blk, 0, stream>>>(bq, bk, bv, qkvb);

    // ---- CSR build (packed records) ----
    csr_init<<<dim3((NM + 255) / 256), blk, 0, stream>>>(cnt, cfil);
    csr_count<<<dim3((unsigned)(NE / 256)), blk, 0, stream>>>(eidx, cnt);
    csr_scan<<<dim3(1), dim3(1024), 0, stream>>>(cnt, coff);
    csr_scatter<<<dim3((unsigned)(NE / 256)), blk, 0, stream>>>(eidx, coff, cfil, pcsr);

    // ---- stage 1 ----
    gemm_mfma2<false, true><<<dim3(NM / 256, DD / 128), blk5, 0, stream>>>(
        xbf, FIN, wtN, b_node, Abf, DD, FIN);
    gemm_mfma2<false, true><<<dim3(NM / 256, 768 / 128), blk5, 0, stream>>>(
        Abf, DD, wtQ, qkvb, Zu, 768, DD);
    conv_fused<<<dim3(NM / 4), blk, 0, stream>>>(
        Zu, eattr, W_edge, b_edge, coff, pcsr);
    gemm_mfma2<false, true><<<dim3(NM / 256, DD / 128), blk5, 0, stream>>>(
        Abf, DD, wtS, bs, (void*)(Zu + 256), 768, DD);
    transpose_add<<<dim3(NM * 64 / 256), blk, 0, stream>>>(Zu, Abf);

    // ---- stage 2: 3 temporal transformer encoder layers ----
    for (int l = 0; l < 3; ++l) {
        gemm_mfma2<false, true><<<dim3(NM / 256, 768 / 128), blk5, 0, stream>>>(
            Abf, DD, wtQKV + (long)l * 768 * 256, bqkv + (long)l * 768, Zu, 768, DD);
        mha_time<<<dim3(BN / 4), blk, 0, stream>>>(Zu);
        // fused Wo + residual + LN1 (128x256 tile, in place over Abf)
        gemm_wo_ln<<<dim3(NM / 128), blk5, 0, stream>>>(
            Zu, 768, wtO + (long)l * 65536, bo + (long)l * DD,
            Abf, g_ln1 + l * DD, b_ln1 + l * DD, DD);
        // unfused FFN (4 chunks of 20480 rows); W2 keeps the NF=2 128x64 tile
        for (int mr = 0; mr < NM / MR; ++mr) {
            const long r0 = (long)mr * MR;
            gemm_mfma2<true, true><<<dim3(MR / 256, FFD / 128), blk5, 0, stream>>>(
                Abf + r0 * DD, DD, wtW1 + (long)l * 2048 * 256, b1 + (long)l * FFD, Hid, FFD, DD);
            gemm_mfma<false, true, 2><<<dim3(MR / 128, DD / 64), blk, 0, stream>>>(
                Hid, FFD, wtW2 + (long)l * 256 * 2048, b2 + (long)l * DD, res2B, DD, FFD);
            ln_residual<<<dim3(MR / 4), blk, 0, stream>>>(
                Abf + r0 * DD, res2B, DD, g_ln2 + l * DD, b_ln2 + l * DD);
        }
    }

    // ---- output head ----
    final_out<<<dim3(BN), blk, 0, stream>>>(Abf, W_out, b_out, out);
}

// Round 19
// 1811.221 us; speedup vs baseline: 1.3838x; 1.0288x over previous
//
#include <hip/hip_runtime.h>
#include <math.h>

// ---- problem constants ----
#define BB   8
#define TT   5
#define NN   2048
#define FIN  64
#define EE   32768
#define DD   256
#define HH   8
#define FFD  2048
#define NCLS 10
#define GG   (BB*TT)        // 40 graphs
#define BN   (BB*NN)        // 16384
#define NM   (GG*NN)        // 81920 rows (= TT*BN)
#define NE   ((long)GG*EE)  // 1310720 edges

#define MR        20480           // rows per FFN chunk (4 chunks)

typedef __attribute__((ext_vector_type(8))) short short8;
typedef __attribute__((ext_vector_type(4))) float f32x4;

// ---- bf16 helpers (RNE) ----
__device__ __forceinline__ unsigned short f2b(float f) {
    unsigned u = __float_as_uint(f);
    u = (u + 0x7fffu + ((u >> 16) & 1u)) >> 16;
    return (unsigned short)u;
}
__device__ __forceinline__ float b2f(unsigned short b) {
    return __uint_as_float(((unsigned)b) << 16);
}

// async global->LDS, 16B per lane (dest must be wave-uniform base + lane*16)
__device__ __forceinline__ void gload_lds16(const void* g, void* l) {
    __builtin_amdgcn_global_load_lds(
        (__attribute__((address_space(1))) void*)g,
        (__attribute__((address_space(3))) void*)l, 16, 0, 0);
}

// =====================================================================
// Weight transpose+convert: fp32 [K][N] -> bf16 [N][K]
// =====================================================================
__device__ __forceinline__ void wtrans_body(const float* in, unsigned short* out,
                                            int K, int N, int bx, int by) {
    __shared__ float t[32][33];
    const int n0 = bx * 32, k0 = by * 32;
    const int tx = threadIdx.x, ty = threadIdx.y;
    for (int i = ty; i < 32; i += 8) t[i][tx] = in[(long)(k0 + i) * N + n0 + tx];
    __syncthreads();
    for (int i = ty; i < 32; i += 8)
        out[(long)(n0 + i) * K + k0 + tx] = f2b(t[tx][i]);
}

__global__ void wtrans(const float* __restrict__ in, unsigned short* __restrict__ out,
                       int K, int N) {
    wtrans_body(in, out, K, N, blockIdx.x, blockIdx.y);
}

// 4 same-shape [256][256] matrices, z selects
__global__ void wtrans4(const float* __restrict__ a, const float* __restrict__ b,
                        const float* __restrict__ c, const float* __restrict__ d,
                        unsigned short* __restrict__ out) {
    const float* src = (blockIdx.z == 0) ? a : (blockIdx.z == 1) ? b
                     : (blockIdx.z == 2) ? c : d;
    wtrans_body(src, out + (long)blockIdx.z * 65536, DD, DD, blockIdx.x, blockIdx.y);
}

// layer-strided: z = layer
__global__ void wtrans_s(const float* __restrict__ in, long sstride,
                         unsigned short* __restrict__ out, long dstride,
                         int K, int N) {
    wtrans_body(in + (long)blockIdx.z * sstride, out + (long)blockIdx.z * dstride,
                K, N, blockIdx.x, blockIdx.y);
}

// fp32 -> bf16 elementwise (n4 float4 groups)
__global__ void xconvert(const float* __restrict__ in, unsigned short* __restrict__ out, long n4) {
    long gid = (long)blockIdx.x * blockDim.x + threadIdx.x;
    if (gid >= n4) return;
    float4 v = ((const float4*)in)[gid];
    ushort4 o;
    o.x = f2b(v.x); o.y = f2b(v.y); o.z = f2b(v.z); o.w = f2b(v.w);
    ((ushort4*)out)[gid] = o;
}

// pack 3 bias vectors of 256 into one 768 buffer
__global__ void pack3(const float* __restrict__ a, const float* __restrict__ b,
                      const float* __restrict__ c, float* __restrict__ o) {
    int i = threadIdx.x;
    o[i] = a[i]; o[256 + i] = b[i]; o[512 + i] = c[i];
}

// =====================================================================
// bf16 MFMA GEMM v2: 256x128 tile, 512 threads = 8 waves (4M x 2N),
// BK=64 + rule-21 XOR swizzle.
// =====================================================================
template <bool RELU, bool OUTBF>
__global__ __launch_bounds__(512) void gemm_mfma2(
    const unsigned short* __restrict__ A, int lda,
    const unsigned short* __restrict__ WT,
    const float* __restrict__ bias,
    void* __restrict__ Cv, int ldc, int K)
{
    __shared__ unsigned short As[256 * 64];
    __shared__ unsigned short Bs[128 * 64];
    const int tid = threadIdx.x;
    const int wid = tid >> 6, lane = tid & 63;
    const int wm = wid >> 1, wn = wid & 1;     // 4 x 2 wave grid
    const int gx = gridDim.x, gy = gridDim.y;
    int bx = blockIdx.x, by = blockIdx.y;
    if ((gx & 7) == 0) {
        const int lbid = bx + gx * by;
        const int xcd = lbid & 7;
        const int i = lbid >> 3;
        const int CX = gx >> 3;
        bx = xcd * CX + i / gy;
        by = i - (i / gy) * gy;
    }
    const long row0 = (long)bx * 256;
    const long col0 = (long)by * 128;
    const int srow = tid >> 3;            // 0..63 (per pass)
    const int schunk = tid & 7;           // 16B chunk in 128B row
    const int fr = lane & 15;
    const int q = lane >> 4;
    f32x4 acc[4][4] = {};
    for (int k0 = 0; k0 < K; k0 += 64) {
        __syncthreads();
#pragma unroll
        for (int p = 0; p < 4; ++p) {
            const int row = p * 64 + srow;
            const int sc = (schunk ^ (row & 7)) * 8;
            gload_lds16(&A[(row0 + row) * (long)lda + k0 + sc], As + row * 64 + schunk * 8);
        }
#pragma unroll
        for (int p = 0; p < 2; ++p) {
            const int row = p * 64 + srow;
            const int sc = (schunk ^ (row & 7)) * 8;
            gload_lds16(&WT[(col0 + row) * (long)K + k0 + sc], Bs + row * 64 + schunk * 8);
        }
        __syncthreads();
#pragma unroll
        for (int kk = 0; kk < 2; ++kk) {
            short8 af[4], bfr[4];
#pragma unroll
            for (int mf = 0; mf < 4; ++mf) {
                const int row = wm * 64 + mf * 16 + fr;
                const int byo = (row * 128 + kk * 64 + q * 16) ^ ((row & 7) << 4);
                af[mf] = *(const short8*)((const char*)As + byo);
            }
#pragma unroll
            for (int nf = 0; nf < 4; ++nf) {
                const int row = wn * 64 + nf * 16 + fr;
                const int byo = (row * 128 + kk * 64 + q * 16) ^ ((row & 7) << 4);
                bfr[nf] = *(const short8*)((const char*)Bs + byo);
            }
#pragma unroll
            for (int mf = 0; mf < 4; ++mf)
#pragma unroll
                for (int nf = 0; nf < 4; ++nf)
                    acc[mf][nf] = __builtin_amdgcn_mfma_f32_16x16x32_bf16(
                        af[mf], bfr[nf], acc[mf][nf], 0, 0, 0);
        }
    }
#pragma unroll
    for (int nf = 0; nf < 4; ++nf) {
        const long col = col0 + wn * 64 + nf * 16 + fr;
        const float bv = bias[col];
#pragma unroll
        for (int mf = 0; mf < 4; ++mf) {
#pragma unroll
            for (int i = 0; i < 4; ++i) {
                const long r = row0 + wm * 64 + mf * 16 + q * 4 + i;
                float vv = acc[mf][nf][i] + bv;
                if (RELU) vv = fmaxf(vv, 0.f);
                if (OUTBF) ((unsigned short*)Cv)[r * ldc + col] = f2b(vv);
                else       ((float*)Cv)[r * ldc + col] = vv;
            }
        }
    }
}

// =====================================================================
// Fused GEMM + residual + LayerNorm, 128x256 tile (full LN row), 512
// threads = 8 waves (2M x 4N).
// seq[M][256] = LN(seq + A @ W + bias) * g + b   (in place over seq)
// =====================================================================
__global__ __launch_bounds__(512) void gemm_wo_ln(
    const unsigned short* __restrict__ A, int lda,
    const unsigned short* __restrict__ WT,
    const float* __restrict__ bias,
    unsigned short* __restrict__ seq,
    const float* __restrict__ g, const float* __restrict__ b, int K)
{
    __shared__ unsigned short As[128 * 64];
    __shared__ unsigned short Bs[256 * 64];
    __shared__ float Lsum[128][4];
    __shared__ float Lsq[128][4];
    const int tid = threadIdx.x;
    const int wid = tid >> 6, lane = tid & 63;
    const int wm = wid >> 2, wn = wid & 3;     // 2 x 4 wave grid
    const int gx = gridDim.x;
    int bx = blockIdx.x;
    if ((gx & 7) == 0) bx = (bx & 7) * (gx >> 3) + (bx >> 3);
    const long row0 = (long)bx * 128;
    const int srow = tid >> 3;            // 0..63 per pass
    const int schunk = tid & 7;
    const int fr = lane & 15;
    const int q = lane >> 4;
    f32x4 acc[4][4] = {};
    for (int k0 = 0; k0 < K; k0 += 64) {
        __syncthreads();
#pragma unroll
        for (int p = 0; p < 2; ++p) {
            const int row = p * 64 + srow;
            const int sc = (schunk ^ (row & 7)) * 8;
            gload_lds16(&A[(row0 + row) * (long)lda + k0 + sc], As + row * 64 + schunk * 8);
        }
#pragma unroll
        for (int p = 0; p < 4; ++p) {
            const int row = p * 64 + srow;
            const int sc = (schunk ^ (row & 7)) * 8;
            gload_lds16(&WT[(long)row * K + k0 + sc], Bs + row * 64 + schunk * 8);
        }
        __syncthreads();
#pragma unroll
        for (int kk = 0; kk < 2; ++kk) {
            short8 af[4], bfr[4];
#pragma unroll
            for (int mf = 0; mf < 4; ++mf) {
                const int row = wm * 64 + mf * 16 + fr;
                const int byo = (row * 128 + kk * 64 + q * 16) ^ ((row & 7) << 4);
                af[mf] = *(const short8*)((const char*)As + byo);
            }
#pragma unroll
            for (int nf = 0; nf < 4; ++nf) {
                const int row = wn * 64 + nf * 16 + fr;
                const int byo = (row * 128 + kk * 64 + q * 16) ^ ((row & 7) << 4);
                bfr[nf] = *(const short8*)((const char*)Bs + byo);
            }
#pragma unroll
            for (int mf = 0; mf < 4; ++mf)
#pragma unroll
                for (int nf = 0; nf < 4; ++nf)
                    acc[mf][nf] = __builtin_amdgcn_mfma_f32_16x16x32_bf16(
                        af[mf], bfr[nf], acc[mf][nf], 0, 0, 0);
        }
    }
    // epilogue: acc += bias + residual(seq)
#pragma unroll
    for (int nf = 0; nf < 4; ++nf) {
        const int col = wn * 64 + nf * 16 + fr;
        const float bv = bias[col];
#pragma unroll
        for (int mf = 0; mf < 4; ++mf)
#pragma unroll
            for (int i = 0; i < 4; ++i) {
                const long r = row0 + wm * 64 + mf * 16 + q * 4 + i;
                acc[mf][nf][i] += bv + b2f(seq[r * 256 + col]);
            }
    }
    // per-row stats: in-thread over nf, shfl over fr group, LDS across wn
#pragma unroll
    for (int mf = 0; mf < 4; ++mf)
#pragma unroll
        for (int i = 0; i < 4; ++i) {
            float s = acc[mf][0][i] + acc[mf][1][i] + acc[mf][2][i] + acc[mf][3][i];
            float s2 = acc[mf][0][i] * acc[mf][0][i] + acc[mf][1][i] * acc[mf][1][i]
                     + acc[mf][2][i] * acc[mf][2][i] + acc[mf][3][i] * acc[mf][3][i];
#pragma unroll
            for (int m = 1; m <= 8; m <<= 1) {
                s += __shfl_xor(s, m, 64);
                s2 += __shfl_xor(s2, m, 64);
            }
            if (fr == 0) {
                const int lr = wm * 64 + mf * 16 + q * 4 + i;
                Lsum[lr][wn] = s;
                Lsq[lr][wn] = s2;
            }
        }
    __syncthreads();
#pragma unroll
    for (int mf = 0; mf < 4; ++mf)
#pragma unroll
        for (int i = 0; i < 4; ++i) {
            const int lr = wm * 64 + mf * 16 + q * 4 + i;
            const float sum = Lsum[lr][0] + Lsum[lr][1] + Lsum[lr][2] + Lsum[lr][3];
            const float sq  = Lsq[lr][0] + Lsq[lr][1] + Lsq[lr][2] + Lsq[lr][3];
            const float mean = sum * (1.f / 256.f);
            const float var = sq * (1.f / 256.f) - mean * mean;
            const float inv = rsqrtf(var + 1e-5f);
            const long r = row0 + lr;
#pragma unroll
            for (int nf = 0; nf < 4; ++nf) {
                const int col = wn * 64 + nf * 16 + fr;
                seq[r * 256 + col] = f2b((acc[mf][nf][i] - mean) * inv * g[col] + b[col]);
            }
        }
}

// =====================================================================
// bf16 MFMA GEMM (128 x 64, NF=2) — kept for W2 (2 blocks/CU win, R14).
// =====================================================================
template <bool RELU, bool OUTBF, int NF>
__global__ __launch_bounds__(256) void gemm_mfma(
    const unsigned short* __restrict__ A, int lda,
    const unsigned short* __restrict__ WT,
    const float* __restrict__ bias,
    void* __restrict__ Cv, int ldc, int K)
{
    __shared__ unsigned short As[128 * 64];
    __shared__ unsigned short Bs[32 * NF * 64];
    const int tid = threadIdx.x;
    const int wid = tid >> 6, lane = tid & 63;
    const int wm = wid >> 1, wn = wid & 1;
    const int gx = gridDim.x, gy = gridDim.y;
    int bx = blockIdx.x, by = blockIdx.y;
    if ((gx & 7) == 0) {
        const int lbid = bx + gx * by;
        const int xcd = lbid & 7;
        const int i = lbid >> 3;
        const int CX = gx >> 3;
        bx = xcd * CX + i / gy;
        by = i - (i / gy) * gy;
    }
    const long row0 = (long)bx * 128;
    const long col0 = (long)by * (32 * NF);
    const int srow = tid >> 3;
    const int schunk = tid & 7;
    const int fr = lane & 15;
    const int q = lane >> 4;
    f32x4 acc[4][NF] = {};
    for (int k0 = 0; k0 < K; k0 += 64) {
        __syncthreads();
#pragma unroll
        for (int p = 0; p < 4; ++p) {
            const int row = p * 32 + srow;
            const int sc = (schunk ^ (row & 7)) * 8;
            gload_lds16(&A[(row0 + row) * (long)lda + k0 + sc], As + row * 64 + schunk * 8);
        }
#pragma unroll
        for (int p = 0; p < NF; ++p) {
            const int row = p * 32 + srow;
            const int sc = (schunk ^ (row & 7)) * 8;
            gload_lds16(&WT[(col0 + row) * (long)K + k0 + sc], Bs + row * 64 + schunk * 8);
        }
        __syncthreads();
#pragma unroll
        for (int kk = 0; kk < 2; ++kk) {
            short8 af[4], bfr[NF];
#pragma unroll
            for (int mf = 0; mf < 4; ++mf) {
                const int row = wm * 64 + mf * 16 + fr;
                const int byo = (row * 128 + kk * 64 + q * 16) ^ ((row & 7) << 4);
                af[mf] = *(const short8*)((const char*)As + byo);
            }
#pragma unroll
            for (int nf = 0; nf < NF; ++nf) {
                const int row = wn * (NF * 16) + nf * 16 + fr;
                const int byo = (row * 128 + kk * 64 + q * 16) ^ ((row & 7) << 4);
                bfr[nf] = *(const short8*)((const char*)Bs + byo);
            }
#pragma unroll
            for (int mf = 0; mf < 4; ++mf)
#pragma unroll
                for (int nf = 0; nf < NF; ++nf)
                    acc[mf][nf] = __builtin_amdgcn_mfma_f32_16x16x32_bf16(
                        af[mf], bfr[nf], acc[mf][nf], 0, 0, 0);
        }
    }
#pragma unroll
    for (int nf = 0; nf < NF; ++nf) {
        const long col = col0 + wn * (NF * 16) + nf * 16 + fr;
        const float bv = bias[col];
#pragma unroll
        for (int mf = 0; mf < 4; ++mf) {
#pragma unroll
            for (int i = 0; i < 4; ++i) {
                const long r = row0 + wm * 64 + mf * 16 + q * 4 + i;
                float vv = acc[mf][nf][i] + bv;
                if (RELU) vv = fmaxf(vv, 0.f);
                if (OUTBF) ((unsigned short*)Cv)[r * ldc + col] = f2b(vv);
                else       ((float*)Cv)[r * ldc + col] = vv;
            }
        }
    }
}

// =====================================================================
// CSR build. pcsr entry packs (srcrow << 15) | e.
// =====================================================================
__global__ void csr_init(int* __restrict__ cnt, int* __restrict__ fill) {
    int gid = blockIdx.x * blockDim.x + threadIdx.x;
    if (gid < NM) { cnt[gid] = 0; fill[gid] = 0; }
}

__global__ void csr_count(const int* __restrict__ eidx, int* __restrict__ cnt) {
    long el = (long)blockIdx.x * blockDim.x + threadIdx.x;
    if (el >= NE) return;
    int g = (int)(el >> 15), e = (int)(el & (EE - 1));
    int tgt = eidx[((long)g * 2 + 1) * EE + e];
    atomicAdd(&cnt[g * NN + tgt], 1);
}

__global__ __launch_bounds__(1024) void csr_scan(const int* __restrict__ cnt, int* __restrict__ off) {
    __shared__ int part[1024];
    const int t = threadIdx.x;
    const int base = t * (NM / 1024);
    int s = 0;
    for (int i = 0; i < NM / 1024; ++i) s += cnt[base + i];
    part[t] = s;
    __syncthreads();
    for (int d = 1; d < 1024; d <<= 1) {
        int v = (t >= d) ? part[t - d] : 0;
        __syncthreads();
        part[t] += v;
        __syncthreads();
    }
    int run = (t == 0) ? 0 : part[t - 1];
    for (int i = 0; i < NM / 1024; ++i) { off[base + i] = run; run += cnt[base + i]; }
    if (t == 1023) off[NM] = run;
}

__global__ void csr_scatter(const int* __restrict__ eidx, const int* __restrict__ off,
                            int* __restrict__ fill, unsigned* __restrict__ pcsr) {
    long el = (long)blockIdx.x * blockDim.x + threadIdx.x;
    if (el >= NE) return;
    int g = (int)(el >> 15), e = (int)(el & (EE - 1));
    int src = eidx[((long)g * 2 + 0) * EE + e];
    int tgt = eidx[((long)g * 2 + 1) * EE + e];
    int tf = g * NN + tgt;
    int pos = atomicAdd(&fill[tf], 1);
    pcsr[off[tf] + pos] = ((unsigned)(g * NN + src) << 15) | (unsigned)e;
}

// =====================================================================
// Fused TransformerConv on interleaved qkv [NM][768]; packed CSR records.
// pk carried one full iteration ahead: k/v/eattr prefetch for j+1 issues
// with ZERO dependency wait (pk loaded at iter j-1); only the cheap 4-byte
// pcsr[j+2] load rides the current iteration's compute.
// =====================================================================
__global__ __launch_bounds__(256) void conv_fused(
    unsigned short* __restrict__ Z,
    const float* __restrict__ eattr,
    const float* __restrict__ W_edge, const float* __restrict__ b_edge,
    const int* __restrict__ off, const unsigned* __restrict__ pcsr)
{
    const int tid = threadIdx.x;
    const int wave = tid >> 6, lane = tid & 63;
    const int bid = (blockIdx.x & 7) * (NM / 4 / 8) + (blockIdx.x >> 3);
    const long tf = (long)bid * 4 + wave;
    const int d0 = lane * 4;
    unsigned short* qrow = &Z[tf * 768];
    const ushort4 q4 = *(const ushort4*)&qrow[d0];
    const float q0 = b2f(q4.x), q1 = b2f(q4.y), q2 = b2f(q4.z), q3 = b2f(q4.w);
    const float be0 = b_edge[d0], be1 = b_edge[d0 + 1],
                be2 = b_edge[d0 + 2], be3 = b_edge[d0 + 3];
    float w0[6], w1r[6], w2r[6], w3r[6];
#pragma unroll
    for (int j2 = 0; j2 < 6; ++j2) {
        const float* wp = &W_edge[j2 * 256 + d0];
        w0[j2] = wp[0]; w1r[j2] = wp[1]; w2r[j2] = wp[2]; w3r[j2] = wp[3];
    }
    float qb = q0 * be0 + q1 * be1 + q2 * be2 + q3 * be3;
    float qw[6];
#pragma unroll
    for (int j2 = 0; j2 < 6; ++j2)
        qw[j2] = q0 * w0[j2] + q1 * w1r[j2] + q2 * w2r[j2] + q3 * w3r[j2];
#pragma unroll
    for (int mm = 1; mm <= 4; mm <<= 1) {
        qb += __shfl_xor(qb, mm, 64);
#pragma unroll
        for (int j2 = 0; j2 < 6; ++j2) qw[j2] += __shfl_xor(qw[j2], mm, 64);
    }
    const float scale = 0.17677669529663687f;  // 1/sqrt(32)
    float s = 0.f, a0 = 0.f, a1 = 0.f, a2 = 0.f, a3 = 0.f;
    float t0 = 0.f, t1 = 0.f, t2 = 0.f, t3 = 0.f, t4 = 0.f, t5 = 0.f;
    const int jb = off[tf], je = off[tf + 1];
    ushort4 kc, vc; float eac[6];
    unsigned pk1 = 0;
    if (jb < je) {
        const unsigned pk = pcsr[jb];
        const long sf = pk >> 15;
        kc = *(const ushort4*)&Z[sf * 768 + 256 + d0];
        vc = *(const ushort4*)&Z[sf * 768 + 512 + d0];
        const long el = (sf >> 11) * EE + (pk & 32767u);
#pragma unroll
        for (int t = 0; t < 6; ++t) eac[t] = eattr[el * 6 + t];
    }
    if (jb + 1 < je) pk1 = pcsr[jb + 1];   // pk for j+1, ready at loop entry
    for (int j = jb; j < je; ++j) {
        ushort4 kn, vn; float ean[6];
        if (j + 1 < je) {   // issue k/v/eattr for j+1 from pre-loaded pk1
            const long sf = pk1 >> 15;
            kn = *(const ushort4*)&Z[sf * 768 + 256 + d0];
            vn = *(const ushort4*)&Z[sf * 768 + 512 + d0];
            const long el = (sf >> 11) * EE + (pk1 & 32767u);
#pragma unroll
            for (int t = 0; t < 6; ++t) ean[t] = eattr[el * 6 + t];
        }
        const unsigned pk2 = (j + 2 < je) ? pcsr[j + 2] : 0;   // for next iter
        float p = q0 * b2f(kc.x) + q1 * b2f(kc.y) + q2 * b2f(kc.z) + q3 * b2f(kc.w);
        p += __shfl_xor(p, 1, 64);
        p += __shfl_xor(p, 2, 64);
        p += __shfl_xor(p, 4, 64);
        float alpha = p + qb;
        alpha += eac[0] * qw[0] + eac[1] * qw[1] + eac[2] * qw[2]
               + eac[3] * qw[3] + eac[4] * qw[4] + eac[5] * qw[5];
        const float a = __expf(alpha * scale);
        s += a;
        a0 += a * b2f(vc.x); a1 += a * b2f(vc.y);
        a2 += a * b2f(vc.z); a3 += a * b2f(vc.w);
        t0 += a * eac[0]; t1 += a * eac[1]; t2 += a * eac[2];
        t3 += a * eac[3]; t4 += a * eac[4]; t5 += a * eac[5];
        kc = kn; vc = vn; pk1 = pk2;
#pragma unroll
        for (int t = 0; t < 6; ++t) eac[t] = ean[t];
    }
    const float inv = (s > 0.f) ? 1.f / s : 0.f;
    float o0 = a0 + be0 * s, o1 = a1 + be1 * s, o2 = a2 + be2 * s, o3 = a3 + be3 * s;
    o0 += w0[0]*t0 + w0[1]*t1 + w0[2]*t2 + w0[3]*t3 + w0[4]*t4 + w0[5]*t5;
    o1 += w1r[0]*t0 + w1r[1]*t1 + w1r[2]*t2 + w1r[3]*t3 + w1r[4]*t4 + w1r[5]*t5;
    o2 += w2r[0]*t0 + w2r[1]*t1 + w2r[2]*t2 + w2r[3]*t3 + w2r[4]*t4 + w2r[5]*t5;
    o3 += w3r[0]*t0 + w3r[1]*t1 + w3r[2]*t2 + w3r[3]*t3 + w3r[4]*t4 + w3r[5]*t5;
    ushort4 o;
    o.x = f2b(o0 * inv); o.y = f2b(o1 * inv);
    o.z = f2b(o2 * inv); o.w = f2b(o3 * inv);
    *(ushort4*)&qrow[d0] = o;
}

// seq(bf16, [t*BN+b*N+n][256]) = conv(q-slice of Z) + skip(k-slice of Z)
__global__ void transpose_add(const unsigned short* __restrict__ Z,
                              unsigned short* __restrict__ out) {
    long gid = (long)blockIdx.x * blockDim.x + threadIdx.x;
    long row = gid >> 6;
    int c4 = (int)(gid & 63);
    int n = (int)(row % NN);
    int bt = (int)(row / NN);
    int t = bt % TT, b = bt / TT;
    long orow = (long)t * BN + (long)b * NN + n;
    ushort4 cv = ((const ushort4*)&Z[row * 768])[c4];
    ushort4 sv = ((const ushort4*)&Z[row * 768 + 256])[c4];
    ushort4 o;
    o.x = f2b(b2f(cv.x) + b2f(sv.x));
    o.y = f2b(b2f(cv.y) + b2f(sv.y));
    o.z = f2b(b2f(cv.z) + b2f(sv.z));
    o.w = f2b(b2f(cv.w) + b2f(sv.w));
    ((ushort4*)out)[orow * 64 + c4] = o;
}

// =====================================================================
// temporal attention v2: one 64-lane wave per node bn.
// =====================================================================
__global__ __launch_bounds__(256) void mha_time(unsigned short* __restrict__ Z)
{
    const int tid = threadIdx.x;
    const int wave = tid >> 6, lane = tid & 63;
    const long bn = (long)blockIdx.x * 4 + wave;
    const int d0 = lane * 4;
    const float scale = 0.17677669529663687f;
    float qv[TT][4], kv[TT][4], vv[TT][4];
    long r[TT];
#pragma unroll
    for (int t = 0; t < TT; ++t) {
        r[t] = ((long)t * BN + bn) * 768 + d0;
        const ushort4 qq = *(const ushort4*)&Z[r[t]];
        const ushort4 kk = *(const ushort4*)&Z[r[t] + 256];
        const ushort4 vx = *(const ushort4*)&Z[r[t] + 512];
        qv[t][0] = b2f(qq.x); qv[t][1] = b2f(qq.y); qv[t][2] = b2f(qq.z); qv[t][3] = b2f(qq.w);
        kv[t][0] = b2f(kk.x); kv[t][1] = b2f(kk.y); kv[t][2] = b2f(kk.z); kv[t][3] = b2f(kk.w);
        vv[t][0] = b2f(vx.x); vv[t][1] = b2f(vx.y); vv[t][2] = b2f(vx.z); vv[t][3] = b2f(vx.w);
    }
    float s[TT][TT];
#pragma unroll
    for (int t = 0; t < TT; ++t)
#pragma unroll
        for (int u = 0; u < TT; ++u) {
            float p = qv[t][0] * kv[u][0] + qv[t][1] * kv[u][1]
                    + qv[t][2] * kv[u][2] + qv[t][3] * kv[u][3];
            p += __shfl_xor(p, 1, 64);
            p += __shfl_xor(p, 2, 64);
            p += __shfl_xor(p, 4, 64);   // 8-lane group = one head
            s[t][u] = p * scale;
        }
#pragma unroll
    for (int t = 0; t < TT; ++t) {
        float mx = s[t][0];
#pragma unroll
        for (int u = 1; u < TT; ++u) mx = fmaxf(mx, s[t][u]);
        float sm = 0.f;
#pragma unroll
        for (int u = 0; u < TT; ++u) { s[t][u] = __expf(s[t][u] - mx); sm += s[t][u]; }
        const float inv = 1.f / sm;
        float o0 = 0.f, o1 = 0.f, o2 = 0.f, o3 = 0.f;
#pragma unroll
        for (int u = 0; u < TT; ++u) {
            o0 += s[t][u] * vv[u][0]; o1 += s[t][u] * vv[u][1];
            o2 += s[t][u] * vv[u][2]; o3 += s[t][u] * vv[u][3];
        }
        ushort4 o;
        o.x = f2b(o0 * inv); o.y = f2b(o1 * inv);
        o.z = f2b(o2 * inv); o.w = f2b(o3 * inv);
        *(ushort4*)&Z[r[t]] = o;
    }
}

// seq(bf16) = LayerNorm(seq + res(bf16, row-stride rstride)) * g + b
__global__ __launch_bounds__(256) void ln_residual(
    unsigned short* __restrict__ seq, const unsigned short* __restrict__ res,
    int rstride, const float* __restrict__ g, const float* __restrict__ b)
{
    const int wave = threadIdx.x >> 6, lane = threadIdx.x & 63;
    long row = (long)blockIdx.x * 4 + wave;
    const ushort4 s4 = *(const ushort4*)&seq[row * 256 + lane * 4];
    const ushort4 r4 = *(const ushort4*)&res[row * (long)rstride + lane * 4];
    float x[4] = { b2f(s4.x) + b2f(r4.x), b2f(s4.y) + b2f(r4.y),
                   b2f(s4.z) + b2f(r4.z), b2f(s4.w) + b2f(r4.w) };
    float sum = x[0] + x[1] + x[2] + x[3];
#pragma unroll
    for (int m = 32; m >= 1; m >>= 1) sum += __shfl_xor(sum, m, 64);
    float mean = sum * (1.f / 256.f);
    float vs = 0.f;
#pragma unroll
    for (int i = 0; i < 4; ++i) { float dl = x[i] - mean; vs += dl * dl; }
#pragma unroll
    for (int m = 32; m >= 1; m >>= 1) vs += __shfl_xor(vs, m, 64);
    float inv = rsqrtf(vs * (1.f / 256.f) + 1e-5f);
    ushort4 o;
    o.x = f2b((x[0] - mean) * inv * g[lane * 4 + 0] + b[lane * 4 + 0]);
    o.y = f2b((x[1] - mean) * inv * g[lane * 4 + 1] + b[lane * 4 + 1]);
    o.z = f2b((x[2] - mean) * inv * g[lane * 4 + 2] + b[lane * 4 + 2]);
    o.w = f2b((x[3] - mean) * inv * g[lane * 4 + 3] + b[lane * 4 + 3]);
    *(ushort4*)&seq[row * 256 + lane * 4] = o;
}

// out[row][0..9] = seq[t=T-1 rows](bf16) @ W_out + b_out ; one block per row
__global__ __launch_bounds__(256) void final_out(
    const unsigned short* __restrict__ seq, const float* __restrict__ Wd,
    const float* __restrict__ bd, float* __restrict__ out)
{
    __shared__ float xs[256];
    long row = blockIdx.x;
    xs[threadIdx.x] = b2f(seq[((long)(TT - 1) * BN + row) * 256 + threadIdx.x]);
    __syncthreads();
    const int wv = threadIdx.x >> 6, lane = threadIdx.x & 63;
    for (int o = wv; o < NCLS; o += 4) {
        float p = 0.f;
#pragma unroll
        for (int i = 0; i < 4; ++i) {
            int kk = lane + 64 * i;
            p += xs[kk] * Wd[kk * NCLS + o];
        }
#pragma unroll
        for (int m = 32; m >= 1; m >>= 1) p += __shfl_xor(p, m, 64);
        if (lane == 0) out[row * NCLS + o] = p + bd[o];
    }
}

__global__ void fill_sentinel(float* __restrict__ out, int n) {
    int gid = blockIdx.x * blockDim.x + threadIdx.x;
    if (gid < n) out[gid] = 1.0e6f;
}

// =====================================================================
extern "C" void kernel_launch(void* const* d_in, const int* in_sizes, int n_in,
                              void* d_out, int out_size, void* d_ws, size_t ws_size,
                              hipStream_t stream) {
    const float* xseq  = (const float*)d_in[0];
    const int*   eidx  = (const int*)d_in[1];
    const float* eattr = (const float*)d_in[2];
    const float* W_node = (const float*)d_in[3];
    const float* b_node = (const float*)d_in[4];
    const float* W_edge = (const float*)d_in[5];
    const float* b_edge = (const float*)d_in[6];
    const float* Wq = (const float*)d_in[7];  const float* bq = (const float*)d_in[8];
    const float* Wk = (const float*)d_in[9];  const float* bk = (const float*)d_in[10];
    const float* Wv = (const float*)d_in[11]; const float* bv = (const float*)d_in[12];
    const float* Ws = (const float*)d_in[13]; const float* bs = (const float*)d_in[14];
    const float* Wqkv = (const float*)d_in[15]; const float* bqkv = (const float*)d_in[16];
    const float* Wo = (const float*)d_in[17];   const float* bo = (const float*)d_in[18];
    const float* W1 = (const float*)d_in[19];   const float* b1 = (const float*)d_in[20];
    const float* W2 = (const float*)d_in[21];   const float* b2 = (const float*)d_in[22];
    const float* g_ln1 = (const float*)d_in[23]; const float* b_ln1 = (const float*)d_in[24];
    const float* g_ln2 = (const float*)d_in[25]; const float* b_ln2 = (const float*)d_in[26];
    const float* W_out = (const float*)d_in[27]; const float* b_out = (const float*)d_in[28];
    float* out = (float*)d_out;

    // ---- workspace layout ----
    const long SZ = (long)NM * DD;            // 20,971,520 elements
    unsigned short* Abf = (unsigned short*)d_ws;     // seq activations bf16 (40MB)
    unsigned short* Zu  = Abf + SZ;                  // qkv interleaved [NM][768] (126MB)
    unsigned short* Hid = Zu;                        // FFN hidden bf16 [MR][2048] (84MB)
    unsigned short* resF = Zu + (long)MR * FFD;      // FFN residual bf16 [NM][256] (42MB)
    unsigned short* WX = Zu + 3 * SZ;
    unsigned short* xbf = WX;                             // 81920*64
    unsigned short* wtN = xbf + (long)NM * FIN;           // [256][64]
    unsigned short* wtQ = wtN + 256 * 64;                 // [768][256] stacked q,k,v
    unsigned short* wtS = wtQ + 3L * 65536;
    unsigned short* wtQKV = wtS + 65536;                  // 3 * [768][256]
    unsigned short* wtO = wtQKV + 3L * 768 * 256;         // 3 * [256][256]
    unsigned short* wtW1 = wtO + 3L * 65536;              // 3 * [2048][256]
    unsigned short* wtW2 = wtW1 + 3L * 2048 * 256;        // 3 * [256][2048]
    int* cnt  = (int*)(wtW2 + 3L * 256 * 2048);
    int* coff = cnt + NM;                                 // NM+1
    int* cfil = coff + NM + 1;
    unsigned* pcsr = (unsigned*)(cfil + NM);              // NE packed records
    float* qkvb = (float*)(pcsr + NE);                    // 768 packed bias
    char* wend = (char*)(qkvb + 768);
    const size_t need = (size_t)(wend - (char*)d_ws);
    if (ws_size < need) {
        fill_sentinel<<<dim3((out_size + 255) / 256), dim3(256), 0, stream>>>(out, out_size);
        return;
    }

    dim3 blk(256);
    dim3 blk5(512);
    dim3 tb(32, 8);

    // ---- prologue (batched weight conversion) ----
    xconvert<<<dim3((unsigned)((long)NM * FIN / 4 / 256)), blk, 0, stream>>>(xseq, xbf, (long)NM * FIN / 4);
    wtrans<<<dim3(DD / 32, FIN / 32), tb, 0, stream>>>(W_node, wtN, FIN, DD);
    wtrans4<<<dim3(DD / 32, DD / 32, 4), tb, 0, stream>>>(Wq, Wk, Wv, Ws, wtQ);
    wtrans_s<<<dim3(768 / 32, DD / 32, 3), tb, 0, stream>>>(Wqkv, (long)DD * 768, wtQKV, 768L * 256, DD, 768);
    wtrans_s<<<dim3(DD / 32, DD / 32, 3), tb, 0, stream>>>(Wo, (long)DD * DD, wtO, 65536L, DD, DD);
    wtrans_s<<<dim3(FFD / 32, DD / 32, 3), tb, 0, stream>>>(W1, (long)DD * FFD, wtW1, 2048L * 256, DD, FFD);
    wtrans_s<<<dim3(DD / 32, FFD / 32, 3), tb, 0, stream>>>(W2, (long)FFD * DD, wtW2, 256L * 2048, FFD, DD);
    pack3<<<dim3(1), blk, 0, stream>>>(bq, bk, bv, qkvb);

    // ---- CSR build (packed records) ----
    csr_init<<<dim3((NM + 255) / 256), blk, 0, stream>>>(cnt, cfil);
    csr_count<<<dim3((unsigned)(NE / 256)), blk, 0, stream>>>(eidx, cnt);
    csr_scan<<<dim3(1), dim3(1024), 0, stream>>>(cnt, coff);
    csr_scatter<<<dim3((unsigned)(NE / 256)), blk, 0, stream>>>(eidx, coff, cfil, pcsr);

    // ---- stage 1 ----
    gemm_mfma2<false, true><<<dim3(NM / 256, DD / 128), blk5, 0, stream>>>(
        xbf, FIN, wtN, b_node, Abf, DD, FIN);
    gemm_mfma2<false, true><<<dim3(NM / 256, 768 / 128), blk5, 0, stream>>>(
        Abf, DD, wtQ, qkvb, Zu, 768, DD);
    conv_fused<<<dim3(NM / 4), blk, 0, stream>>>(
        Zu, eattr, W_edge, b_edge, coff, pcsr);
    gemm_mfma2<false, true><<<dim3(NM / 256, DD / 128), blk5, 0, stream>>>(
        Abf, DD, wtS, bs, (void*)(Zu + 256), 768, DD);
    transpose_add<<<dim3(NM * 64 / 256), blk, 0, stream>>>(Zu, Abf);

    // ---- stage 2: 3 temporal transformer encoder layers ----
    for (int l = 0; l < 3; ++l) {
        gemm_mfma2<false, true><<<dim3(NM / 256, 768 / 128), blk5, 0, stream>>>(
            Abf, DD, wtQKV + (long)l * 768 * 256, bqkv + (long)l * 768, Zu, 768, DD);
        mha_time<<<dim3(BN / 4), blk, 0, stream>>>(Zu);
        // fused Wo + residual + LN1 (128x256 tile, in place over Abf)
        gemm_wo_ln<<<dim3(NM / 128), blk5, 0, stream>>>(
            Zu, 768, wtO + (long)l * 65536, bo + (long)l * DD,
            Abf, g_ln1 + l * DD, b_ln1 + l * DD, DD);
        // FFN: 4 chunks of W1->W2 (W2 writes its slice of the full resF),
        // then a single full-M LN2
        for (int mr = 0; mr < NM / MR; ++mr) {
            const long r0 = (long)mr * MR;
            gemm_mfma2<true, true><<<dim3(MR / 256, FFD / 128), blk5, 0, stream>>>(
                Abf + r0 * DD, DD, wtW1 + (long)l * 2048 * 256, b1 + (long)l * FFD, Hid, FFD, DD);
            gemm_mfma<false, true, 2><<<dim3(MR / 128, DD / 64), blk, 0, stream>>>(
                Hid, FFD, wtW2 + (long)l * 256 * 2048, b2 + (long)l * DD,
                resF + r0 * DD, DD, FFD);
        }
        ln_residual<<<dim3(NM / 4), blk, 0, stream>>>(
            Abf, resF, DD, g_ln2 + l * DD, b_ln2 + l * DD);
    }

    // ---- output head ----
    final_out<<<dim3(BN), blk, 0, stream>>>(Abf, W_out, b_out, out);
}

// Round 20
// 1802.254 us; speedup vs baseline: 1.3907x; 1.0050x over previous
//
#include <hip/hip_runtime.h>
#include <math.h>

// ---- problem constants ----
#define BB   8
#define TT   5
#define NN   2048
#define FIN  64
#define EE   32768
#define DD   256
#define HH   8
#define FFD  2048
#define NCLS 10
#define GG   (BB*TT)        // 40 graphs
#define BN   (BB*NN)        // 16384
#define NM   (GG*NN)        // 81920 rows (= TT*BN)
#define NE   ((long)GG*EE)  // 1310720 edges

#define MR        20480           // rows per FFN chunk (4 chunks)

typedef __attribute__((ext_vector_type(8))) short short8;
typedef __attribute__((ext_vector_type(4))) float f32x4;

// ---- bf16 helpers (RNE) ----
__device__ __forceinline__ unsigned short f2b(float f) {
    unsigned u = __float_as_uint(f);
    u = (u + 0x7fffu + ((u >> 16) & 1u)) >> 16;
    return (unsigned short)u;
}
__device__ __forceinline__ float b2f(unsigned short b) {
    return __uint_as_float(((unsigned)b) << 16);
}

// async global->LDS, 16B per lane (dest must be wave-uniform base + lane*16)
__device__ __forceinline__ void gload_lds16(const void* g, void* l) {
    __builtin_amdgcn_global_load_lds(
        (__attribute__((address_space(1))) void*)g,
        (__attribute__((address_space(3))) void*)l, 16, 0, 0);
}

// =====================================================================
// Weight transpose+convert: fp32 [K][N] -> bf16 [N][K]
// =====================================================================
__device__ __forceinline__ void wtrans_body(const float* in, unsigned short* out,
                                            int K, int N, int bx, int by) {
    __shared__ float t[32][33];
    const int n0 = bx * 32, k0 = by * 32;
    const int tx = threadIdx.x, ty = threadIdx.y;
    for (int i = ty; i < 32; i += 8) t[i][tx] = in[(long)(k0 + i) * N + n0 + tx];
    __syncthreads();
    for (int i = ty; i < 32; i += 8)
        out[(long)(n0 + i) * K + k0 + tx] = f2b(t[tx][i]);
}

__global__ void wtrans(const float* __restrict__ in, unsigned short* __restrict__ out,
                       int K, int N) {
    wtrans_body(in, out, K, N, blockIdx.x, blockIdx.y);
}

// 4 same-shape [256][256] matrices, z selects
__global__ void wtrans4(const float* __restrict__ a, const float* __restrict__ b,
                        const float* __restrict__ c, const float* __restrict__ d,
                        unsigned short* __restrict__ out) {
    const float* src = (blockIdx.z == 0) ? a : (blockIdx.z == 1) ? b
                     : (blockIdx.z == 2) ? c : d;
    wtrans_body(src, out + (long)blockIdx.z * 65536, DD, DD, blockIdx.x, blockIdx.y);
}

// layer-strided: z = layer
__global__ void wtrans_s(const float* __restrict__ in, long sstride,
                         unsigned short* __restrict__ out, long dstride,
                         int K, int N) {
    wtrans_body(in + (long)blockIdx.z * sstride, out + (long)blockIdx.z * dstride,
                K, N, blockIdx.x, blockIdx.y);
}

// fp32 -> bf16 elementwise (n4 float4 groups)
__global__ void xconvert(const float* __restrict__ in, unsigned short* __restrict__ out, long n4) {
    long gid = (long)blockIdx.x * blockDim.x + threadIdx.x;
    if (gid >= n4) return;
    float4 v = ((const float4*)in)[gid];
    ushort4 o;
    o.x = f2b(v.x); o.y = f2b(v.y); o.z = f2b(v.z); o.w = f2b(v.w);
    ((ushort4*)out)[gid] = o;
}

// pack 3 bias vectors of 256 into one 768 buffer
__global__ void pack3(const float* __restrict__ a, const float* __restrict__ b,
                      const float* __restrict__ c, float* __restrict__ o) {
    int i = threadIdx.x;
    o[i] = a[i]; o[256 + i] = b[i]; o[512 + i] = c[i];
}

// =====================================================================
// bf16 MFMA GEMM v2: 256x128 tile, 512 threads = 8 waves (4M x 2N),
// BK=64 + rule-21 XOR swizzle.
// =====================================================================
template <bool RELU, bool OUTBF>
__global__ __launch_bounds__(512) void gemm_mfma2(
    const unsigned short* __restrict__ A, int lda,
    const unsigned short* __restrict__ WT,
    const float* __restrict__ bias,
    void* __restrict__ Cv, int ldc, int K)
{
    __shared__ unsigned short As[256 * 64];
    __shared__ unsigned short Bs[128 * 64];
    const int tid = threadIdx.x;
    const int wid = tid >> 6, lane = tid & 63;
    const int wm = wid >> 1, wn = wid & 1;     // 4 x 2 wave grid
    const int gx = gridDim.x, gy = gridDim.y;
    int bx = blockIdx.x, by = blockIdx.y;
    if ((gx & 7) == 0) {
        const int lbid = bx + gx * by;
        const int xcd = lbid & 7;
        const int i = lbid >> 3;
        const int CX = gx >> 3;
        bx = xcd * CX + i / gy;
        by = i - (i / gy) * gy;
    }
    const long row0 = (long)bx * 256;
    const long col0 = (long)by * 128;
    const int srow = tid >> 3;            // 0..63 (per pass)
    const int schunk = tid & 7;           // 16B chunk in 128B row
    const int fr = lane & 15;
    const int q = lane >> 4;
    f32x4 acc[4][4] = {};
    for (int k0 = 0; k0 < K; k0 += 64) {
        __syncthreads();
#pragma unroll
        for (int p = 0; p < 4; ++p) {
            const int row = p * 64 + srow;
            const int sc = (schunk ^ (row & 7)) * 8;
            gload_lds16(&A[(row0 + row) * (long)lda + k0 + sc], As + row * 64 + schunk * 8);
        }
#pragma unroll
        for (int p = 0; p < 2; ++p) {
            const int row = p * 64 + srow;
            const int sc = (schunk ^ (row & 7)) * 8;
            gload_lds16(&WT[(col0 + row) * (long)K + k0 + sc], Bs + row * 64 + schunk * 8);
        }
        __syncthreads();
#pragma unroll
        for (int kk = 0; kk < 2; ++kk) {
            short8 af[4], bfr[4];
#pragma unroll
            for (int mf = 0; mf < 4; ++mf) {
                const int row = wm * 64 + mf * 16 + fr;
                const int byo = (row * 128 + kk * 64 + q * 16) ^ ((row & 7) << 4);
                af[mf] = *(const short8*)((const char*)As + byo);
            }
#pragma unroll
            for (int nf = 0; nf < 4; ++nf) {
                const int row = wn * 64 + nf * 16 + fr;
                const int byo = (row * 128 + kk * 64 + q * 16) ^ ((row & 7) << 4);
                bfr[nf] = *(const short8*)((const char*)Bs + byo);
            }
#pragma unroll
            for (int mf = 0; mf < 4; ++mf)
#pragma unroll
                for (int nf = 0; nf < 4; ++nf)
                    acc[mf][nf] = __builtin_amdgcn_mfma_f32_16x16x32_bf16(
                        af[mf], bfr[nf], acc[mf][nf], 0, 0, 0);
        }
    }
#pragma unroll
    for (int nf = 0; nf < 4; ++nf) {
        const long col = col0 + wn * 64 + nf * 16 + fr;
        const float bv = bias[col];
#pragma unroll
        for (int mf = 0; mf < 4; ++mf) {
#pragma unroll
            for (int i = 0; i < 4; ++i) {
                const long r = row0 + wm * 64 + mf * 16 + q * 4 + i;
                float vv = acc[mf][nf][i] + bv;
                if (RELU) vv = fmaxf(vv, 0.f);
                if (OUTBF) ((unsigned short*)Cv)[r * ldc + col] = f2b(vv);
                else       ((float*)Cv)[r * ldc + col] = vv;
            }
        }
    }
}

// =====================================================================
// Fused GEMM + residual + LayerNorm, 128x256 tile (full LN row), 512
// threads = 8 waves (2M x 4N).
// seq[M][256] = LN(seq + A @ W + bias) * g + b   (in place over seq)
// =====================================================================
__global__ __launch_bounds__(512) void gemm_wo_ln(
    const unsigned short* __restrict__ A, int lda,
    const unsigned short* __restrict__ WT,
    const float* __restrict__ bias,
    unsigned short* __restrict__ seq,
    const float* __restrict__ g, const float* __restrict__ b, int K)
{
    __shared__ unsigned short As[128 * 64];
    __shared__ unsigned short Bs[256 * 64];
    __shared__ float Lsum[128][4];
    __shared__ float Lsq[128][4];
    const int tid = threadIdx.x;
    const int wid = tid >> 6, lane = tid & 63;
    const int wm = wid >> 2, wn = wid & 3;     // 2 x 4 wave grid
    const int gx = gridDim.x;
    int bx = blockIdx.x;
    if ((gx & 7) == 0) bx = (bx & 7) * (gx >> 3) + (bx >> 3);
    const long row0 = (long)bx * 128;
    const int srow = tid >> 3;            // 0..63 per pass
    const int schunk = tid & 7;
    const int fr = lane & 15;
    const int q = lane >> 4;
    f32x4 acc[4][4] = {};
    for (int k0 = 0; k0 < K; k0 += 64) {
        __syncthreads();
#pragma unroll
        for (int p = 0; p < 2; ++p) {
            const int row = p * 64 + srow;
            const int sc = (schunk ^ (row & 7)) * 8;
            gload_lds16(&A[(row0 + row) * (long)lda + k0 + sc], As + row * 64 + schunk * 8);
        }
#pragma unroll
        for (int p = 0; p < 4; ++p) {
            const int row = p * 64 + srow;
            const int sc = (schunk ^ (row & 7)) * 8;
            gload_lds16(&WT[(long)row * K + k0 + sc], Bs + row * 64 + schunk * 8);
        }
        __syncthreads();
#pragma unroll
        for (int kk = 0; kk < 2; ++kk) {
            short8 af[4], bfr[4];
#pragma unroll
            for (int mf = 0; mf < 4; ++mf) {
                const int row = wm * 64 + mf * 16 + fr;
                const int byo = (row * 128 + kk * 64 + q * 16) ^ ((row & 7) << 4);
                af[mf] = *(const short8*)((const char*)As + byo);
            }
#pragma unroll
            for (int nf = 0; nf < 4; ++nf) {
                const int row = wn * 64 + nf * 16 + fr;
                const int byo = (row * 128 + kk * 64 + q * 16) ^ ((row & 7) << 4);
                bfr[nf] = *(const short8*)((const char*)Bs + byo);
            }
#pragma unroll
            for (int mf = 0; mf < 4; ++mf)
#pragma unroll
                for (int nf = 0; nf < 4; ++nf)
                    acc[mf][nf] = __builtin_amdgcn_mfma_f32_16x16x32_bf16(
                        af[mf], bfr[nf], acc[mf][nf], 0, 0, 0);
        }
    }
    // epilogue: acc += bias + residual(seq)
#pragma unroll
    for (int nf = 0; nf < 4; ++nf) {
        const int col = wn * 64 + nf * 16 + fr;
        const float bv = bias[col];
#pragma unroll
        for (int mf = 0; mf < 4; ++mf)
#pragma unroll
            for (int i = 0; i < 4; ++i) {
                const long r = row0 + wm * 64 + mf * 16 + q * 4 + i;
                acc[mf][nf][i] += bv + b2f(seq[r * 256 + col]);
            }
    }
    // per-row stats: in-thread over nf, shfl over fr group, LDS across wn
#pragma unroll
    for (int mf = 0; mf < 4; ++mf)
#pragma unroll
        for (int i = 0; i < 4; ++i) {
            float s = acc[mf][0][i] + acc[mf][1][i] + acc[mf][2][i] + acc[mf][3][i];
            float s2 = acc[mf][0][i] * acc[mf][0][i] + acc[mf][1][i] * acc[mf][1][i]
                     + acc[mf][2][i] * acc[mf][2][i] + acc[mf][3][i] * acc[mf][3][i];
#pragma unroll
            for (int m = 1; m <= 8; m <<= 1) {
                s += __shfl_xor(s, m, 64);
                s2 += __shfl_xor(s2, m, 64);
            }
            if (fr == 0) {
                const int lr = wm * 64 + mf * 16 + q * 4 + i;
                Lsum[lr][wn] = s;
                Lsq[lr][wn] = s2;
            }
        }
    __syncthreads();
#pragma unroll
    for (int mf = 0; mf < 4; ++mf)
#pragma unroll
        for (int i = 0; i < 4; ++i) {
            const int lr = wm * 64 + mf * 16 + q * 4 + i;
            const float sum = Lsum[lr][0] + Lsum[lr][1] + Lsum[lr][2] + Lsum[lr][3];
            const float sq  = Lsq[lr][0] + Lsq[lr][1] + Lsq[lr][2] + Lsq[lr][3];
            const float mean = sum * (1.f / 256.f);
            const float var = sq * (1.f / 256.f) - mean * mean;
            const float inv = rsqrtf(var + 1e-5f);
            const long r = row0 + lr;
#pragma unroll
            for (int nf = 0; nf < 4; ++nf) {
                const int col = wn * 64 + nf * 16 + fr;
                seq[r * 256 + col] = f2b((acc[mf][nf][i] - mean) * inv * g[col] + b[col]);
            }
        }
}

// =====================================================================
// bf16 MFMA GEMM (128 x 64, NF=2) — kept for W2 (2 blocks/CU win, R14).
// =====================================================================
template <bool RELU, bool OUTBF, int NF>
__global__ __launch_bounds__(256) void gemm_mfma(
    const unsigned short* __restrict__ A, int lda,
    const unsigned short* __restrict__ WT,
    const float* __restrict__ bias,
    void* __restrict__ Cv, int ldc, int K)
{
    __shared__ unsigned short As[128 * 64];
    __shared__ unsigned short Bs[32 * NF * 64];
    const int tid = threadIdx.x;
    const int wid = tid >> 6, lane = tid & 63;
    const int wm = wid >> 1, wn = wid & 1;
    const int gx = gridDim.x, gy = gridDim.y;
    int bx = blockIdx.x, by = blockIdx.y;
    if ((gx & 7) == 0) {
        const int lbid = bx + gx * by;
        const int xcd = lbid & 7;
        const int i = lbid >> 3;
        const int CX = gx >> 3;
        bx = xcd * CX + i / gy;
        by = i - (i / gy) * gy;
    }
    const long row0 = (long)bx * 128;
    const long col0 = (long)by * (32 * NF);
    const int srow = tid >> 3;
    const int schunk = tid & 7;
    const int fr = lane & 15;
    const int q = lane >> 4;
    f32x4 acc[4][NF] = {};
    for (int k0 = 0; k0 < K; k0 += 64) {
        __syncthreads();
#pragma unroll
        for (int p = 0; p < 4; ++p) {
            const int row = p * 32 + srow;
            const int sc = (schunk ^ (row & 7)) * 8;
            gload_lds16(&A[(row0 + row) * (long)lda + k0 + sc], As + row * 64 + schunk * 8);
        }
#pragma unroll
        for (int p = 0; p < NF; ++p) {
            const int row = p * 32 + srow;
            const int sc = (schunk ^ (row & 7)) * 8;
            gload_lds16(&WT[(col0 + row) * (long)K + k0 + sc], Bs + row * 64 + schunk * 8);
        }
        __syncthreads();
#pragma unroll
        for (int kk = 0; kk < 2; ++kk) {
            short8 af[4], bfr[NF];
#pragma unroll
            for (int mf = 0; mf < 4; ++mf) {
                const int row = wm * 64 + mf * 16 + fr;
                const int byo = (row * 128 + kk * 64 + q * 16) ^ ((row & 7) << 4);
                af[mf] = *(const short8*)((const char*)As + byo);
            }
#pragma unroll
            for (int nf = 0; nf < NF; ++nf) {
                const int row = wn * (NF * 16) + nf * 16 + fr;
                const int byo = (row * 128 + kk * 64 + q * 16) ^ ((row & 7) << 4);
                bfr[nf] = *(const short8*)((const char*)Bs + byo);
            }
#pragma unroll
            for (int mf = 0; mf < 4; ++mf)
#pragma unroll
                for (int nf = 0; nf < NF; ++nf)
                    acc[mf][nf] = __builtin_amdgcn_mfma_f32_16x16x32_bf16(
                        af[mf], bfr[nf], acc[mf][nf], 0, 0, 0);
        }
    }
#pragma unroll
    for (int nf = 0; nf < NF; ++nf) {
        const long col = col0 + wn * (NF * 16) + nf * 16 + fr;
        const float bv = bias[col];
#pragma unroll
        for (int mf = 0; mf < 4; ++mf) {
#pragma unroll
            for (int i = 0; i < 4; ++i) {
                const long r = row0 + wm * 64 + mf * 16 + q * 4 + i;
                float vv = acc[mf][nf][i] + bv;
                if (RELU) vv = fmaxf(vv, 0.f);
                if (OUTBF) ((unsigned short*)Cv)[r * ldc + col] = f2b(vv);
                else       ((float*)Cv)[r * ldc + col] = vv;
            }
        }
    }
}

// =====================================================================
// CSR build. pcsr[j] = srcrow; eab[j] = 6 bf16 edge attrs (12B, CSR order).
// =====================================================================
__global__ void csr_init(int* __restrict__ cnt, int* __restrict__ fill) {
    int gid = blockIdx.x * blockDim.x + threadIdx.x;
    if (gid < NM) { cnt[gid] = 0; fill[gid] = 0; }
}

__global__ void csr_count(const int* __restrict__ eidx, int* __restrict__ cnt) {
    long el = (long)blockIdx.x * blockDim.x + threadIdx.x;
    if (el >= NE) return;
    int g = (int)(el >> 15), e = (int)(el & (EE - 1));
    int tgt = eidx[((long)g * 2 + 1) * EE + e];
    atomicAdd(&cnt[g * NN + tgt], 1);
}

__global__ __launch_bounds__(1024) void csr_scan(const int* __restrict__ cnt, int* __restrict__ off) {
    __shared__ int part[1024];
    const int t = threadIdx.x;
    const int base = t * (NM / 1024);
    int s = 0;
    for (int i = 0; i < NM / 1024; ++i) s += cnt[base + i];
    part[t] = s;
    __syncthreads();
    for (int d = 1; d < 1024; d <<= 1) {
        int v = (t >= d) ? part[t - d] : 0;
        __syncthreads();
        part[t] += v;
        __syncthreads();
    }
    int run = (t == 0) ? 0 : part[t - 1];
    for (int i = 0; i < NM / 1024; ++i) { off[base + i] = run; run += cnt[base + i]; }
    if (t == 1023) off[NM] = run;
}

__global__ void csr_scatter(const int* __restrict__ eidx, const float* __restrict__ eattr,
                            const int* __restrict__ off, int* __restrict__ fill,
                            unsigned* __restrict__ pcsr, unsigned* __restrict__ eab) {
    long el = (long)blockIdx.x * blockDim.x + threadIdx.x;
    if (el >= NE) return;
    int g = (int)(el >> 15), e = (int)(el & (EE - 1));
    int src = eidx[((long)g * 2 + 0) * EE + e];
    int tgt = eidx[((long)g * 2 + 1) * EE + e];
    int tf = g * NN + tgt;
    int pos = atomicAdd(&fill[tf], 1);
    const long j = (long)off[tf] + pos;
    pcsr[j] = (unsigned)(g * NN + src);
    const float* ea = &eattr[el * 6];
    eab[j * 3 + 0] = (unsigned)f2b(ea[0]) | ((unsigned)f2b(ea[1]) << 16);
    eab[j * 3 + 1] = (unsigned)f2b(ea[2]) | ((unsigned)f2b(ea[3]) << 16);
    eab[j * 3 + 2] = (unsigned)f2b(ea[4]) | ((unsigned)f2b(ea[5]) << 16);
}

// =====================================================================
// Fused TransformerConv on interleaved qkv [NM][768]. Edge attrs ride
// the sequential eab stream (bf16, CSR order) -> the only random stream
// left is the k/v gather, prefetched one full iteration ahead.
// =====================================================================
__global__ __launch_bounds__(256) void conv_fused(
    unsigned short* __restrict__ Z,
    const float* __restrict__ W_edge, const float* __restrict__ b_edge,
    const int* __restrict__ off, const unsigned* __restrict__ pcsr,
    const unsigned* __restrict__ eab)
{
    const int tid = threadIdx.x;
    const int wave = tid >> 6, lane = tid & 63;
    const int bid = (blockIdx.x & 7) * (NM / 4 / 8) + (blockIdx.x >> 3);
    const long tf = (long)bid * 4 + wave;
    const int d0 = lane * 4;
    unsigned short* qrow = &Z[tf * 768];
    const ushort4 q4 = *(const ushort4*)&qrow[d0];
    const float q0 = b2f(q4.x), q1 = b2f(q4.y), q2 = b2f(q4.z), q3 = b2f(q4.w);
    const float be0 = b_edge[d0], be1 = b_edge[d0 + 1],
                be2 = b_edge[d0 + 2], be3 = b_edge[d0 + 3];
    float w0[6], w1r[6], w2r[6], w3r[6];
#pragma unroll
    for (int j2 = 0; j2 < 6; ++j2) {
        const float* wp = &W_edge[j2 * 256 + d0];
        w0[j2] = wp[0]; w1r[j2] = wp[1]; w2r[j2] = wp[2]; w3r[j2] = wp[3];
    }
    float qb = q0 * be0 + q1 * be1 + q2 * be2 + q3 * be3;
    float qw[6];
#pragma unroll
    for (int j2 = 0; j2 < 6; ++j2)
        qw[j2] = q0 * w0[j2] + q1 * w1r[j2] + q2 * w2r[j2] + q3 * w3r[j2];
#pragma unroll
    for (int mm = 1; mm <= 4; mm <<= 1) {
        qb += __shfl_xor(qb, mm, 64);
#pragma unroll
        for (int j2 = 0; j2 < 6; ++j2) qw[j2] += __shfl_xor(qw[j2], mm, 64);
    }
    const float scale = 0.17677669529663687f;  // 1/sqrt(32)
    float s = 0.f, a0 = 0.f, a1 = 0.f, a2 = 0.f, a3 = 0.f;
    float t0 = 0.f, t1 = 0.f, t2 = 0.f, t3 = 0.f, t4 = 0.f, t5 = 0.f;
    const int jb = off[tf], je = off[tf + 1];
    ushort4 kc, vc;
    unsigned ecA = 0, ecB = 0, ecC = 0;          // current edge attrs (6 bf16)
    unsigned pk1 = 0, e1A = 0, e1B = 0, e1C = 0; // next edge record
    if (jb < je) {
        const unsigned pk = pcsr[jb];
        const long sf = pk;
        kc = *(const ushort4*)&Z[sf * 768 + 256 + d0];
        vc = *(const ushort4*)&Z[sf * 768 + 512 + d0];
        ecA = eab[(long)jb * 3 + 0];
        ecB = eab[(long)jb * 3 + 1];
        ecC = eab[(long)jb * 3 + 2];
    }
    if (jb + 1 < je) {
        pk1 = pcsr[jb + 1];
        e1A = eab[(long)(jb + 1) * 3 + 0];
        e1B = eab[(long)(jb + 1) * 3 + 1];
        e1C = eab[(long)(jb + 1) * 3 + 2];
    }
    for (int j = jb; j < je; ++j) {
        ushort4 kn, vn;
        if (j + 1 < je) {   // issue k/v for j+1 from pre-loaded pk1 (no wait)
            const long sf = pk1;
            kn = *(const ushort4*)&Z[sf * 768 + 256 + d0];
            vn = *(const ushort4*)&Z[sf * 768 + 512 + d0];
        }
        unsigned pk2 = 0, e2A = 0, e2B = 0, e2C = 0;
        if (j + 2 < je) {   // cheap sequential loads for next iteration
            pk2 = pcsr[j + 2];
            e2A = eab[(long)(j + 2) * 3 + 0];
            e2B = eab[(long)(j + 2) * 3 + 1];
            e2C = eab[(long)(j + 2) * 3 + 2];
        }
        float eac[6];
        eac[0] = b2f((unsigned short)(ecA & 0xffffu));
        eac[1] = b2f((unsigned short)(ecA >> 16));
        eac[2] = b2f((unsigned short)(ecB & 0xffffu));
        eac[3] = b2f((unsigned short)(ecB >> 16));
        eac[4] = b2f((unsigned short)(ecC & 0xffffu));
        eac[5] = b2f((unsigned short)(ecC >> 16));
        float p = q0 * b2f(kc.x) + q1 * b2f(kc.y) + q2 * b2f(kc.z) + q3 * b2f(kc.w);
        p += __shfl_xor(p, 1, 64);
        p += __shfl_xor(p, 2, 64);
        p += __shfl_xor(p, 4, 64);
        float alpha = p + qb;
        alpha += eac[0] * qw[0] + eac[1] * qw[1] + eac[2] * qw[2]
               + eac[3] * qw[3] + eac[4] * qw[4] + eac[5] * qw[5];
        const float a = __expf(alpha * scale);
        s += a;
        a0 += a * b2f(vc.x); a1 += a * b2f(vc.y);
        a2 += a * b2f(vc.z); a3 += a * b2f(vc.w);
        t0 += a * eac[0]; t1 += a * eac[1]; t2 += a * eac[2];
        t3 += a * eac[3]; t4 += a * eac[4]; t5 += a * eac[5];
        kc = kn; vc = vn;
        ecA = e1A; ecB = e1B; ecC = e1C;
        pk1 = pk2; e1A = e2A; e1B = e2B; e1C = e2C;
    }
    const float inv = (s > 0.f) ? 1.f / s : 0.f;
    float o0 = a0 + be0 * s, o1 = a1 + be1 * s, o2 = a2 + be2 * s, o3 = a3 + be3 * s;
    o0 += w0[0]*t0 + w0[1]*t1 + w0[2]*t2 + w0[3]*t3 + w0[4]*t4 + w0[5]*t5;
    o1 += w1r[0]*t0 + w1r[1]*t1 + w1r[2]*t2 + w1r[3]*t3 + w1r[4]*t4 + w1r[5]*t5;
    o2 += w2r[0]*t0 + w2r[1]*t1 + w2r[2]*t2 + w2r[3]*t3 + w2r[4]*t4 + w2r[5]*t5;
    o3 += w3r[0]*t0 + w3r[1]*t1 + w3r[2]*t2 + w3r[3]*t3 + w3r[4]*t4 + w3r[5]*t5;
    ushort4 o;
    o.x = f2b(o0 * inv); o.y = f2b(o1 * inv);
    o.z = f2b(o2 * inv); o.w = f2b(o3 * inv);
    *(ushort4*)&qrow[d0] = o;
}

// seq(bf16, [t*BN+b*N+n][256]) = conv(q-slice of Z) + skip(k-slice of Z)
__global__ void transpose_add(const unsigned short* __restrict__ Z,
                              unsigned short* __restrict__ out) {
    long gid = (long)blockIdx.x * blockDim.x + threadIdx.x;
    long row = gid >> 6;
    int c4 = (int)(gid & 63);
    int n = (int)(row % NN);
    int bt = (int)(row / NN);
    int t = bt % TT, b = bt / TT;
    long orow = (long)t * BN + (long)b * NN + n;
    ushort4 cv = ((const ushort4*)&Z[row * 768])[c4];
    ushort4 sv = ((const ushort4*)&Z[row * 768 + 256])[c4];
    ushort4 o;
    o.x = f2b(b2f(cv.x) + b2f(sv.x));
    o.y = f2b(b2f(cv.y) + b2f(sv.y));
    o.z = f2b(b2f(cv.z) + b2f(sv.z));
    o.w = f2b(b2f(cv.w) + b2f(sv.w));
    ((ushort4*)out)[orow * 64 + c4] = o;
}

// =====================================================================
// temporal attention v2: one 64-lane wave per node bn.
// =====================================================================
__global__ __launch_bounds__(256) void mha_time(unsigned short* __restrict__ Z)
{
    const int tid = threadIdx.x;
    const int wave = tid >> 6, lane = tid & 63;
    const long bn = (long)blockIdx.x * 4 + wave;
    const int d0 = lane * 4;
    const float scale = 0.17677669529663687f;
    float qv[TT][4], kv[TT][4], vv[TT][4];
    long r[TT];
#pragma unroll
    for (int t = 0; t < TT; ++t) {
        r[t] = ((long)t * BN + bn) * 768 + d0;
        const ushort4 qq = *(const ushort4*)&Z[r[t]];
        const ushort4 kk = *(const ushort4*)&Z[r[t] + 256];
        const ushort4 vx = *(const ushort4*)&Z[r[t] + 512];
        qv[t][0] = b2f(qq.x); qv[t][1] = b2f(qq.y); qv[t][2] = b2f(qq.z); qv[t][3] = b2f(qq.w);
        kv[t][0] = b2f(kk.x); kv[t][1] = b2f(kk.y); kv[t][2] = b2f(kk.z); kv[t][3] = b2f(kk.w);
        vv[t][0] = b2f(vx.x); vv[t][1] = b2f(vx.y); vv[t][2] = b2f(vx.z); vv[t][3] = b2f(vx.w);
    }
    float s[TT][TT];
#pragma unroll
    for (int t = 0; t < TT; ++t)
#pragma unroll
        for (int u = 0; u < TT; ++u) {
            float p = qv[t][0] * kv[u][0] + qv[t][1] * kv[u][1]
                    + qv[t][2] * kv[u][2] + qv[t][3] * kv[u][3];
            p += __shfl_xor(p, 1, 64);
            p += __shfl_xor(p, 2, 64);
            p += __shfl_xor(p, 4, 64);   // 8-lane group = one head
            s[t][u] = p * scale;
        }
#pragma unroll
    for (int t = 0; t < TT; ++t) {
        float mx = s[t][0];
#pragma unroll
        for (int u = 1; u < TT; ++u) mx = fmaxf(mx, s[t][u]);
        float sm = 0.f;
#pragma unroll
        for (int u = 0; u < TT; ++u) { s[t][u] = __expf(s[t][u] - mx); sm += s[t][u]; }
        const float inv = 1.f / sm;
        float o0 = 0.f, o1 = 0.f, o2 = 0.f, o3 = 0.f;
#pragma unroll
        for (int u = 0; u < TT; ++u) {
            o0 += s[t][u] * vv[u][0]; o1 += s[t][u] * vv[u][1];
            o2 += s[t][u] * vv[u][2]; o3 += s[t][u] * vv[u][3];
        }
        ushort4 o;
        o.x = f2b(o0 * inv); o.y = f2b(o1 * inv);
        o.z = f2b(o2 * inv); o.w = f2b(o3 * inv);
        *(ushort4*)&Z[r[t]] = o;
    }
}

// seq(bf16) = LayerNorm(seq + res(bf16, row-stride rstride)) * g + b
__global__ __launch_bounds__(256) void ln_residual(
    unsigned short* __restrict__ seq, const unsigned short* __restrict__ res,
    int rstride, const float* __restrict__ g, const float* __restrict__ b)
{
    const int wave = threadIdx.x >> 6, lane = threadIdx.x & 63;
    long row = (long)blockIdx.x * 4 + wave;
    const ushort4 s4 = *(const ushort4*)&seq[row * 256 + lane * 4];
    const ushort4 r4 = *(const ushort4*)&res[row * (long)rstride + lane * 4];
    float x[4] = { b2f(s4.x) + b2f(r4.x), b2f(s4.y) + b2f(r4.y),
                   b2f(s4.z) + b2f(r4.z), b2f(s4.w) + b2f(r4.w) };
    float sum = x[0] + x[1] + x[2] + x[3];
#pragma unroll
    for (int m = 32; m >= 1; m >>= 1) sum += __shfl_xor(sum, m, 64);
    float mean = sum * (1.f / 256.f);
    float vs = 0.f;
#pragma unroll
    for (int i = 0; i < 4; ++i) { float dl = x[i] - mean; vs += dl * dl; }
#pragma unroll
    for (int m = 32; m >= 1; m >>= 1) vs += __shfl_xor(vs, m, 64);
    float inv = rsqrtf(vs * (1.f / 256.f) + 1e-5f);
    ushort4 o;
    o.x = f2b((x[0] - mean) * inv * g[lane * 4 + 0] + b[lane * 4 + 0]);
    o.y = f2b((x[1] - mean) * inv * g[lane * 4 + 1] + b[lane * 4 + 1]);
    o.z = f2b((x[2] - mean) * inv * g[lane * 4 + 2] + b[lane * 4 + 2]);
    o.w = f2b((x[3] - mean) * inv * g[lane * 4 + 3] + b[lane * 4 + 3]);
    *(ushort4*)&seq[row * 256 + lane * 4] = o;
}

// out[row][0..9] = seq[t=T-1 rows](bf16) @ W_out + b_out ; one block per row
__global__ __launch_bounds__(256) void final_out(
    const unsigned short* __restrict__ seq, const float* __restrict__ Wd,
    const float* __restrict__ bd, float* __restrict__ out)
{
    __shared__ float xs[256];
    long row = blockIdx.x;
    xs[threadIdx.x] = b2f(seq[((long)(TT - 1) * BN + row) * 256 + threadIdx.x]);
    __syncthreads();
    const int wv = threadIdx.x >> 6, lane = threadIdx.x & 63;
    for (int o = wv; o < NCLS; o += 4) {
        float p = 0.f;
#pragma unroll
        for (int i = 0; i < 4; ++i) {
            int kk = lane + 64 * i;
            p += xs[kk] * Wd[kk * NCLS + o];
        }
#pragma unroll
        for (int m = 32; m >= 1; m >>= 1) p += __shfl_xor(p, m, 64);
        if (lane == 0) out[row * NCLS + o] = p + bd[o];
    }
}

__global__ void fill_sentinel(float* __restrict__ out, int n) {
    int gid = blockIdx.x * blockDim.x + threadIdx.x;
    if (gid < n) out[gid] = 1.0e6f;
}

// =====================================================================
extern "C" void kernel_launch(void* const* d_in, const int* in_sizes, int n_in,
                              void* d_out, int out_size, void* d_ws, size_t ws_size,
                              hipStream_t stream) {
    const float* xseq  = (const float*)d_in[0];
    const int*   eidx  = (const int*)d_in[1];
    const float* eattr = (const float*)d_in[2];
    const float* W_node = (const float*)d_in[3];
    const float* b_node = (const float*)d_in[4];
    const float* W_edge = (const float*)d_in[5];
    const float* b_edge = (const float*)d_in[6];
    const float* Wq = (const float*)d_in[7];  const float* bq = (const float*)d_in[8];
    const float* Wk = (const float*)d_in[9];  const float* bk = (const float*)d_in[10];
    const float* Wv = (const float*)d_in[11]; const float* bv = (const float*)d_in[12];
    const float* Ws = (const float*)d_in[13]; const float* bs = (const float*)d_in[14];
    const float* Wqkv = (const float*)d_in[15]; const float* bqkv = (const float*)d_in[16];
    const float* Wo = (const float*)d_in[17];   const float* bo = (const float*)d_in[18];
    const float* W1 = (const float*)d_in[19];   const float* b1 = (const float*)d_in[20];
    const float* W2 = (const float*)d_in[21];   const float* b2 = (const float*)d_in[22];
    const float* g_ln1 = (const float*)d_in[23]; const float* b_ln1 = (const float*)d_in[24];
    const float* g_ln2 = (const float*)d_in[25]; const float* b_ln2 = (const float*)d_in[26];
    const float* W_out = (const float*)d_in[27]; const float* b_out = (const float*)d_in[28];
    float* out = (float*)d_out;

    // ---- workspace layout ----
    const long SZ = (long)NM * DD;            // 20,971,520 elements
    unsigned short* Abf = (unsigned short*)d_ws;     // seq activations bf16 (42MB)
    unsigned short* Zu  = Abf + SZ;                  // qkv interleaved [NM][768] (126MB)
    unsigned short* Hid = Zu;                        // FFN hidden bf16 [MR][2048] (84MB)
    unsigned short* resF = Zu + (long)MR * FFD;      // FFN residual bf16 [NM][256] (42MB)
    // weights (xbf moved to tail; overlaid by eab after h-GEMM)
    unsigned short* wtN = Zu + 3 * SZ;                    // [256][64]
    unsigned short* wtQ = wtN + 256 * 64;                 // [768][256] stacked q,k,v
    unsigned short* wtS = wtQ + 3L * 65536;
    unsigned short* wtQKV = wtS + 65536;                  // 3 * [768][256]
    unsigned short* wtO = wtQKV + 3L * 768 * 256;         // 3 * [256][256]
    unsigned short* wtW1 = wtO + 3L * 65536;              // 3 * [2048][256]
    unsigned short* wtW2 = wtW1 + 3L * 2048 * 256;        // 3 * [256][2048]
    int* cnt  = (int*)(wtW2 + 3L * 256 * 2048);
    int* coff = cnt + NM;                                 // NM+1
    int* cfil = coff + NM + 1;
    unsigned* pcsr = (unsigned*)(cfil + NM);              // NE srcrow records
    float* qkvb = (float*)(pcsr + NE);                    // 768 packed bias
    // tail region: xbf (NM*64 bf16 = 10.5MB) overlaid by eab (NE*12B = 15.7MB)
    unsigned short* xbf = (unsigned short*)(qkvb + 768);
    unsigned* eab = (unsigned*)xbf;                       // valid after h-GEMM
    const long tail_bytes = (long)NE * 12;                // max(10.5MB, 15.7MB)
    char* wend = (char*)xbf + tail_bytes;
    const size_t need = (size_t)(wend - (char*)d_ws);
    if (ws_size < need) {
        fill_sentinel<<<dim3((out_size + 255) / 256), dim3(256), 0, stream>>>(out, out_size);
        return;
    }

    dim3 blk(256);
    dim3 blk5(512);
    dim3 tb(32, 8);

    // ---- prologue (batched weight conversion) ----
    xconvert<<<dim3((unsigned)((long)NM * FIN / 4 / 256)), blk, 0, stream>>>(xseq, xbf, (long)NM * FIN / 4);
    wtrans<<<dim3(DD / 32, FIN / 32), tb, 0, stream>>>(W_node, wtN, FIN, DD);
    wtrans4<<<dim3(DD / 32, DD / 32, 4), tb, 0, stream>>>(Wq, Wk, Wv, Ws, wtQ);
    wtrans_s<<<dim3(768 / 32, DD / 32, 3), tb, 0, stream>>>(Wqkv, (long)DD * 768, wtQKV, 768L * 256, DD, 768);
    wtrans_s<<<dim3(DD / 32, DD / 32, 3), tb, 0, stream>>>(Wo, (long)DD * DD, wtO, 65536L, DD, DD);
    wtrans_s<<<dim3(FFD / 32, DD / 32, 3), tb, 0, stream>>>(W1, (long)DD * FFD, wtW1, 2048L * 256, DD, FFD);
    wtrans_s<<<dim3(DD / 32, FFD / 32, 3), tb, 0, stream>>>(W2, (long)FFD * DD, wtW2, 256L * 2048, FFD, DD);
    pack3<<<dim3(1), blk, 0, stream>>>(bq, bk, bv, qkvb);

    // ---- stage 1 GEMMs (xbf consumed here, then overlaid by eab) ----
    gemm_mfma2<false, true><<<dim3(NM / 256, DD / 128), blk5, 0, stream>>>(
        xbf, FIN, wtN, b_node, Abf, DD, FIN);
    gemm_mfma2<false, true><<<dim3(NM / 256, 768 / 128), blk5, 0, stream>>>(
        Abf, DD, wtQ, qkvb, Zu, 768, DD);

    // ---- CSR build (packed records + bf16 edge attrs; xbf now dead) ----
    csr_init<<<dim3((NM + 255) / 256), blk, 0, stream>>>(cnt, cfil);
    csr_count<<<dim3((unsigned)(NE / 256)), blk, 0, stream>>>(eidx, cnt);
    csr_scan<<<dim3(1), dim3(1024), 0, stream>>>(cnt, coff);
    csr_scatter<<<dim3((unsigned)(NE / 256)), blk, 0, stream>>>(
        eidx, eattr, coff, cfil, pcsr, eab);

    // ---- conv + skip + reshape ----
    conv_fused<<<dim3(NM / 4), blk, 0, stream>>>(
        Zu, W_edge, b_edge, coff, pcsr, eab);
    gemm_mfma2<false, true><<<dim3(NM / 256, DD / 128), blk5, 0, stream>>>(
        Abf, DD, wtS, bs, (void*)(Zu + 256), 768, DD);
    transpose_add<<<dim3(NM * 64 / 256), blk, 0, stream>>>(Zu, Abf);

    // ---- stage 2: 3 temporal transformer encoder layers ----
    for (int l = 0; l < 3; ++l) {
        gemm_mfma2<false, true><<<dim3(NM / 256, 768 / 128), blk5, 0, stream>>>(
            Abf, DD, wtQKV + (long)l * 768 * 256, bqkv + (long)l * 768, Zu, 768, DD);
        mha_time<<<dim3(BN / 4), blk, 0, stream>>>(Zu);
        // fused Wo + residual + LN1 (128x256 tile, in place over Abf)
        gemm_wo_ln<<<dim3(NM / 128), blk5, 0, stream>>>(
            Zu, 768, wtO + (long)l * 65536, bo + (long)l * DD,
            Abf, g_ln1 + l * DD, b_ln1 + l * DD, DD);
        // FFN: 4 chunks of W1->W2 (W2 writes its slice of resF), one full LN2
        for (int mr = 0; mr < NM / MR; ++mr) {
            const long r0 = (long)mr * MR;
            gemm_mfma2<true, true><<<dim3(MR / 256, FFD / 128), blk5, 0, stream>>>(
                Abf + r0 * DD, DD, wtW1 + (long)l * 2048 * 256, b1 + (long)l * FFD, Hid, FFD, DD);
            gemm_mfma<false, true, 2><<<dim3(MR / 128, DD / 64), blk, 0, stream>>>(
                Hid, FFD, wtW2 + (long)l * 256 * 2048, b2 + (long)l * DD,
                resF + r0 * DD, DD, FFD);
        }
        ln_residual<<<dim3(NM / 4), blk, 0, stream>>>(
            Abf, resF, DD, g_ln2 + l * DD, b_ln2 + l * DD);
    }

    // ---- output head ----
    final_out<<<dim3(BN), blk, 0, stream>>>(Abf, W_out, b_out, out);
}

// Round 21
// 1757.320 us; speedup vs baseline: 1.4263x; 1.0256x over previous
//
#include <hip/hip_runtime.h>
#include <math.h>
#include <stdint.h>

// ---- problem constants ----
#define BB   8
#define TT   5
#define NN   2048
#define FIN  64
#define EE   32768
#define DD   256
#define HH   8
#define FFD  2048
#define NCLS 10
#define GG   (BB*TT)        // 40 graphs
#define BN   (BB*NN)        // 16384
#define NM   (GG*NN)        // 81920 rows (= TT*BN)
#define NE   ((long)GG*EE)  // 1310720 edges

#define MR        20480           // rows per FFN chunk (4 chunks)

typedef __attribute__((ext_vector_type(8))) short short8;
typedef __attribute__((ext_vector_type(4))) float f32x4;

// ---- bf16 helpers (RNE) ----
__device__ __forceinline__ unsigned short f2b(float f) {
    unsigned u = __float_as_uint(f);
    u = (u + 0x7fffu + ((u >> 16) & 1u)) >> 16;
    return (unsigned short)u;
}
__device__ __forceinline__ float b2f(unsigned short b) {
    return __uint_as_float(((unsigned)b) << 16);
}

// async global->LDS, 16B per lane (dest must be wave-uniform base + lane*16)
__device__ __forceinline__ void gload_lds16(const void* g, void* l) {
    __builtin_amdgcn_global_load_lds(
        (__attribute__((address_space(1))) void*)g,
        (__attribute__((address_space(3))) void*)l, 16, 0, 0);
}

// =====================================================================
// Weight transpose+convert: fp32 [K][N] -> bf16 [N][K]
// =====================================================================
__device__ __forceinline__ void wtrans_body(const float* in, unsigned short* out,
                                            int K, int N, int bx, int by) {
    __shared__ float t[32][33];
    const int n0 = bx * 32, k0 = by * 32;
    const int tx = threadIdx.x, ty = threadIdx.y;
    for (int i = ty; i < 32; i += 8) t[i][tx] = in[(long)(k0 + i) * N + n0 + tx];
    __syncthreads();
    for (int i = ty; i < 32; i += 8)
        out[(long)(n0 + i) * K + k0 + tx] = f2b(t[tx][i]);
}

__global__ void wtrans(const float* __restrict__ in, unsigned short* __restrict__ out,
                       int K, int N) {
    wtrans_body(in, out, K, N, blockIdx.x, blockIdx.y);
}

// 4 same-shape [256][256] matrices, z selects
__global__ void wtrans4(const float* __restrict__ a, const float* __restrict__ b,
                        const float* __restrict__ c, const float* __restrict__ d,
                        unsigned short* __restrict__ out) {
    const float* src = (blockIdx.z == 0) ? a : (blockIdx.z == 1) ? b
                     : (blockIdx.z == 2) ? c : d;
    wtrans_body(src, out + (long)blockIdx.z * 65536, DD, DD, blockIdx.x, blockIdx.y);
}

// layer-strided: z = layer
__global__ void wtrans_s(const float* __restrict__ in, long sstride,
                         unsigned short* __restrict__ out, long dstride,
                         int K, int N) {
    wtrans_body(in + (long)blockIdx.z * sstride, out + (long)blockIdx.z * dstride,
                K, N, blockIdx.x, blockIdx.y);
}

// fp32 -> bf16 elementwise (n4 float4 groups)
__global__ void xconvert(const float* __restrict__ in, unsigned short* __restrict__ out, long n4) {
    long gid = (long)blockIdx.x * blockDim.x + threadIdx.x;
    if (gid >= n4) return;
    float4 v = ((const float4*)in)[gid];
    ushort4 o;
    o.x = f2b(v.x); o.y = f2b(v.y); o.z = f2b(v.z); o.w = f2b(v.w);
    ((ushort4*)out)[gid] = o;
}

// pack 3 bias vectors of 256 into one 768 buffer
__global__ void pack3(const float* __restrict__ a, const float* __restrict__ b,
                      const float* __restrict__ c, float* __restrict__ o) {
    int i = threadIdx.x;
    o[i] = a[i]; o[256 + i] = b[i]; o[512 + i] = c[i];
}

// =====================================================================
// bf16 MFMA GEMM v2: 256x128 tile, 512 threads = 8 waves (4M x 2N),
// BK=64 + rule-21 XOR swizzle.
// =====================================================================
template <bool RELU, bool OUTBF>
__global__ __launch_bounds__(512) void gemm_mfma2(
    const unsigned short* __restrict__ A, int lda,
    const unsigned short* __restrict__ WT,
    const float* __restrict__ bias,
    void* __restrict__ Cv, int ldc, int K)
{
    __shared__ unsigned short As[256 * 64];
    __shared__ unsigned short Bs[128 * 64];
    const int tid = threadIdx.x;
    const int wid = tid >> 6, lane = tid & 63;
    const int wm = wid >> 1, wn = wid & 1;     // 4 x 2 wave grid
    const int gx = gridDim.x, gy = gridDim.y;
    int bx = blockIdx.x, by = blockIdx.y;
    if ((gx & 7) == 0) {
        const int lbid = bx + gx * by;
        const int xcd = lbid & 7;
        const int i = lbid >> 3;
        const int CX = gx >> 3;
        bx = xcd * CX + i / gy;
        by = i - (i / gy) * gy;
    }
    const long row0 = (long)bx * 256;
    const long col0 = (long)by * 128;
    const int srow = tid >> 3;            // 0..63 (per pass)
    const int schunk = tid & 7;           // 16B chunk in 128B row
    const int fr = lane & 15;
    const int q = lane >> 4;
    f32x4 acc[4][4] = {};
    for (int k0 = 0; k0 < K; k0 += 64) {
        __syncthreads();
#pragma unroll
        for (int p = 0; p < 4; ++p) {
            const int row = p * 64 + srow;
            const int sc = (schunk ^ (row & 7)) * 8;
            gload_lds16(&A[(row0 + row) * (long)lda + k0 + sc], As + row * 64 + schunk * 8);
        }
#pragma unroll
        for (int p = 0; p < 2; ++p) {
            const int row = p * 64 + srow;
            const int sc = (schunk ^ (row & 7)) * 8;
            gload_lds16(&WT[(col0 + row) * (long)K + k0 + sc], Bs + row * 64 + schunk * 8);
        }
        __syncthreads();
#pragma unroll
        for (int kk = 0; kk < 2; ++kk) {
            short8 af[4], bfr[4];
#pragma unroll
            for (int mf = 0; mf < 4; ++mf) {
                const int row = wm * 64 + mf * 16 + fr;
                const int byo = (row * 128 + kk * 64 + q * 16) ^ ((row & 7) << 4);
                af[mf] = *(const short8*)((const char*)As + byo);
            }
#pragma unroll
            for (int nf = 0; nf < 4; ++nf) {
                const int row = wn * 64 + nf * 16 + fr;
                const int byo = (row * 128 + kk * 64 + q * 16) ^ ((row & 7) << 4);
                bfr[nf] = *(const short8*)((const char*)Bs + byo);
            }
#pragma unroll
            for (int mf = 0; mf < 4; ++mf)
#pragma unroll
                for (int nf = 0; nf < 4; ++nf)
                    acc[mf][nf] = __builtin_amdgcn_mfma_f32_16x16x32_bf16(
                        af[mf], bfr[nf], acc[mf][nf], 0, 0, 0);
        }
    }
#pragma unroll
    for (int nf = 0; nf < 4; ++nf) {
        const long col = col0 + wn * 64 + nf * 16 + fr;
        const float bv = bias[col];
#pragma unroll
        for (int mf = 0; mf < 4; ++mf) {
#pragma unroll
            for (int i = 0; i < 4; ++i) {
                const long r = row0 + wm * 64 + mf * 16 + q * 4 + i;
                float vv = acc[mf][nf][i] + bv;
                if (RELU) vv = fmaxf(vv, 0.f);
                if (OUTBF) ((unsigned short*)Cv)[r * ldc + col] = f2b(vv);
                else       ((float*)Cv)[r * ldc + col] = vv;
            }
        }
    }
}

// =====================================================================
// Fused GEMM + residual + LayerNorm, 128x256 tile (full LN row), 512
// threads = 8 waves (2M x 4N).
// seq[M][256] = LN(seq + A @ W + bias) * g + b   (in place over seq)
// =====================================================================
__global__ __launch_bounds__(512) void gemm_wo_ln(
    const unsigned short* __restrict__ A, int lda,
    const unsigned short* __restrict__ WT,
    const float* __restrict__ bias,
    unsigned short* __restrict__ seq,
    const float* __restrict__ g, const float* __restrict__ b, int K)
{
    __shared__ unsigned short As[128 * 64];
    __shared__ unsigned short Bs[256 * 64];
    __shared__ float Lsum[128][4];
    __shared__ float Lsq[128][4];
    const int tid = threadIdx.x;
    const int wid = tid >> 6, lane = tid & 63;
    const int wm = wid >> 2, wn = wid & 3;     // 2 x 4 wave grid
    const int gx = gridDim.x;
    int bx = blockIdx.x;
    if ((gx & 7) == 0) bx = (bx & 7) * (gx >> 3) + (bx >> 3);
    const long row0 = (long)bx * 128;
    const int srow = tid >> 3;            // 0..63 per pass
    const int schunk = tid & 7;
    const int fr = lane & 15;
    const int q = lane >> 4;
    f32x4 acc[4][4] = {};
    for (int k0 = 0; k0 < K; k0 += 64) {
        __syncthreads();
#pragma unroll
        for (int p = 0; p < 2; ++p) {
            const int row = p * 64 + srow;
            const int sc = (schunk ^ (row & 7)) * 8;
            gload_lds16(&A[(row0 + row) * (long)lda + k0 + sc], As + row * 64 + schunk * 8);
        }
#pragma unroll
        for (int p = 0; p < 4; ++p) {
            const int row = p * 64 + srow;
            const int sc = (schunk ^ (row & 7)) * 8;
            gload_lds16(&WT[(long)row * K + k0 + sc], Bs + row * 64 + schunk * 8);
        }
        __syncthreads();
#pragma unroll
        for (int kk = 0; kk < 2; ++kk) {
            short8 af[4], bfr[4];
#pragma unroll
            for (int mf = 0; mf < 4; ++mf) {
                const int row = wm * 64 + mf * 16 + fr;
                const int byo = (row * 128 + kk * 64 + q * 16) ^ ((row & 7) << 4);
                af[mf] = *(const short8*)((const char*)As + byo);
            }
#pragma unroll
            for (int nf = 0; nf < 4; ++nf) {
                const int row = wn * 64 + nf * 16 + fr;
                const int byo = (row * 128 + kk * 64 + q * 16) ^ ((row & 7) << 4);
                bfr[nf] = *(const short8*)((const char*)Bs + byo);
            }
#pragma unroll
            for (int mf = 0; mf < 4; ++mf)
#pragma unroll
                for (int nf = 0; nf < 4; ++nf)
                    acc[mf][nf] = __builtin_amdgcn_mfma_f32_16x16x32_bf16(
                        af[mf], bfr[nf], acc[mf][nf], 0, 0, 0);
        }
    }
    // epilogue: acc += bias + residual(seq)
#pragma unroll
    for (int nf = 0; nf < 4; ++nf) {
        const int col = wn * 64 + nf * 16 + fr;
        const float bv = bias[col];
#pragma unroll
        for (int mf = 0; mf < 4; ++mf)
#pragma unroll
            for (int i = 0; i < 4; ++i) {
                const long r = row0 + wm * 64 + mf * 16 + q * 4 + i;
                acc[mf][nf][i] += bv + b2f(seq[r * 256 + col]);
            }
    }
    // per-row stats: in-thread over nf, shfl over fr group, LDS across wn
#pragma unroll
    for (int mf = 0; mf < 4; ++mf)
#pragma unroll
        for (int i = 0; i < 4; ++i) {
            float s = acc[mf][0][i] + acc[mf][1][i] + acc[mf][2][i] + acc[mf][3][i];
            float s2 = acc[mf][0][i] * acc[mf][0][i] + acc[mf][1][i] * acc[mf][1][i]
                     + acc[mf][2][i] * acc[mf][2][i] + acc[mf][3][i] * acc[mf][3][i];
#pragma unroll
            for (int m = 1; m <= 8; m <<= 1) {
                s += __shfl_xor(s, m, 64);
                s2 += __shfl_xor(s2, m, 64);
            }
            if (fr == 0) {
                const int lr = wm * 64 + mf * 16 + q * 4 + i;
                Lsum[lr][wn] = s;
                Lsq[lr][wn] = s2;
            }
        }
    __syncthreads();
#pragma unroll
    for (int mf = 0; mf < 4; ++mf)
#pragma unroll
        for (int i = 0; i < 4; ++i) {
            const int lr = wm * 64 + mf * 16 + q * 4 + i;
            const float sum = Lsum[lr][0] + Lsum[lr][1] + Lsum[lr][2] + Lsum[lr][3];
            const float sq  = Lsq[lr][0] + Lsq[lr][1] + Lsq[lr][2] + Lsq[lr][3];
            const float mean = sum * (1.f / 256.f);
            const float var = sq * (1.f / 256.f) - mean * mean;
            const float inv = rsqrtf(var + 1e-5f);
            const long r = row0 + lr;
#pragma unroll
            for (int nf = 0; nf < 4; ++nf) {
                const int col = wn * 64 + nf * 16 + fr;
                seq[r * 256 + col] = f2b((acc[mf][nf][i] - mean) * inv * g[col] + b[col]);
            }
        }
}

// =====================================================================
// bf16 MFMA GEMM (128 x 64, NF=2) — kept for W2 (2 blocks/CU win, R14).
// =====================================================================
template <bool RELU, bool OUTBF, int NF>
__global__ __launch_bounds__(256) void gemm_mfma(
    const unsigned short* __restrict__ A, int lda,
    const unsigned short* __restrict__ WT,
    const float* __restrict__ bias,
    void* __restrict__ Cv, int ldc, int K)
{
    __shared__ unsigned short As[128 * 64];
    __shared__ unsigned short Bs[32 * NF * 64];
    const int tid = threadIdx.x;
    const int wid = tid >> 6, lane = tid & 63;
    const int wm = wid >> 1, wn = wid & 1;
    const int gx = gridDim.x, gy = gridDim.y;
    int bx = blockIdx.x, by = blockIdx.y;
    if ((gx & 7) == 0) {
        const int lbid = bx + gx * by;
        const int xcd = lbid & 7;
        const int i = lbid >> 3;
        const int CX = gx >> 3;
        bx = xcd * CX + i / gy;
        by = i - (i / gy) * gy;
    }
    const long row0 = (long)bx * 128;
    const long col0 = (long)by * (32 * NF);
    const int srow = tid >> 3;
    const int schunk = tid & 7;
    const int fr = lane & 15;
    const int q = lane >> 4;
    f32x4 acc[4][NF] = {};
    for (int k0 = 0; k0 < K; k0 += 64) {
        __syncthreads();
#pragma unroll
        for (int p = 0; p < 4; ++p) {
            const int row = p * 32 + srow;
            const int sc = (schunk ^ (row & 7)) * 8;
            gload_lds16(&A[(row0 + row) * (long)lda + k0 + sc], As + row * 64 + schunk * 8);
        }
#pragma unroll
        for (int p = 0; p < NF; ++p) {
            const int row = p * 32 + srow;
            const int sc = (schunk ^ (row & 7)) * 8;
            gload_lds16(&WT[(col0 + row) * (long)K + k0 + sc], Bs + row * 64 + schunk * 8);
        }
        __syncthreads();
#pragma unroll
        for (int kk = 0; kk < 2; ++kk) {
            short8 af[4], bfr[NF];
#pragma unroll
            for (int mf = 0; mf < 4; ++mf) {
                const int row = wm * 64 + mf * 16 + fr;
                const int byo = (row * 128 + kk * 64 + q * 16) ^ ((row & 7) << 4);
                af[mf] = *(const short8*)((const char*)As + byo);
            }
#pragma unroll
            for (int nf = 0; nf < NF; ++nf) {
                const int row = wn * (NF * 16) + nf * 16 + fr;
                const int byo = (row * 128 + kk * 64 + q * 16) ^ ((row & 7) << 4);
                bfr[nf] = *(const short8*)((const char*)Bs + byo);
            }
#pragma unroll
            for (int mf = 0; mf < 4; ++mf)
#pragma unroll
                for (int nf = 0; nf < NF; ++nf)
                    acc[mf][nf] = __builtin_amdgcn_mfma_f32_16x16x32_bf16(
                        af[mf], bfr[nf], acc[mf][nf], 0, 0, 0);
        }
    }
#pragma unroll
    for (int nf = 0; nf < NF; ++nf) {
        const long col = col0 + wn * (NF * 16) + nf * 16 + fr;
        const float bv = bias[col];
#pragma unroll
        for (int mf = 0; mf < 4; ++mf) {
#pragma unroll
            for (int i = 0; i < 4; ++i) {
                const long r = row0 + wm * 64 + mf * 16 + q * 4 + i;
                float vv = acc[mf][nf][i] + bv;
                if (RELU) vv = fmaxf(vv, 0.f);
                if (OUTBF) ((unsigned short*)Cv)[r * ldc + col] = f2b(vv);
                else       ((float*)Cv)[r * ldc + col] = vv;
            }
        }
    }
}

// =====================================================================
// CSR build. erec[j] = {srcrow, ea01, ea23, ea45} — ONE 16B record per
// edge (single scattered line-touch vs two separate arrays).
// =====================================================================
__global__ void csr_init(int* __restrict__ cnt, int* __restrict__ fill) {
    int gid = blockIdx.x * blockDim.x + threadIdx.x;
    if (gid < NM) { cnt[gid] = 0; fill[gid] = 0; }
}

__global__ void csr_count(const int* __restrict__ eidx, int* __restrict__ cnt) {
    long el = (long)blockIdx.x * blockDim.x + threadIdx.x;
    if (el >= NE) return;
    int g = (int)(el >> 15), e = (int)(el & (EE - 1));
    int tgt = eidx[((long)g * 2 + 1) * EE + e];
    atomicAdd(&cnt[g * NN + tgt], 1);
}

__global__ __launch_bounds__(1024) void csr_scan(const int* __restrict__ cnt, int* __restrict__ off) {
    __shared__ int part[1024];
    const int t = threadIdx.x;
    const int base = t * (NM / 1024);
    int s = 0;
    for (int i = 0; i < NM / 1024; ++i) s += cnt[base + i];
    part[t] = s;
    __syncthreads();
    for (int d = 1; d < 1024; d <<= 1) {
        int v = (t >= d) ? part[t - d] : 0;
        __syncthreads();
        part[t] += v;
        __syncthreads();
    }
    int run = (t == 0) ? 0 : part[t - 1];
    for (int i = 0; i < NM / 1024; ++i) { off[base + i] = run; run += cnt[base + i]; }
    if (t == 1023) off[NM] = run;
}

__global__ void csr_scatter(const int* __restrict__ eidx, const float* __restrict__ eattr,
                            const int* __restrict__ off, int* __restrict__ fill,
                            uint4* __restrict__ erec) {
    long el = (long)blockIdx.x * blockDim.x + threadIdx.x;
    if (el >= NE) return;
    int g = (int)(el >> 15), e = (int)(el & (EE - 1));
    int src = eidx[((long)g * 2 + 0) * EE + e];
    int tgt = eidx[((long)g * 2 + 1) * EE + e];
    int tf = g * NN + tgt;
    int pos = atomicAdd(&fill[tf], 1);
    const long j = (long)off[tf] + pos;
    const float* ea = &eattr[el * 6];
    uint4 r;
    r.x = (unsigned)(g * NN + src);
    r.y = (unsigned)f2b(ea[0]) | ((unsigned)f2b(ea[1]) << 16);
    r.z = (unsigned)f2b(ea[2]) | ((unsigned)f2b(ea[3]) << 16);
    r.w = (unsigned)f2b(ea[4]) | ((unsigned)f2b(ea[5]) << 16);
    erec[j] = r;
}

// =====================================================================
// Fused TransformerConv on interleaved qkv [NM][768]. Per edge: one
// sequential 16B record (srcrow + 6 bf16 attrs) + the k/v gather,
// prefetched one full iteration ahead.
// =====================================================================
__global__ __launch_bounds__(256) void conv_fused(
    unsigned short* __restrict__ Z,
    const float* __restrict__ W_edge, const float* __restrict__ b_edge,
    const int* __restrict__ off, const uint4* __restrict__ erec)
{
    const int tid = threadIdx.x;
    const int wave = tid >> 6, lane = tid & 63;
    const int bid = (blockIdx.x & 7) * (NM / 4 / 8) + (blockIdx.x >> 3);
    const long tf = (long)bid * 4 + wave;
    const int d0 = lane * 4;
    unsigned short* qrow = &Z[tf * 768];
    const ushort4 q4 = *(const ushort4*)&qrow[d0];
    const float q0 = b2f(q4.x), q1 = b2f(q4.y), q2 = b2f(q4.z), q3 = b2f(q4.w);
    const float be0 = b_edge[d0], be1 = b_edge[d0 + 1],
                be2 = b_edge[d0 + 2], be3 = b_edge[d0 + 3];
    float w0[6], w1r[6], w2r[6], w3r[6];
#pragma unroll
    for (int j2 = 0; j2 < 6; ++j2) {
        const float* wp = &W_edge[j2 * 256 + d0];
        w0[j2] = wp[0]; w1r[j2] = wp[1]; w2r[j2] = wp[2]; w3r[j2] = wp[3];
    }
    float qb = q0 * be0 + q1 * be1 + q2 * be2 + q3 * be3;
    float qw[6];
#pragma unroll
    for (int j2 = 0; j2 < 6; ++j2)
        qw[j2] = q0 * w0[j2] + q1 * w1r[j2] + q2 * w2r[j2] + q3 * w3r[j2];
#pragma unroll
    for (int mm = 1; mm <= 4; mm <<= 1) {
        qb += __shfl_xor(qb, mm, 64);
#pragma unroll
        for (int j2 = 0; j2 < 6; ++j2) qw[j2] += __shfl_xor(qw[j2], mm, 64);
    }
    const float scale = 0.17677669529663687f;  // 1/sqrt(32)
    float s = 0.f, a0 = 0.f, a1 = 0.f, a2 = 0.f, a3 = 0.f;
    float t0 = 0.f, t1 = 0.f, t2 = 0.f, t3 = 0.f, t4 = 0.f, t5 = 0.f;
    const int jb = off[tf], je = off[tf + 1];
    ushort4 kc, vc;
    uint4 rc = {0, 0, 0, 0};        // current record
    uint4 r1 = {0, 0, 0, 0};        // next record (loaded one iter ahead)
    if (jb < je) {
        rc = erec[jb];
        const long sf = rc.x;
        kc = *(const ushort4*)&Z[sf * 768 + 256 + d0];
        vc = *(const ushort4*)&Z[sf * 768 + 512 + d0];
    }
    if (jb + 1 < je) r1 = erec[jb + 1];
    for (int j = jb; j < je; ++j) {
        ushort4 kn, vn;
        if (j + 1 < je) {   // issue k/v for j+1 from pre-loaded r1 (no wait)
            const long sf = r1.x;
            kn = *(const ushort4*)&Z[sf * 768 + 256 + d0];
            vn = *(const ushort4*)&Z[sf * 768 + 512 + d0];
        }
        uint4 r2 = {0, 0, 0, 0};
        if (j + 2 < je) r2 = erec[j + 2];   // cheap sequential 16B load
        float eac[6];
        eac[0] = b2f((unsigned short)(rc.y & 0xffffu));
        eac[1] = b2f((unsigned short)(rc.y >> 16));
        eac[2] = b2f((unsigned short)(rc.z & 0xffffu));
        eac[3] = b2f((unsigned short)(rc.z >> 16));
        eac[4] = b2f((unsigned short)(rc.w & 0xffffu));
        eac[5] = b2f((unsigned short)(rc.w >> 16));
        float p = q0 * b2f(kc.x) + q1 * b2f(kc.y) + q2 * b2f(kc.z) + q3 * b2f(kc.w);
        p += __shfl_xor(p, 1, 64);
        p += __shfl_xor(p, 2, 64);
        p += __shfl_xor(p, 4, 64);
        float alpha = p + qb;
        alpha += eac[0] * qw[0] + eac[1] * qw[1] + eac[2] * qw[2]
               + eac[3] * qw[3] + eac[4] * qw[4] + eac[5] * qw[5];
        const float a = __expf(alpha * scale);
        s += a;
        a0 += a * b2f(vc.x); a1 += a * b2f(vc.y);
        a2 += a * b2f(vc.z); a3 += a * b2f(vc.w);
        t0 += a * eac[0]; t1 += a * eac[1]; t2 += a * eac[2];
        t3 += a * eac[3]; t4 += a * eac[4]; t5 += a * eac[5];
        kc = kn; vc = vn;
        rc = r1; r1 = r2;
    }
    const float inv = (s > 0.f) ? 1.f / s : 0.f;
    float o0 = a0 + be0 * s, o1 = a1 + be1 * s, o2 = a2 + be2 * s, o3 = a3 + be3 * s;
    o0 += w0[0]*t0 + w0[1]*t1 + w0[2]*t2 + w0[3]*t3 + w0[4]*t4 + w0[5]*t5;
    o1 += w1r[0]*t0 + w1r[1]*t1 + w1r[2]*t2 + w1r[3]*t3 + w1r[4]*t4 + w1r[5]*t5;
    o2 += w2r[0]*t0 + w2r[1]*t1 + w2r[2]*t2 + w2r[3]*t3 + w2r[4]*t4 + w2r[5]*t5;
    o3 += w3r[0]*t0 + w3r[1]*t1 + w3r[2]*t2 + w3r[3]*t3 + w3r[4]*t4 + w3r[5]*t5;
    ushort4 o;
    o.x = f2b(o0 * inv); o.y = f2b(o1 * inv);
    o.z = f2b(o2 * inv); o.w = f2b(o3 * inv);
    *(ushort4*)&qrow[d0] = o;
}

// seq(bf16, [t*BN+b*N+n][256]) = conv(q-slice of Z) + skip(k-slice of Z)
__global__ void transpose_add(const unsigned short* __restrict__ Z,
                              unsigned short* __restrict__ out) {
    long gid = (long)blockIdx.x * blockDim.x + threadIdx.x;
    long row = gid >> 6;
    int c4 = (int)(gid & 63);
    int n = (int)(row % NN);
    int bt = (int)(row / NN);
    int t = bt % TT, b = bt / TT;
    long orow = (long)t * BN + (long)b * NN + n;
    ushort4 cv = ((const ushort4*)&Z[row * 768])[c4];
    ushort4 sv = ((const ushort4*)&Z[row * 768 + 256])[c4];
    ushort4 o;
    o.x = f2b(b2f(cv.x) + b2f(sv.x));
    o.y = f2b(b2f(cv.y) + b2f(sv.y));
    o.z = f2b(b2f(cv.z) + b2f(sv.z));
    o.w = f2b(b2f(cv.w) + b2f(sv.w));
    ((ushort4*)out)[orow * 64 + c4] = o;
}

// =====================================================================
// temporal attention v2: one 64-lane wave per node bn.
// =====================================================================
__global__ __launch_bounds__(256) void mha_time(unsigned short* __restrict__ Z)
{
    const int tid = threadIdx.x;
    const int wave = tid >> 6, lane = tid & 63;
    const long bn = (long)blockIdx.x * 4 + wave;
    const int d0 = lane * 4;
    const float scale = 0.17677669529663687f;
    float qv[TT][4], kv[TT][4], vv[TT][4];
    long r[TT];
#pragma unroll
    for (int t = 0; t < TT; ++t) {
        r[t] = ((long)t * BN + bn) * 768 + d0;
        const ushort4 qq = *(const ushort4*)&Z[r[t]];
        const ushort4 kk = *(const ushort4*)&Z[r[t] + 256];
        const ushort4 vx = *(const ushort4*)&Z[r[t] + 512];
        qv[t][0] = b2f(qq.x); qv[t][1] = b2f(qq.y); qv[t][2] = b2f(qq.z); qv[t][3] = b2f(qq.w);
        kv[t][0] = b2f(kk.x); kv[t][1] = b2f(kk.y); kv[t][2] = b2f(kk.z); kv[t][3] = b2f(kk.w);
        vv[t][0] = b2f(vx.x); vv[t][1] = b2f(vx.y); vv[t][2] = b2f(vx.z); vv[t][3] = b2f(vx.w);
    }
    float s[TT][TT];
#pragma unroll
    for (int t = 0; t < TT; ++t)
#pragma unroll
        for (int u = 0; u < TT; ++u) {
            float p = qv[t][0] * kv[u][0] + qv[t][1] * kv[u][1]
                    + qv[t][2] * kv[u][2] + qv[t][3] * kv[u][3];
            p += __shfl_xor(p, 1, 64);
            p += __shfl_xor(p, 2, 64);
            p += __shfl_xor(p, 4, 64);   // 8-lane group = one head
            s[t][u] = p * scale;
        }
#pragma unroll
    for (int t = 0; t < TT; ++t) {
        float mx = s[t][0];
#pragma unroll
        for (int u = 1; u < TT; ++u) mx = fmaxf(mx, s[t][u]);
        float sm = 0.f;
#pragma unroll
        for (int u = 0; u < TT; ++u) { s[t][u] = __expf(s[t][u] - mx); sm += s[t][u]; }
        const float inv = 1.f / sm;
        float o0 = 0.f, o1 = 0.f, o2 = 0.f, o3 = 0.f;
#pragma unroll
        for (int u = 0; u < TT; ++u) {
            o0 += s[t][u] * vv[u][0]; o1 += s[t][u] * vv[u][1];
            o2 += s[t][u] * vv[u][2]; o3 += s[t][u] * vv[u][3];
        }
        ushort4 o;
        o.x = f2b(o0 * inv); o.y = f2b(o1 * inv);
        o.z = f2b(o2 * inv); o.w = f2b(o3 * inv);
        *(ushort4*)&Z[r[t]] = o;
    }
}

// seq(bf16) = LayerNorm(seq + res(bf16, row-stride rstride)) * g + b
__global__ __launch_bounds__(256) void ln_residual(
    unsigned short* __restrict__ seq, const unsigned short* __restrict__ res,
    int rstride, const float* __restrict__ g, const float* __restrict__ b)
{
    const int wave = threadIdx.x >> 6, lane = threadIdx.x & 63;
    long row = (long)blockIdx.x * 4 + wave;
    const ushort4 s4 = *(const ushort4*)&seq[row * 256 + lane * 4];
    const ushort4 r4 = *(const ushort4*)&res[row * (long)rstride + lane * 4];
    float x[4] = { b2f(s4.x) + b2f(r4.x), b2f(s4.y) + b2f(r4.y),
                   b2f(s4.z) + b2f(r4.z), b2f(s4.w) + b2f(r4.w) };
    float sum = x[0] + x[1] + x[2] + x[3];
#pragma unroll
    for (int m = 32; m >= 1; m >>= 1) sum += __shfl_xor(sum, m, 64);
    float mean = sum * (1.f / 256.f);
    float vs = 0.f;
#pragma unroll
    for (int i = 0; i < 4; ++i) { float dl = x[i] - mean; vs += dl * dl; }
#pragma unroll
    for (int m = 32; m >= 1; m >>= 1) vs += __shfl_xor(vs, m, 64);
    float inv = rsqrtf(vs * (1.f / 256.f) + 1e-5f);
    ushort4 o;
    o.x = f2b((x[0] - mean) * inv * g[lane * 4 + 0] + b[lane * 4 + 0]);
    o.y = f2b((x[1] - mean) * inv * g[lane * 4 + 1] + b[lane * 4 + 1]);
    o.z = f2b((x[2] - mean) * inv * g[lane * 4 + 2] + b[lane * 4 + 2]);
    o.w = f2b((x[3] - mean) * inv * g[lane * 4 + 3] + b[lane * 4 + 3]);
    *(ushort4*)&seq[row * 256 + lane * 4] = o;
}

// out[row][0..9] = seq[t=T-1 rows](bf16) @ W_out + b_out ; one block per row
__global__ __launch_bounds__(256) void final_out(
    const unsigned short* __restrict__ seq, const float* __restrict__ Wd,
    const float* __restrict__ bd, float* __restrict__ out)
{
    __shared__ float xs[256];
    long row = blockIdx.x;
    xs[threadIdx.x] = b2f(seq[((long)(TT - 1) * BN + row) * 256 + threadIdx.x]);
    __syncthreads();
    const int wv = threadIdx.x >> 6, lane = threadIdx.x & 63;
    for (int o = wv; o < NCLS; o += 4) {
        float p = 0.f;
#pragma unroll
        for (int i = 0; i < 4; ++i) {
            int kk = lane + 64 * i;
            p += xs[kk] * Wd[kk * NCLS + o];
        }
#pragma unroll
        for (int m = 32; m >= 1; m >>= 1) p += __shfl_xor(p, m, 64);
        if (lane == 0) out[row * NCLS + o] = p + bd[o];
    }
}

__global__ void fill_sentinel(float* __restrict__ out, int n) {
    int gid = blockIdx.x * blockDim.x + threadIdx.x;
    if (gid < n) out[gid] = 1.0e6f;
}

// =====================================================================
extern "C" void kernel_launch(void* const* d_in, const int* in_sizes, int n_in,
                              void* d_out, int out_size, void* d_ws, size_t ws_size,
                              hipStream_t stream) {
    const float* xseq  = (const float*)d_in[0];
    const int*   eidx  = (const int*)d_in[1];
    const float* eattr = (const float*)d_in[2];
    const float* W_node = (const float*)d_in[3];
    const float* b_node = (const float*)d_in[4];
    const float* W_edge = (const float*)d_in[5];
    const float* b_edge = (const float*)d_in[6];
    const float* Wq = (const float*)d_in[7];  const float* bq = (const float*)d_in[8];
    const float* Wk = (const float*)d_in[9];  const float* bk = (const float*)d_in[10];
    const float* Wv = (const float*)d_in[11]; const float* bv = (const float*)d_in[12];
    const float* Ws = (const float*)d_in[13]; const float* bs = (const float*)d_in[14];
    const float* Wqkv = (const float*)d_in[15]; const float* bqkv = (const float*)d_in[16];
    const float* Wo = (const float*)d_in[17];   const float* bo = (const float*)d_in[18];
    const float* W1 = (const float*)d_in[19];   const float* b1 = (const float*)d_in[20];
    const float* W2 = (const float*)d_in[21];   const float* b2 = (const float*)d_in[22];
    const float* g_ln1 = (const float*)d_in[23]; const float* b_ln1 = (const float*)d_in[24];
    const float* g_ln2 = (const float*)d_in[25]; const float* b_ln2 = (const float*)d_in[26];
    const float* W_out = (const float*)d_in[27]; const float* b_out = (const float*)d_in[28];
    float* out = (float*)d_out;

    // ---- workspace layout ----
    const long SZ = (long)NM * DD;            // 20,971,520 elements
    unsigned short* Abf = (unsigned short*)d_ws;     // seq activations bf16 (42MB)
    unsigned short* Zu  = Abf + SZ;                  // qkv interleaved [NM][768] (126MB)
    unsigned short* Hid = Zu;                        // FFN hidden bf16 [MR][2048] (84MB)
    unsigned short* resF = Zu + (long)MR * FFD;      // FFN residual bf16 [NM][256] (42MB)
    unsigned short* wtN = Zu + 3 * SZ;                    // [256][64]
    unsigned short* wtQ = wtN + 256 * 64;                 // [768][256] stacked q,k,v
    unsigned short* wtS = wtQ + 3L * 65536;
    unsigned short* wtQKV = wtS + 65536;                  // 3 * [768][256]
    unsigned short* wtO = wtQKV + 3L * 768 * 256;         // 3 * [256][256]
    unsigned short* wtW1 = wtO + 3L * 65536;              // 3 * [2048][256]
    unsigned short* wtW2 = wtW1 + 3L * 2048 * 256;        // 3 * [256][2048]
    int* cnt  = (int*)(wtW2 + 3L * 256 * 2048);
    int* coff = cnt + NM;                                 // NM+1
    int* cfil = coff + NM + 1;
    float* qkvb = (float*)(cfil + NM);                    // 768 packed bias
    // tail region: xbf (NM*64 bf16 = 10.5MB) overlaid by erec (NE*16B = 21MB)
    char* tail = (char*)(qkvb + 768);
    tail = (char*)(((uintptr_t)tail + 15) & ~(uintptr_t)15);  // 16B align
    unsigned short* xbf = (unsigned short*)tail;
    uint4* erec = (uint4*)tail;                           // valid after h-GEMM
    char* wend = tail + (long)NE * 16;
    const size_t need = (size_t)(wend - (char*)d_ws);
    if (ws_size < need) {
        fill_sentinel<<<dim3((out_size + 255) / 256), dim3(256), 0, stream>>>(out, out_size);
        return;
    }

    dim3 blk(256);
    dim3 blk5(512);
    dim3 tb(32, 8);

    // ---- prologue (batched weight conversion) ----
    xconvert<<<dim3((unsigned)((long)NM * FIN / 4 / 256)), blk, 0, stream>>>(xseq, xbf, (long)NM * FIN / 4);
    wtrans<<<dim3(DD / 32, FIN / 32), tb, 0, stream>>>(W_node, wtN, FIN, DD);
    wtrans4<<<dim3(DD / 32, DD / 32, 4), tb, 0, stream>>>(Wq, Wk, Wv, Ws, wtQ);
    wtrans_s<<<dim3(768 / 32, DD / 32, 3), tb, 0, stream>>>(Wqkv, (long)DD * 768, wtQKV, 768L * 256, DD, 768);
    wtrans_s<<<dim3(DD / 32, DD / 32, 3), tb, 0, stream>>>(Wo, (long)DD * DD, wtO, 65536L, DD, DD);
    wtrans_s<<<dim3(FFD / 32, DD / 32, 3), tb, 0, stream>>>(W1, (long)DD * FFD, wtW1, 2048L * 256, DD, FFD);
    wtrans_s<<<dim3(DD / 32, FFD / 32, 3), tb, 0, stream>>>(W2, (long)FFD * DD, wtW2, 256L * 2048, FFD, DD);
    pack3<<<dim3(1), blk, 0, stream>>>(bq, bk, bv, qkvb);

    // ---- stage 1 GEMMs (xbf consumed here, then overlaid by erec) ----
    gemm_mfma2<false, true><<<dim3(NM / 256, DD / 128), blk5, 0, stream>>>(
        xbf, FIN, wtN, b_node, Abf, DD, FIN);
    gemm_mfma2<false, true><<<dim3(NM / 256, 768 / 128), blk5, 0, stream>>>(
        Abf, DD, wtQ, qkvb, Zu, 768, DD);

    // ---- CSR build (merged 16B records; xbf now dead) ----
    csr_init<<<dim3((NM + 255) / 256), blk, 0, stream>>>(cnt, cfil);
    csr_count<<<dim3((unsigned)(NE / 256)), blk, 0, stream>>>(eidx, cnt);
    csr_scan<<<dim3(1), dim3(1024), 0, stream>>>(cnt, coff);
    csr_scatter<<<dim3((unsigned)(NE / 256)), blk, 0, stream>>>(
        eidx, eattr, coff, cfil, erec);

    // ---- conv + skip + reshape ----
    conv_fused<<<dim3(NM / 4), blk, 0, stream>>>(
        Zu, W_edge, b_edge, coff, erec);
    gemm_mfma2<false, true><<<dim3(NM / 256, DD / 128), blk5, 0, stream>>>(
        Abf, DD, wtS, bs, (void*)(Zu + 256), 768, DD);
    transpose_add<<<dim3(NM * 64 / 256), blk, 0, stream>>>(Zu, Abf);

    // ---- stage 2: 3 temporal transformer encoder layers ----
    for (int l = 0; l < 3; ++l) {
        gemm_mfma2<false, true><<<dim3(NM / 256, 768 / 128), blk5, 0, stream>>>(
            Abf, DD, wtQKV + (long)l * 768 * 256, bqkv + (long)l * 768, Zu, 768, DD);
        mha_time<<<dim3(BN / 4), blk, 0, stream>>>(Zu);
        // fused Wo + residual + LN1 (128x256 tile, in place over Abf)
        gemm_wo_ln<<<dim3(NM / 128), blk5, 0, stream>>>(
            Zu, 768, wtO + (long)l * 65536, bo + (long)l * DD,
            Abf, g_ln1 + l * DD, b_ln1 + l * DD, DD);
        // FFN: 4 chunks of W1->W2 (W2 writes its slice of resF), one full LN2
        for (int mr = 0; mr < NM / MR; ++mr) {
            const long r0 = (long)mr * MR;
            gemm_mfma2<true, true><<<dim3(MR / 256, FFD / 128), blk5, 0, stream>>>(
                Abf + r0 * DD, DD, wtW1 + (long)l * 2048 * 256, b1 + (long)l * FFD, Hid, FFD, DD);
            gemm_mfma<false, true, 2><<<dim3(MR / 128, DD / 64), blk, 0, stream>>>(
                Hid, FFD, wtW2 + (long)l * 256 * 2048, b2 + (long)l * DD,
                resF + r0 * DD, DD, FFD);
        }
        ln_residual<<<dim3(NM / 4), blk, 0, stream>>>(
            Abf, resF, DD, g_ln2 + l * DD, b_ln2 + l * DD);
    }

    // ---- output head ----
    final_out<<<dim3(BN), blk, 0, stream>>>(Abf, W_out, b_out, out);
}